// Round 1
// baseline (1252.052 us; speedup 1.0000x reference)
//
#include <hip/hip_runtime.h>
#include <math.h>

#define NN    20000
#define E0    160000
#define EL    180000
#define NG    64
#define INDIM 1304
#define NEG_SLOPE 0.2f

// ---------------- fp32 tiled GEMM: C[M,N] = A[M,K] @ B[K,N], row-major ----------------
template<int BM, int BN, int BK>
__global__ __launch_bounds__(256)
void sgemm(const float* __restrict__ A, const float* __restrict__ B,
           float* __restrict__ C, int M, int N, int K) {
    __shared__ float As[BK][BM + 1];
    __shared__ float Bs[BK][BN];
    const int tx = threadIdx.x % 16;
    const int ty = threadIdx.x / 16;
    const int bm = blockIdx.y * BM;
    const int bn = blockIdx.x * BN;
    float acc[4][4];
#pragma unroll
    for (int i = 0; i < 4; i++)
#pragma unroll
        for (int j = 0; j < 4; j++) acc[i][j] = 0.f;

    for (int k0 = 0; k0 < K; k0 += BK) {
        // load A tile 64x16 (m = t/16 + i*16, k = t%16)
        {
            int m = threadIdx.x / BK;
            int kk = threadIdx.x % BK;
#pragma unroll
            for (int i = 0; i < 4; i++) {
                int row = bm + m + i * 16;
                float v = 0.f;
                if (row < M && (k0 + kk) < K) v = A[(size_t)row * K + k0 + kk];
                As[kk][m + i * 16] = v;
            }
        }
        // load B tile 16x64 (k = t/64 + i*4, n = t%64)
        {
            int n = threadIdx.x % BN;
            int kk = threadIdx.x / BN;
#pragma unroll
            for (int i = 0; i < 4; i++) {
                int krow = kk + i * 4;
                float v = 0.f;
                int col = bn + n;
                if ((k0 + krow) < K && col < N) v = B[(size_t)(k0 + krow) * N + col];
                Bs[krow][n] = v;
            }
        }
        __syncthreads();
#pragma unroll
        for (int kk = 0; kk < BK; kk++) {
            float a[4], b[4];
#pragma unroll
            for (int i = 0; i < 4; i++) a[i] = As[kk][ty * 4 + i];
#pragma unroll
            for (int j = 0; j < 4; j++) b[j] = Bs[kk][tx * 4 + j];
#pragma unroll
            for (int i = 0; i < 4; i++)
#pragma unroll
                for (int j = 0; j < 4; j++) acc[i][j] += a[i] * b[j];
        }
        __syncthreads();
    }
#pragma unroll
    for (int i = 0; i < 4; i++) {
        int row = bm + ty * 4 + i;
        if (row >= M) continue;
#pragma unroll
        for (int j = 0; j < 4; j++) {
            int col = bn + tx * 4 + j;
            if (col < N) C[(size_t)row * N + col] = acc[i][j];
        }
    }
}

// ---------------- attention logits e_src/e_dst per node ----------------
template<int H>
__global__ __launch_bounds__(256)
void compute_e(const float* __restrict__ hfeat, const float* __restrict__ a_src,
               const float* __restrict__ a_dst, float* __restrict__ esrc,
               float* __restrict__ edst) {
    const int n = blockIdx.x;
    const int t = threadIdx.x;
    __shared__ float red_s[4], red_d[4];
    for (int hd = 0; hd < H; hd++) {
        float hv = hfeat[(size_t)n * H * 256 + hd * 256 + t];
        float ps = hv * a_src[hd * 256 + t];
        float pd = hv * a_dst[hd * 256 + t];
#pragma unroll
        for (int o = 32; o > 0; o >>= 1) {
            ps += __shfl_down(ps, o, 64);
            pd += __shfl_down(pd, o, 64);
        }
        int wave = t >> 6, lane = t & 63;
        if (lane == 0) { red_s[wave] = ps; red_d[wave] = pd; }
        __syncthreads();
        if (t == 0) {
            esrc[n * H + hd] = red_s[0] + red_s[1] + red_s[2] + red_s[3];
            edst[n * H + hd] = red_d[0] + red_d[1] + red_d[2] + red_d[3];
        }
        __syncthreads();
    }
}

// ---------------- CSR build ----------------
__global__ void hist_kernel(const int* __restrict__ ei, int* __restrict__ deg) {
    int e = blockIdx.x * 256 + threadIdx.x;
    if (e >= EL) return;
    int d = (e < E0) ? ei[E0 + e] : (e - E0);
    atomicAdd(&deg[d], 1);
}

__global__ __launch_bounds__(1024)
void scan_kernel(const int* __restrict__ deg, int* __restrict__ off) {
    __shared__ int buf[1024];
    __shared__ int carry;
    int t = threadIdx.x;
    if (t == 0) { carry = 0; off[0] = 0; }
    __syncthreads();
    for (int base = 0; base < NN; base += 1024) {
        int i = base + t;
        int v = (i < NN) ? deg[i] : 0;
        buf[t] = v;
        __syncthreads();
        for (int s = 1; s < 1024; s <<= 1) {
            int x = (t >= s) ? buf[t - s] : 0;
            __syncthreads();
            buf[t] += x;
            __syncthreads();
        }
        if (i < NN) off[i + 1] = carry + buf[t];
        __syncthreads();
        if (t == 1023) carry += buf[1023];
        __syncthreads();
    }
}

__global__ void fill_kernel(const int* __restrict__ ei, const int* __restrict__ off,
                            int* __restrict__ cur, int* __restrict__ csr) {
    int e = blockIdx.x * 256 + threadIdx.x;
    if (e >= EL) return;
    int d = (e < E0) ? ei[E0 + e] : (e - E0);
    int s = (e < E0) ? ei[e] : (e - E0);
    int pos = off[d] + atomicAdd(&cur[d], 1);
    csr[pos] = s;
}

// ---------------- GAT aggregation (softmax over incoming edges, fused) ----------------
template<int H, bool RELU>
__global__ __launch_bounds__(256)
void gat_aggregate(const float* __restrict__ hfeat,   // [N, H*256]
                   const float* __restrict__ esrc,    // [N, H]
                   const float* __restrict__ edst,    // [N, H]
                   const int* __restrict__ off, const int* __restrict__ csr,
                   const float* __restrict__ bias,    // [H*256]
                   float* __restrict__ out) {         // [N, H*256]
    const int n = blockIdx.x;
    const int t = threadIdx.x;
    const int beg = off[n], end = off[n + 1];

    __shared__ int s_src[256];
    __shared__ float s_e[H * 256];

    float m[H], den[H], acc[H];
#pragma unroll
    for (int h = 0; h < H; h++) { m[h] = -INFINITY; den[h] = 0.f; acc[h] = 0.f; }

    float ed[H];
#pragma unroll
    for (int h = 0; h < H; h++) ed[h] = edst[n * H + h];

    for (int base = beg; base < end; base += 256) {
        int cnt = min(256, end - base);
        __syncthreads();
        if (t < cnt) {
            int s = csr[base + t];
            s_src[t] = s;
#pragma unroll
            for (int h = 0; h < H; h++) {
                float v = esrc[s * H + h] + ed[h];
                s_e[h * 256 + t] = (v >= 0.f) ? v : NEG_SLOPE * v;
            }
        }
        __syncthreads();
        // chunk max per head (redundant per thread; deg is small)
        float cm[H];
#pragma unroll
        for (int h = 0; h < H; h++) cm[h] = -INFINITY;
        for (int i = 0; i < cnt; i++)
#pragma unroll
            for (int h = 0; h < H; h++) cm[h] = fmaxf(cm[h], s_e[h * 256 + i]);
        // online rescale
#pragma unroll
        for (int h = 0; h < H; h++) {
            float nm = fmaxf(m[h], cm[h]);
            float sc = expf(m[h] - nm);   // m=-inf first time -> 0, nm finite
            den[h] *= sc;
            acc[h] *= sc;
            m[h] = nm;
        }
        for (int i = 0; i < cnt; i++) {
            int s = s_src[i];
#pragma unroll
            for (int h = 0; h < H; h++) {
                float w = expf(s_e[h * 256 + i] - m[h]);
                den[h] += w;
                acc[h] += w * hfeat[(size_t)s * H * 256 + h * 256 + t];
            }
        }
    }
#pragma unroll
    for (int h = 0; h < H; h++) {
        float r = acc[h] / (den[h] + 1e-16f) + bias[h * 256 + t];
        if (RELU) r = fmaxf(r, 0.f);
        out[(size_t)n * H * 256 + h * 256 + t] = r;
    }
}

// ---------------- pooling ----------------
__global__ __launch_bounds__(256)
void pool_kernel(const float* __restrict__ out2, const int* __restrict__ batch,
                 float* __restrict__ pooled, float* __restrict__ cnts) {
    int n = blockIdx.x, t = threadIdx.x;
    int g = batch[n];
    atomicAdd(&pooled[g * 256 + t], out2[(size_t)n * 256 + t]);
    if (t == 0) atomicAdd(&cnts[g], 1.0f);
}

// ---------------- MLP head + softmax ----------------
__global__ __launch_bounds__(256)
void head_kernel(const float* __restrict__ phy, const float* __restrict__ pooled,
                 const float* __restrict__ cnts,
                 const float* __restrict__ w11, const float* __restrict__ b11,
                 const float* __restrict__ w12, const float* __restrict__ b12,
                 const float* __restrict__ w21, const float* __restrict__ b21,
                 const float* __restrict__ w22, const float* __restrict__ b22,
                 float* __restrict__ out) {
    int g = blockIdx.x, t = threadIdx.x;
    __shared__ float ph[188];
    __shared__ float z[384];
    __shared__ float mid[128];
    __shared__ float t1[192];
    __shared__ float lg[2];
    if (t < 188) ph[t] = phy[g * 188 + t];
    z[t] = pooled[g * 256 + t] / fmaxf(cnts[g], 1.0f);
    __syncthreads();
    if (t < 128) {
        float s = b11[t];
        for (int k = 0; k < 188; k++) s += ph[k] * w11[k * 128 + t];
        mid[t] = fmaxf(s, 0.f);
    }
    __syncthreads();
    if (t < 128) {
        float s = b12[t];
        for (int k = 0; k < 128; k++) s += mid[k] * w12[k * 128 + t];
        z[256 + t] = fmaxf(s, 0.f);
    }
    __syncthreads();
    if (t < 192) {
        float s = b21[t];
        for (int k = 0; k < 384; k++) s += z[k] * w21[k * 192 + t];
        t1[t] = fmaxf(s, 0.f);
    }
    __syncthreads();
    if (t < 2) {
        float s = b22[t];
        for (int k = 0; k < 192; k++) s += t1[k] * w22[k * 2 + t];
        lg[t] = s;
    }
    __syncthreads();
    if (t == 0) {
        float mx = fmaxf(lg[0], lg[1]);
        float e0 = expf(lg[0] - mx), e1 = expf(lg[1] - mx);
        float d = e0 + e1;
        out[g * 2 + 0] = e0 / d;
        out[g * 2 + 1] = e1 / d;
    }
}

extern "C" void kernel_launch(void* const* d_in, const int* in_sizes, int n_in,
                              void* d_out, int out_size, void* d_ws, size_t ws_size,
                              hipStream_t stream) {
    const float* x       = (const float*)d_in[0];
    const int*   ei      = (const int*)  d_in[1];
    const float* phy     = (const float*)d_in[2];
    const int*   batch   = (const int*)  d_in[3];
    const float* W1      = (const float*)d_in[4];
    const float* a_src1  = (const float*)d_in[5];
    const float* a_dst1  = (const float*)d_in[6];
    const float* b1      = (const float*)d_in[7];
    const float* W2      = (const float*)d_in[8];
    const float* a_src2  = (const float*)d_in[9];
    const float* a_dst2  = (const float*)d_in[10];
    const float* b2      = (const float*)d_in[11];
    const float* fc1_w1  = (const float*)d_in[12];
    const float* fc1_b1  = (const float*)d_in[13];
    const float* fc1_w2  = (const float*)d_in[14];
    const float* fc1_b2  = (const float*)d_in[15];
    const float* fc2_w1  = (const float*)d_in[16];
    const float* fc2_b1  = (const float*)d_in[17];
    const float* fc2_w2  = (const float*)d_in[18];
    const float* fc2_b2  = (const float*)d_in[19];
    float* out = (float*)d_out;

    // ---- workspace layout ----
    char* base = (char*)d_ws;
    size_t o = 0;
    auto alloc = [&](size_t bytes) { size_t r = o; o += (bytes + 255) & ~255ULL; return r; };

    size_t o_h1    = alloc((size_t)NN * 768 * 4);   // h1 = x@W1 (dead after agg1)
    size_t o_h1out = alloc((size_t)NN * 768 * 4);   // relu(gat1)
    size_t o_es1   = alloc((size_t)NN * 3 * 4);
    size_t o_ed1   = alloc((size_t)NN * 3 * 4);
    size_t o_es2   = alloc((size_t)NN * 4);
    size_t o_ed2   = alloc((size_t)NN * 4);
    size_t o_deg   = alloc((size_t)(NN + 1) * 4);
    size_t o_off   = alloc((size_t)(NN + 1) * 4);
    size_t o_cur   = alloc((size_t)NN * 4);
    size_t o_csr   = alloc((size_t)EL * 4);
    size_t o_pool  = alloc((size_t)NG * 256 * 4);
    size_t o_cnts  = alloc((size_t)NG * 4);

    float* h1    = (float*)(base + o_h1);
    float* h1out = (float*)(base + o_h1out);
    // h2 / out2 overlay the dead h1 region (h1 unused after gat_aggregate<3>)
    float* h2    = (float*)(base + o_h1);
    float* out2  = (float*)(base + o_h1 + (size_t)NN * 256 * 4);
    float* es1   = (float*)(base + o_es1);
    float* ed1   = (float*)(base + o_ed1);
    float* es2   = (float*)(base + o_es2);
    float* ed2   = (float*)(base + o_ed2);
    int*   deg   = (int*)(base + o_deg);
    int*   offs  = (int*)(base + o_off);
    int*   cur   = (int*)(base + o_cur);
    int*   csr   = (int*)(base + o_csr);
    float* pooled= (float*)(base + o_pool);
    float* cnts  = (float*)(base + o_cnts);

    hipMemsetAsync(deg, 0, (size_t)(NN + 1) * 4, stream);
    hipMemsetAsync(cur, 0, (size_t)NN * 4, stream);
    hipMemsetAsync(pooled, 0, (size_t)NG * 256 * 4, stream);
    hipMemsetAsync(cnts, 0, (size_t)NG * 4, stream);

    // CSR build (independent of GEMM1)
    hist_kernel<<<(EL + 255) / 256, 256, 0, stream>>>(ei, deg);
    scan_kernel<<<1, 1024, 0, stream>>>(deg, offs);
    fill_kernel<<<(EL + 255) / 256, 256, 0, stream>>>(ei, offs, cur, csr);

    // Layer 1
    sgemm<64, 64, 16><<<dim3(768 / 64, (NN + 63) / 64), 256, 0, stream>>>(x, W1, h1, NN, 768, INDIM);
    compute_e<3><<<NN, 256, 0, stream>>>(h1, a_src1, a_dst1, es1, ed1);
    gat_aggregate<3, true><<<NN, 256, 0, stream>>>(h1, es1, ed1, offs, csr, b1, h1out);

    // Layer 2
    sgemm<64, 64, 16><<<dim3(256 / 64, (NN + 63) / 64), 256, 0, stream>>>(h1out, W2, h2, NN, 256, 768);
    compute_e<1><<<NN, 256, 0, stream>>>(h2, a_src2, a_dst2, es2, ed2);
    gat_aggregate<1, false><<<NN, 256, 0, stream>>>(h2, es2, ed2, offs, csr, b2, out2);

    // Pool + head
    pool_kernel<<<NN, 256, 0, stream>>>(out2, batch, pooled, cnts);
    head_kernel<<<NG, 256, 0, stream>>>(phy, pooled, cnts,
                                        fc1_w1, fc1_b1, fc1_w2, fc1_b2,
                                        fc2_w1, fc2_b1, fc2_w2, fc2_b2, out);
}

// Round 2
// 564.622 us; speedup vs baseline: 2.2175x; 2.2175x over previous
//
#include <hip/hip_runtime.h>
#include <hip/hip_bf16.h>
#include <math.h>

#define NN    20000
#define NP    20096          // 157*128 padded rows
#define E0    160000
#define EL    180000
#define NG    64
#define INDIM 1304
#define K1P   1312           // K padded to multiple of 32
#define NEG_SLOPE 0.2f

typedef __bf16 bf16x8 __attribute__((ext_vector_type(8)));
typedef float  f32x4  __attribute__((ext_vector_type(4)));

__device__ __forceinline__ void gload16(const void* g, void* l) {
    __builtin_amdgcn_global_load_lds(
        (const __attribute__((address_space(1))) void*)g,
        (__attribute__((address_space(3))) void*)l, 16, 0, 0);
}

// ---------------- bf16 MFMA GEMM: C[M,N] = A[Mp,K] @ Bt[N,K]^T ----------------
// m97 structure: 128x128 tile, BK=32, 4 waves each 64x64, 16x16x32 MFMA,
// global_load_lds width-16 staging into linear LDS.
template<typename CT>
__global__ __launch_bounds__(256)
void mfma_gemm(const __hip_bfloat16* __restrict__ A,   // [Mp][K] row-major (rows padded w/ zeros)
               const __hip_bfloat16* __restrict__ Bt,  // [N][K]  row-major (= B transposed)
               CT* __restrict__ C,                     // [M][N]  row-major
               int M, int N, int K) {                  // K multiple of 32; N multiple of 128
    __shared__ __hip_bfloat16 As[128 * 32];
    __shared__ __hip_bfloat16 Bs[128 * 32];
    const int t = threadIdx.x;
    const int w = t >> 6;
    const int l = t & 63;
    const int bm = blockIdx.y * 128;
    const int bn = blockIdx.x * 128;
    const int wm = (w >> 1) * 64;
    const int wn = (w & 1) * 64;

    f32x4 acc[4][4];
#pragma unroll
    for (int i = 0; i < 4; i++)
#pragma unroll
        for (int j = 0; j < 4; j++) acc[i][j] = (f32x4){0.f, 0.f, 0.f, 0.f};

    // staging: thread t covers LDS bytes issue*4096 + t*16  ->  row t/4 (+64), col (t%4)*8
    const int sr = t >> 2;
    const int sc = (t & 3) * 8;
    const __hip_bfloat16* a0 = A  + (size_t)(bm + sr)      * K + sc;
    const __hip_bfloat16* a1 = A  + (size_t)(bm + 64 + sr) * K + sc;
    const __hip_bfloat16* b0 = Bt + (size_t)(bn + sr)      * K + sc;
    const __hip_bfloat16* b1 = Bt + (size_t)(bn + 64 + sr) * K + sc;
    char* asw0 = (char*)As + w * 1024;
    char* asw1 = (char*)As + 4096 + w * 1024;
    char* bsw0 = (char*)Bs + w * 1024;
    char* bsw1 = (char*)Bs + 4096 + w * 1024;

    const int fr = l & 15;   // row (A) / col (B) within fragment
    const int fq = l >> 4;   // k-group

    for (int k0 = 0; k0 < K; k0 += 32) {
        gload16(a0 + k0, asw0);
        gload16(a1 + k0, asw1);
        gload16(b0 + k0, bsw0);
        gload16(b1 + k0, bsw1);
        __syncthreads();   // drains vmcnt: LDS tiles complete & visible
        bf16x8 av[4], bv[4];
#pragma unroll
        for (int i = 0; i < 4; i++)
            av[i] = *(const bf16x8*)&As[(wm + i * 16 + fr) * 32 + fq * 8];
#pragma unroll
        for (int j = 0; j < 4; j++)
            bv[j] = *(const bf16x8*)&Bs[(wn + j * 16 + fr) * 32 + fq * 8];
#pragma unroll
        for (int i = 0; i < 4; i++)
#pragma unroll
            for (int j = 0; j < 4; j++)
                acc[i][j] = __builtin_amdgcn_mfma_f32_16x16x32_bf16(av[i], bv[j], acc[i][j], 0, 0, 0);
        __syncthreads();   // all waves done reading before next stage
    }

    // C/D layout (m89-verified): col = lane&15, row = (lane>>4)*4 + reg
#pragma unroll
    for (int i = 0; i < 4; i++) {
#pragma unroll
        for (int j = 0; j < 4; j++) {
#pragma unroll
            for (int r = 0; r < 4; r++) {
                int row = bm + wm + i * 16 + fq * 4 + r;
                int col = bn + wn + j * 16 + fr;
                if (row < M) {
                    if constexpr (sizeof(CT) == 2)
                        C[(size_t)row * N + col] = __float2bfloat16(acc[i][j][r]);
                    else
                        C[(size_t)row * N + col] = acc[i][j][r];
                }
            }
        }
    }
}

// ---------------- fp32 -> bf16 conversions ----------------
__global__ __launch_bounds__(256)
void convert_x(const float* __restrict__ X, __hip_bfloat16* __restrict__ Xb) {
    int idx = blockIdx.x * 256 + threadIdx.x;
    const int nb = K1P / 8;  // 164 blocks of 8 cols
    if (idx >= NP * nb) return;
    int row = idx / nb;
    int cb = (idx - row * nb) * 8;
    union { __hip_bfloat16 h[8]; float4 f4; } u;
    if (row < NN && cb + 8 <= INDIM) {
        const float4* p = (const float4*)(X + (size_t)row * INDIM + cb);
        float4 u0 = p[0], u1 = p[1];
        u.h[0] = __float2bfloat16(u0.x); u.h[1] = __float2bfloat16(u0.y);
        u.h[2] = __float2bfloat16(u0.z); u.h[3] = __float2bfloat16(u0.w);
        u.h[4] = __float2bfloat16(u1.x); u.h[5] = __float2bfloat16(u1.y);
        u.h[6] = __float2bfloat16(u1.z); u.h[7] = __float2bfloat16(u1.w);
    } else {
#pragma unroll
        for (int e = 0; e < 8; e++) {
            float f = (row < NN && cb + e < INDIM) ? X[(size_t)row * INDIM + cb + e] : 0.f;
            u.h[e] = __float2bfloat16(f);
        }
    }
    *(float4*)(Xb + (size_t)row * K1P + cb) = u.f4;
}

__global__ __launch_bounds__(256)
void convert_wT(const float* __restrict__ W, __hip_bfloat16* __restrict__ Wt,
                int K, int N, int Kp) {   // W:[K][N] -> Wt:[N][Kp] (zero pad)
    int idx = blockIdx.x * 256 + threadIdx.x;
    if (idx >= N * Kp) return;
    int n = idx / Kp, k = idx - n * Kp;
    float f = (k < K) ? W[(size_t)k * N + n] : 0.f;
    Wt[idx] = __float2bfloat16(f);
}

// ---------------- attention logits per node ----------------
template<int H>
__global__ __launch_bounds__(256)
void compute_e(const __hip_bfloat16* __restrict__ hfeat, const float* __restrict__ a_src,
               const float* __restrict__ a_dst, float* __restrict__ esrc,
               float* __restrict__ edst) {
    const int n = blockIdx.x;
    const int t = threadIdx.x;
    __shared__ float red_s[4], red_d[4];
    for (int hd = 0; hd < H; hd++) {
        float hv = __bfloat162float(hfeat[(size_t)n * H * 256 + hd * 256 + t]);
        float ps = hv * a_src[hd * 256 + t];
        float pd = hv * a_dst[hd * 256 + t];
#pragma unroll
        for (int o = 32; o > 0; o >>= 1) {
            ps += __shfl_down(ps, o, 64);
            pd += __shfl_down(pd, o, 64);
        }
        int wave = t >> 6, lane = t & 63;
        if (lane == 0) { red_s[wave] = ps; red_d[wave] = pd; }
        __syncthreads();
        if (t == 0) {
            esrc[n * H + hd] = red_s[0] + red_s[1] + red_s[2] + red_s[3];
            edst[n * H + hd] = red_d[0] + red_d[1] + red_d[2] + red_d[3];
        }
        __syncthreads();
    }
}

// ---------------- CSR build ----------------
__global__ void hist_kernel(const int* __restrict__ ei, int* __restrict__ deg) {
    int e = blockIdx.x * 256 + threadIdx.x;
    if (e >= EL) return;
    int d = (e < E0) ? ei[E0 + e] : (e - E0);
    atomicAdd(&deg[d], 1);
}

__global__ __launch_bounds__(1024)
void scan_kernel(const int* __restrict__ deg, int* __restrict__ off) {
    __shared__ int wsum[16];
    __shared__ int carry_s;
    int t = threadIdx.x, lane = t & 63, wv = t >> 6;
    if (t == 0) { carry_s = 0; off[0] = 0; }
    __syncthreads();
    for (int base = 0; base < NN; base += 1024) {
        int i = base + t;
        int v = (i < NN) ? deg[i] : 0;
        int x = v;
#pragma unroll
        for (int o = 1; o < 64; o <<= 1) {
            int y = __shfl_up(x, o, 64);
            if (lane >= o) x += y;
        }
        if (lane == 63) wsum[wv] = x;
        __syncthreads();
        if (wv == 0 && lane < 16) {
            int s = wsum[lane];
#pragma unroll
            for (int o = 1; o < 16; o <<= 1) {
                int y = __shfl_up(s, o, 64);
                if (lane >= o) s += y;
            }
            wsum[lane] = s;
        }
        __syncthreads();
        int woff = (wv == 0) ? 0 : wsum[wv - 1];
        int total = wsum[15];
        if (i < NN) off[i + 1] = carry_s + woff + x;
        __syncthreads();
        if (t == 0) carry_s += total;
        __syncthreads();
    }
}

__global__ void fill_kernel(const int* __restrict__ ei, const int* __restrict__ off,
                            int* __restrict__ cur, int* __restrict__ csr) {
    int e = blockIdx.x * 256 + threadIdx.x;
    if (e >= EL) return;
    int d = (e < E0) ? ei[E0 + e] : (e - E0);
    int s = (e < E0) ? ei[e] : (e - E0);
    int pos = off[d] + atomicAdd(&cur[d], 1);
    csr[pos] = s;
}

// ---------------- GAT aggregation (fused softmax over incoming edges) ----------------
template<int H, bool RELU, typename OutT>
__global__ __launch_bounds__(256)
void gat_aggregate(const __hip_bfloat16* __restrict__ hfeat,  // [N][H*256] bf16
                   const float* __restrict__ esrc,            // [N][H]
                   const float* __restrict__ edst,            // [N][H]
                   const int* __restrict__ off, const int* __restrict__ csr,
                   const float* __restrict__ bias,            // [H*256]
                   OutT* __restrict__ out) {                  // [N][H*256]
    const int n = blockIdx.x;
    const int t = threadIdx.x;
    const int beg = off[n], end = off[n + 1];

    __shared__ int s_src[256];
    __shared__ float s_e[H * 256];

    float m[H], den[H], acc[H];
#pragma unroll
    for (int h = 0; h < H; h++) { m[h] = -INFINITY; den[h] = 0.f; acc[h] = 0.f; }

    float ed[H];
#pragma unroll
    for (int h = 0; h < H; h++) ed[h] = edst[n * H + h];

    for (int base = beg; base < end; base += 256) {
        int cnt = min(256, end - base);
        __syncthreads();
        if (t < cnt) {
            int s = csr[base + t];
            s_src[t] = s;
#pragma unroll
            for (int h = 0; h < H; h++) {
                float v = esrc[s * H + h] + ed[h];
                s_e[h * 256 + t] = (v >= 0.f) ? v : NEG_SLOPE * v;
            }
        }
        __syncthreads();
        float cm[H];
#pragma unroll
        for (int h = 0; h < H; h++) cm[h] = -INFINITY;
        for (int i = 0; i < cnt; i++)
#pragma unroll
            for (int h = 0; h < H; h++) cm[h] = fmaxf(cm[h], s_e[h * 256 + i]);
#pragma unroll
        for (int h = 0; h < H; h++) {
            float nm = fmaxf(m[h], cm[h]);
            float sc = expf(m[h] - nm);
            den[h] *= sc;
            acc[h] *= sc;
            m[h] = nm;
        }
        for (int i = 0; i < cnt; i++) {
            int s = s_src[i];
#pragma unroll
            for (int h = 0; h < H; h++) {
                float wgt = expf(s_e[h * 256 + i] - m[h]);
                den[h] += wgt;
                acc[h] += wgt * __bfloat162float(hfeat[(size_t)s * (H * 256) + h * 256 + t]);
            }
        }
    }
#pragma unroll
    for (int h = 0; h < H; h++) {
        float r = acc[h] / (den[h] + 1e-16f) + bias[h * 256 + t];
        if (RELU) r = fmaxf(r, 0.f);
        if constexpr (sizeof(OutT) == 2)
            out[(size_t)n * (H * 256) + h * 256 + t] = __float2bfloat16(r);
        else
            out[(size_t)n * (H * 256) + h * 256 + t] = r;
    }
}

// ---------------- pooling ----------------
__global__ __launch_bounds__(256)
void pool_kernel(const float* __restrict__ out2, const int* __restrict__ batch,
                 float* __restrict__ pooled, float* __restrict__ cnts) {
    int n = blockIdx.x, t = threadIdx.x;
    int g = batch[n];
    atomicAdd(&pooled[g * 256 + t], out2[(size_t)n * 256 + t]);
    if (t == 0) atomicAdd(&cnts[g], 1.0f);
}

// ---------------- MLP head + softmax ----------------
__global__ __launch_bounds__(256)
void head_kernel(const float* __restrict__ phy, const float* __restrict__ pooled,
                 const float* __restrict__ cnts,
                 const float* __restrict__ w11, const float* __restrict__ b11,
                 const float* __restrict__ w12, const float* __restrict__ b12,
                 const float* __restrict__ w21, const float* __restrict__ b21,
                 const float* __restrict__ w22, const float* __restrict__ b22,
                 float* __restrict__ out) {
    int g = blockIdx.x, t = threadIdx.x;
    __shared__ float ph[188];
    __shared__ float z[384];
    __shared__ float mid[128];
    __shared__ float t1[192];
    __shared__ float lg[2];
    if (t < 188) ph[t] = phy[g * 188 + t];
    z[t] = pooled[g * 256 + t] / fmaxf(cnts[g], 1.0f);
    __syncthreads();
    if (t < 128) {
        float s = b11[t];
        for (int k = 0; k < 188; k++) s += ph[k] * w11[k * 128 + t];
        mid[t] = fmaxf(s, 0.f);
    }
    __syncthreads();
    if (t < 128) {
        float s = b12[t];
        for (int k = 0; k < 128; k++) s += mid[k] * w12[k * 128 + t];
        z[256 + t] = fmaxf(s, 0.f);
    }
    __syncthreads();
    if (t < 192) {
        float s = b21[t];
        for (int k = 0; k < 384; k++) s += z[k] * w21[k * 192 + t];
        t1[t] = fmaxf(s, 0.f);
    }
    __syncthreads();
    if (t < 2) {
        float s = b22[t];
        for (int k = 0; k < 192; k++) s += t1[k] * w22[k * 2 + t];
        lg[t] = s;
    }
    __syncthreads();
    if (t == 0) {
        float mx = fmaxf(lg[0], lg[1]);
        float e0 = expf(lg[0] - mx), e1 = expf(lg[1] - mx);
        float d = e0 + e1;
        out[g * 2 + 0] = e0 / d;
        out[g * 2 + 1] = e1 / d;
    }
}

extern "C" void kernel_launch(void* const* d_in, const int* in_sizes, int n_in,
                              void* d_out, int out_size, void* d_ws, size_t ws_size,
                              hipStream_t stream) {
    const float* x       = (const float*)d_in[0];
    const int*   ei      = (const int*)  d_in[1];
    const float* phy     = (const float*)d_in[2];
    const int*   batch   = (const int*)  d_in[3];
    const float* W1      = (const float*)d_in[4];
    const float* a_src1  = (const float*)d_in[5];
    const float* a_dst1  = (const float*)d_in[6];
    const float* b1      = (const float*)d_in[7];
    const float* W2      = (const float*)d_in[8];
    const float* a_src2  = (const float*)d_in[9];
    const float* a_dst2  = (const float*)d_in[10];
    const float* b2      = (const float*)d_in[11];
    const float* fc1_w1  = (const float*)d_in[12];
    const float* fc1_b1  = (const float*)d_in[13];
    const float* fc1_w2  = (const float*)d_in[14];
    const float* fc1_b2  = (const float*)d_in[15];
    const float* fc2_w1  = (const float*)d_in[16];
    const float* fc2_b1  = (const float*)d_in[17];
    const float* fc2_w2  = (const float*)d_in[18];
    const float* fc2_b2  = (const float*)d_in[19];
    float* out = (float*)d_out;

    char* base = (char*)d_ws;
    size_t o = 0;
    auto alloc = [&](size_t bytes) { size_t r = o; o += (bytes + 255) & ~255ULL; return r; };

    size_t o_xb   = alloc((size_t)NP * K1P * 2);     // 52.7MB; reused for h2b/out2 after GEMM1
    size_t o_w1t  = alloc((size_t)768 * K1P * 2);
    size_t o_w2t  = alloc((size_t)256 * 768 * 2);
    size_t o_h1b  = alloc((size_t)NP * 768 * 2);     // GEMM1 out (bf16)
    size_t o_hob  = alloc((size_t)NP * 768 * 2);     // agg1 out (bf16), GEMM2 A
    size_t o_es1  = alloc((size_t)NN * 3 * 4);
    size_t o_ed1  = alloc((size_t)NN * 3 * 4);
    size_t o_es2  = alloc((size_t)NN * 4);
    size_t o_ed2  = alloc((size_t)NN * 4);
    size_t o_deg  = alloc((size_t)(NN + 1) * 4);
    size_t o_off  = alloc((size_t)(NN + 1) * 4);
    size_t o_cur  = alloc((size_t)NN * 4);
    size_t o_csr  = alloc((size_t)EL * 4);
    size_t o_pool = alloc((size_t)NG * 256 * 4);
    size_t o_cnts = alloc((size_t)NG * 4);

    __hip_bfloat16* xb   = (__hip_bfloat16*)(base + o_xb);
    __hip_bfloat16* w1t  = (__hip_bfloat16*)(base + o_w1t);
    __hip_bfloat16* w2t  = (__hip_bfloat16*)(base + o_w2t);
    __hip_bfloat16* h1b  = (__hip_bfloat16*)(base + o_h1b);
    __hip_bfloat16* hob  = (__hip_bfloat16*)(base + o_hob);
    // overlays in dead xb region (xb only used by GEMM1)
    __hip_bfloat16* h2b  = (__hip_bfloat16*)(base + o_xb);                       // 10.3MB
    float*          out2 = (float*)(base + o_xb + (size_t)24 * 1024 * 1024);     // 20.5MB
    float* es1   = (float*)(base + o_es1);
    float* ed1   = (float*)(base + o_ed1);
    float* es2   = (float*)(base + o_es2);
    float* ed2   = (float*)(base + o_ed2);
    int*   deg   = (int*)(base + o_deg);
    int*   offs  = (int*)(base + o_off);
    int*   cur   = (int*)(base + o_cur);
    int*   csr   = (int*)(base + o_csr);
    float* pooled= (float*)(base + o_pool);
    float* cnts  = (float*)(base + o_cnts);

    hipMemsetAsync(deg, 0, (size_t)(NN + 1) * 4, stream);
    hipMemsetAsync(cur, 0, (size_t)NN * 4, stream);
    hipMemsetAsync(pooled, 0, (size_t)NG * 256 * 4, stream);
    hipMemsetAsync(cnts, 0, (size_t)NG * 4, stream);
    // zero pad rows of GEMM2's A (rows NN..NP-1)
    hipMemsetAsync(hob + (size_t)NN * 768, 0, (size_t)(NP - NN) * 768 * 2, stream);

    // conversions
    convert_x<<<(NP * (K1P / 8) + 255) / 256, 256, 0, stream>>>(x, xb);
    convert_wT<<<(768 * K1P + 255) / 256, 256, 0, stream>>>(W1, w1t, INDIM, 768, K1P);
    convert_wT<<<(256 * 768 + 255) / 256, 256, 0, stream>>>(W2, w2t, 768, 256, 768);

    // CSR build
    hist_kernel<<<(EL + 255) / 256, 256, 0, stream>>>(ei, deg);
    scan_kernel<<<1, 1024, 0, stream>>>(deg, offs);
    fill_kernel<<<(EL + 255) / 256, 256, 0, stream>>>(ei, offs, cur, csr);

    // Layer 1: h1 = x @ W1 (bf16 MFMA), then GAT aggregate + ReLU -> bf16
    mfma_gemm<__hip_bfloat16><<<dim3(6, 157), 256, 0, stream>>>(xb, w1t, h1b, NN, 768, K1P);
    compute_e<3><<<NN, 256, 0, stream>>>(h1b, a_src1, a_dst1, es1, ed1);
    gat_aggregate<3, true, __hip_bfloat16><<<NN, 256, 0, stream>>>(h1b, es1, ed1, offs, csr, b1, hob);

    // Layer 2
    mfma_gemm<__hip_bfloat16><<<dim3(2, 157), 256, 0, stream>>>(hob, w2t, h2b, NN, 256, 768);
    compute_e<1><<<NN, 256, 0, stream>>>(h2b, a_src2, a_dst2, es2, ed2);
    gat_aggregate<1, false, float><<<NN, 256, 0, stream>>>(h2b, es2, ed2, offs, csr, b2, out2);

    // Pool + head
    pool_kernel<<<NN, 256, 0, stream>>>(out2, batch, pooled, cnts);
    head_kernel<<<NG, 256, 0, stream>>>(phy, pooled, cnts,
                                        fc1_w1, fc1_b1, fc1_w2, fc1_b2,
                                        fc2_w1, fc2_b1, fc2_w2, fc2_b2, out);
}

// Round 3
// 350.534 us; speedup vs baseline: 3.5718x; 1.6107x over previous
//
#include <hip/hip_runtime.h>
#include <hip/hip_bf16.h>
#include <math.h>

#define NN    20000
#define NP    20096          // 157*128 padded rows
#define E0    160000
#define EL    180000
#define NG    64
#define INDIM 1304
#define K1P   1312           // K padded to multiple of 32
#define NEG_SLOPE 0.2f
#define PCH   8              // pool chunks per graph

typedef __bf16 bf16x8 __attribute__((ext_vector_type(8)));
typedef __bf16 bf16x4 __attribute__((ext_vector_type(4)));
typedef float  f32x4  __attribute__((ext_vector_type(4)));

__device__ __forceinline__ void gload16(const void* g, void* l) {
    __builtin_amdgcn_global_load_lds(
        (const __attribute__((address_space(1))) void*)g,
        (__attribute__((address_space(3))) void*)l, 16, 0, 0);
}

// ---------------- bf16 MFMA GEMM: C[M,N] = A[Mp,K] @ Bt[N,K]^T ----------------
template<typename CT>
__global__ __launch_bounds__(256)
void mfma_gemm(const __hip_bfloat16* __restrict__ A,   // [Mp][K] row-major (pad rows zeroed)
               const __hip_bfloat16* __restrict__ Bt,  // [N][K]  row-major (= B transposed)
               CT* __restrict__ C,                     // [M][N]  row-major
               int M, int N, int K) {                  // K %32==0; N %128==0
    __shared__ __hip_bfloat16 As[128 * 32];
    __shared__ __hip_bfloat16 Bs[128 * 32];
    const int t = threadIdx.x;
    const int w = t >> 6;
    const int l = t & 63;
    const int bm = blockIdx.y * 128;
    const int bn = blockIdx.x * 128;
    const int wm = (w >> 1) * 64;
    const int wn = (w & 1) * 64;

    f32x4 acc[4][4];
#pragma unroll
    for (int i = 0; i < 4; i++)
#pragma unroll
        for (int j = 0; j < 4; j++) acc[i][j] = (f32x4){0.f, 0.f, 0.f, 0.f};

    const int sr = t >> 2;
    const int sc = (t & 3) * 8;
    const __hip_bfloat16* a0 = A  + (size_t)(bm + sr)      * K + sc;
    const __hip_bfloat16* a1 = A  + (size_t)(bm + 64 + sr) * K + sc;
    const __hip_bfloat16* b0 = Bt + (size_t)(bn + sr)      * K + sc;
    const __hip_bfloat16* b1 = Bt + (size_t)(bn + 64 + sr) * K + sc;
    char* asw0 = (char*)As + w * 1024;
    char* asw1 = (char*)As + 4096 + w * 1024;
    char* bsw0 = (char*)Bs + w * 1024;
    char* bsw1 = (char*)Bs + 4096 + w * 1024;

    const int fr = l & 15;
    const int fq = l >> 4;

    for (int k0 = 0; k0 < K; k0 += 32) {
        gload16(a0 + k0, asw0);
        gload16(a1 + k0, asw1);
        gload16(b0 + k0, bsw0);
        gload16(b1 + k0, bsw1);
        __syncthreads();
        bf16x8 av[4], bv[4];
#pragma unroll
        for (int i = 0; i < 4; i++)
            av[i] = *(const bf16x8*)&As[(wm + i * 16 + fr) * 32 + fq * 8];
#pragma unroll
        for (int j = 0; j < 4; j++)
            bv[j] = *(const bf16x8*)&Bs[(wn + j * 16 + fr) * 32 + fq * 8];
#pragma unroll
        for (int i = 0; i < 4; i++)
#pragma unroll
            for (int j = 0; j < 4; j++)
                acc[i][j] = __builtin_amdgcn_mfma_f32_16x16x32_bf16(av[i], bv[j], acc[i][j], 0, 0, 0);
        __syncthreads();
    }

#pragma unroll
    for (int i = 0; i < 4; i++) {
#pragma unroll
        for (int j = 0; j < 4; j++) {
#pragma unroll
            for (int r = 0; r < 4; r++) {
                int row = bm + wm + i * 16 + fq * 4 + r;
                int col = bn + wn + j * 16 + fr;
                if (row < M) {
                    if constexpr (sizeof(CT) == 2)
                        C[(size_t)row * N + col] = __float2bfloat16(acc[i][j][r]);
                    else
                        C[(size_t)row * N + col] = acc[i][j][r];
                }
            }
        }
    }
}

// ---------------- fp32 -> bf16 conversions ----------------
__global__ __launch_bounds__(256)
void convert_x(const float* __restrict__ X, __hip_bfloat16* __restrict__ Xb) {
    int idx = blockIdx.x * 256 + threadIdx.x;
    const int nb = K1P / 8;
    if (idx >= NP * nb) return;
    int row = idx / nb;
    int cb = (idx - row * nb) * 8;
    union { __hip_bfloat16 h[8]; float4 f4; } u;
    if (row < NN && cb + 8 <= INDIM) {
        const float4* p = (const float4*)(X + (size_t)row * INDIM + cb);
        float4 u0 = p[0], u1 = p[1];
        u.h[0] = __float2bfloat16(u0.x); u.h[1] = __float2bfloat16(u0.y);
        u.h[2] = __float2bfloat16(u0.z); u.h[3] = __float2bfloat16(u0.w);
        u.h[4] = __float2bfloat16(u1.x); u.h[5] = __float2bfloat16(u1.y);
        u.h[6] = __float2bfloat16(u1.z); u.h[7] = __float2bfloat16(u1.w);
    } else {
#pragma unroll
        for (int e = 0; e < 8; e++) {
            float f = (row < NN && cb + e < INDIM) ? X[(size_t)row * INDIM + cb + e] : 0.f;
            u.h[e] = __float2bfloat16(f);
        }
    }
    *(float4*)(Xb + (size_t)row * K1P + cb) = u.f4;
}

__global__ __launch_bounds__(256)
void convert_wT(const float* __restrict__ W, __hip_bfloat16* __restrict__ Wt,
                int K, int N, int Kp) {
    int idx = blockIdx.x * 256 + threadIdx.x;
    if (idx >= N * Kp) return;
    int n = idx / Kp, k = idx - n * Kp;
    float f = (k < K) ? W[(size_t)k * N + n] : 0.f;
    Wt[idx] = __float2bfloat16(f);
}

// ---------------- attention logits: one wave per node ----------------
template<int H>
__global__ __launch_bounds__(256)
void compute_e(const __hip_bfloat16* __restrict__ hfeat, const float* __restrict__ a_src,
               const float* __restrict__ a_dst, float* __restrict__ esrc,
               float* __restrict__ edst, int N) {
    const int wv = threadIdx.x >> 6, lane = threadIdx.x & 63;
    const int n = blockIdx.x * 4 + wv;
    if (n >= N) return;
#pragma unroll
    for (int hd = 0; hd < H; hd++) {
        bf16x4 hv = *(const bf16x4*)(hfeat + (size_t)n * (H * 256) + hd * 256 + lane * 4);
        float ps = 0.f, pd = 0.f;
#pragma unroll
        for (int e = 0; e < 4; e++) {
            float f = (float)hv[e];
            ps += f * a_src[hd * 256 + lane * 4 + e];
            pd += f * a_dst[hd * 256 + lane * 4 + e];
        }
#pragma unroll
        for (int o = 32; o > 0; o >>= 1) {
            ps += __shfl_down(ps, o, 64);
            pd += __shfl_down(pd, o, 64);
        }
        if (lane == 0) {
            esrc[n * H + hd] = ps;
            edst[n * H + hd] = pd;
        }
    }
}

// ---------------- CSR build ----------------
__global__ void hist_kernel(const int* __restrict__ ei, int* __restrict__ deg) {
    int e = blockIdx.x * 256 + threadIdx.x;
    if (e >= EL) return;
    int d = (e < E0) ? ei[E0 + e] : (e - E0);
    atomicAdd(&deg[d], 1);
}

__global__ __launch_bounds__(1024)
void scan_kernel(const int* __restrict__ deg, int* __restrict__ off) {
    __shared__ int wsum[16];
    __shared__ int carry_s;
    int t = threadIdx.x, lane = t & 63, wv = t >> 6;
    if (t == 0) { carry_s = 0; off[0] = 0; }
    __syncthreads();
    for (int base = 0; base < NN; base += 1024) {
        int i = base + t;
        int v = (i < NN) ? deg[i] : 0;
        int x = v;
#pragma unroll
        for (int o = 1; o < 64; o <<= 1) {
            int y = __shfl_up(x, o, 64);
            if (lane >= o) x += y;
        }
        if (lane == 63) wsum[wv] = x;
        __syncthreads();
        if (wv == 0 && lane < 16) {
            int s = wsum[lane];
#pragma unroll
            for (int o = 1; o < 16; o <<= 1) {
                int y = __shfl_up(s, o, 64);
                if (lane >= o) s += y;
            }
            wsum[lane] = s;
        }
        __syncthreads();
        int woff = (wv == 0) ? 0 : wsum[wv - 1];
        int total = wsum[15];
        if (i < NN) off[i + 1] = carry_s + woff + x;
        __syncthreads();
        if (t == 0) carry_s += total;
        __syncthreads();
    }
}

__global__ void fill_kernel(const int* __restrict__ ei, const int* __restrict__ off,
                            int* __restrict__ cur, int* __restrict__ csr) {
    int e = blockIdx.x * 256 + threadIdx.x;
    if (e >= EL) return;
    int d = (e < E0) ? ei[E0 + e] : (e - E0);
    int s = (e < E0) ? ei[e] : (e - E0);
    int pos = off[d] + atomicAdd(&cur[d], 1);
    csr[pos] = s;
}

// ---------------- GAT aggregation (fused softmax, exp computed once per edge) ----------------
template<int H, bool RELU, typename OutT>
__global__ __launch_bounds__(256)
void gat_aggregate(const __hip_bfloat16* __restrict__ hfeat,  // [N][H*256] bf16
                   const float* __restrict__ esrc,
                   const float* __restrict__ edst,
                   const int* __restrict__ off, const int* __restrict__ csr,
                   const float* __restrict__ bias,
                   OutT* __restrict__ out) {
    const int n = blockIdx.x;
    const int t = threadIdx.x;
    const int beg = off[n], end = off[n + 1];

    __shared__ int s_src[256];
    __shared__ float s_w[H * 256];

    float m[H], den[H], acc[H];
#pragma unroll
    for (int h = 0; h < H; h++) { m[h] = -INFINITY; den[h] = 0.f; acc[h] = 0.f; }

    float ed[H];
#pragma unroll
    for (int h = 0; h < H; h++) ed[h] = edst[n * H + h];

    for (int base = beg; base < end; base += 256) {
        int cnt = min(256, end - base);
        __syncthreads();
        if (t < cnt) {
            int s = csr[base + t];
            s_src[t] = s;
#pragma unroll
            for (int h = 0; h < H; h++) {
                float v = esrc[s * H + h] + ed[h];
                s_w[h * 256 + t] = (v >= 0.f) ? v : NEG_SLOPE * v;
            }
        }
        __syncthreads();
        // chunk max (every thread scans -> identical m/den across threads)
        float cm[H];
#pragma unroll
        for (int h = 0; h < H; h++) cm[h] = -INFINITY;
        for (int i = 0; i < cnt; i++)
#pragma unroll
            for (int h = 0; h < H; h++) cm[h] = fmaxf(cm[h], s_w[h * 256 + i]);
#pragma unroll
        for (int h = 0; h < H; h++) {
            float nm = fmaxf(m[h], cm[h]);
            float sc = expf(m[h] - nm);
            den[h] *= sc;
            acc[h] *= sc;
            m[h] = nm;
        }
        __syncthreads();   // everyone done reading raw logits
        if (t < cnt) {
#pragma unroll
            for (int h = 0; h < H; h++)
                s_w[h * 256 + t] = expf(s_w[h * 256 + t] - m[h]);
        }
        __syncthreads();   // weights visible
        for (int i = 0; i < cnt; i++) {
            int s = s_src[i];
#pragma unroll
            for (int h = 0; h < H; h++) {
                float wgt = s_w[h * 256 + i];
                den[h] += wgt;
                acc[h] += wgt * __bfloat162float(hfeat[(size_t)s * (H * 256) + h * 256 + t]);
            }
        }
    }
#pragma unroll
    for (int h = 0; h < H; h++) {
        float r = acc[h] / (den[h] + 1e-16f) + bias[h * 256 + t];
        if (RELU) r = fmaxf(r, 0.f);
        if constexpr (sizeof(OutT) == 2)
            out[(size_t)n * (H * 256) + h * 256 + t] = __float2bfloat16(r);
        else
            out[(size_t)n * (H * 256) + h * 256 + t] = r;
    }
}

// ---------------- pooling: deterministic segmented reduction ----------------
__device__ __forceinline__ int lower_bound_batch(const int* __restrict__ batch, int key) {
    int lo = 0, hi = NN;
    while (lo < hi) {
        int mid = (lo + hi) >> 1;
        if (batch[mid] < key) lo = mid + 1; else hi = mid;
    }
    return lo;
}

__global__ __launch_bounds__(256)
void pool_partial(const float* __restrict__ out2, const int* __restrict__ batch,
                  float* __restrict__ partial, float* __restrict__ cnts) {
    const int g = blockIdx.x, c = blockIdx.y, t = threadIdx.x;
    const int s = lower_bound_batch(batch, g);
    const int e = lower_bound_batch(batch, g + 1);
    float acc = 0.f;
    for (int n = s + c; n < e; n += PCH) acc += out2[(size_t)n * 256 + t];
    partial[((size_t)g * PCH + c) * 256 + t] = acc;
    if (t == 0 && c == 0) cnts[g] = (float)(e - s);
}

// ---------------- MLP head + softmax (folds 8-way pool reduction) ----------------
__global__ __launch_bounds__(256)
void head_kernel(const float* __restrict__ phy, const float* __restrict__ partial,
                 const float* __restrict__ cnts,
                 const float* __restrict__ w11, const float* __restrict__ b11,
                 const float* __restrict__ w12, const float* __restrict__ b12,
                 const float* __restrict__ w21, const float* __restrict__ b21,
                 const float* __restrict__ w22, const float* __restrict__ b22,
                 float* __restrict__ out) {
    int g = blockIdx.x, t = threadIdx.x;
    __shared__ float ph[188];
    __shared__ float z[384];
    __shared__ float mid[128];
    __shared__ float t1[192];
    __shared__ float lg[2];
    if (t < 188) ph[t] = phy[g * 188 + t];
    {
        float s = 0.f;
#pragma unroll
        for (int c = 0; c < PCH; c++) s += partial[((size_t)g * PCH + c) * 256 + t];
        z[t] = s / fmaxf(cnts[g], 1.0f);
    }
    __syncthreads();
    if (t < 128) {
        float s = b11[t];
        for (int k = 0; k < 188; k++) s += ph[k] * w11[k * 128 + t];
        mid[t] = fmaxf(s, 0.f);
    }
    __syncthreads();
    if (t < 128) {
        float s = b12[t];
        for (int k = 0; k < 128; k++) s += mid[k] * w12[k * 128 + t];
        z[256 + t] = fmaxf(s, 0.f);
    }
    __syncthreads();
    if (t < 192) {
        float s = b21[t];
        for (int k = 0; k < 384; k++) s += z[k] * w21[k * 192 + t];
        t1[t] = fmaxf(s, 0.f);
    }
    __syncthreads();
    if (t < 2) {
        float s = b22[t];
        for (int k = 0; k < 192; k++) s += t1[k] * w22[k * 2 + t];
        lg[t] = s;
    }
    __syncthreads();
    if (t == 0) {
        float mx = fmaxf(lg[0], lg[1]);
        float e0 = expf(lg[0] - mx), e1 = expf(lg[1] - mx);
        float d = e0 + e1;
        out[g * 2 + 0] = e0 / d;
        out[g * 2 + 1] = e1 / d;
    }
}

extern "C" void kernel_launch(void* const* d_in, const int* in_sizes, int n_in,
                              void* d_out, int out_size, void* d_ws, size_t ws_size,
                              hipStream_t stream) {
    const float* x       = (const float*)d_in[0];
    const int*   ei      = (const int*)  d_in[1];
    const float* phy     = (const float*)d_in[2];
    const int*   batch   = (const int*)  d_in[3];
    const float* W1      = (const float*)d_in[4];
    const float* a_src1  = (const float*)d_in[5];
    const float* a_dst1  = (const float*)d_in[6];
    const float* b1      = (const float*)d_in[7];
    const float* W2      = (const float*)d_in[8];
    const float* a_src2  = (const float*)d_in[9];
    const float* a_dst2  = (const float*)d_in[10];
    const float* b2      = (const float*)d_in[11];
    const float* fc1_w1  = (const float*)d_in[12];
    const float* fc1_b1  = (const float*)d_in[13];
    const float* fc1_w2  = (const float*)d_in[14];
    const float* fc1_b2  = (const float*)d_in[15];
    const float* fc2_w1  = (const float*)d_in[16];
    const float* fc2_b1  = (const float*)d_in[17];
    const float* fc2_w2  = (const float*)d_in[18];
    const float* fc2_b2  = (const float*)d_in[19];
    float* out = (float*)d_out;

    char* base = (char*)d_ws;
    size_t o = 0;
    auto alloc = [&](size_t bytes) { size_t r = o; o += (bytes + 255) & ~255ULL; return r; };

    size_t o_xb   = alloc((size_t)NP * K1P * 2);     // reused for h2b/out2 after GEMM1
    size_t o_w1t  = alloc((size_t)768 * K1P * 2);
    size_t o_w2t  = alloc((size_t)256 * 768 * 2);
    size_t o_h1b  = alloc((size_t)NP * 768 * 2);
    size_t o_hob  = alloc((size_t)NP * 768 * 2);
    size_t o_es1  = alloc((size_t)NN * 3 * 4);
    size_t o_ed1  = alloc((size_t)NN * 3 * 4);
    size_t o_es2  = alloc((size_t)NN * 4);
    size_t o_ed2  = alloc((size_t)NN * 4);
    size_t o_deg  = alloc((size_t)(NN + 1) * 4);
    size_t o_off  = alloc((size_t)(NN + 1) * 4);
    size_t o_cur  = alloc((size_t)NN * 4);
    size_t o_csr  = alloc((size_t)EL * 4);
    size_t o_part = alloc((size_t)NG * PCH * 256 * 4);
    size_t o_cnts = alloc((size_t)NG * 4);

    __hip_bfloat16* xb   = (__hip_bfloat16*)(base + o_xb);
    __hip_bfloat16* w1t  = (__hip_bfloat16*)(base + o_w1t);
    __hip_bfloat16* w2t  = (__hip_bfloat16*)(base + o_w2t);
    __hip_bfloat16* h1b  = (__hip_bfloat16*)(base + o_h1b);
    __hip_bfloat16* hob  = (__hip_bfloat16*)(base + o_hob);
    __hip_bfloat16* h2b  = (__hip_bfloat16*)(base + o_xb);
    float*          out2 = (float*)(base + o_xb + (size_t)24 * 1024 * 1024);
    float* es1   = (float*)(base + o_es1);
    float* ed1   = (float*)(base + o_ed1);
    float* es2   = (float*)(base + o_es2);
    float* ed2   = (float*)(base + o_ed2);
    int*   deg   = (int*)(base + o_deg);
    int*   offs  = (int*)(base + o_off);
    int*   cur   = (int*)(base + o_cur);
    int*   csr   = (int*)(base + o_csr);
    float* part  = (float*)(base + o_part);
    float* cnts  = (float*)(base + o_cnts);

    hipMemsetAsync(deg, 0, (size_t)(NN + 1) * 4, stream);
    hipMemsetAsync(cur, 0, (size_t)NN * 4, stream);
    hipMemsetAsync(hob + (size_t)NN * 768, 0, (size_t)(NP - NN) * 768 * 2, stream);

    convert_x<<<(NP * (K1P / 8) + 255) / 256, 256, 0, stream>>>(x, xb);
    convert_wT<<<(768 * K1P + 255) / 256, 256, 0, stream>>>(W1, w1t, INDIM, 768, K1P);
    convert_wT<<<(256 * 768 + 255) / 256, 256, 0, stream>>>(W2, w2t, 768, 256, 768);

    hist_kernel<<<(EL + 255) / 256, 256, 0, stream>>>(ei, deg);
    scan_kernel<<<1, 1024, 0, stream>>>(deg, offs);
    fill_kernel<<<(EL + 255) / 256, 256, 0, stream>>>(ei, offs, cur, csr);

    mfma_gemm<__hip_bfloat16><<<dim3(6, 157), 256, 0, stream>>>(xb, w1t, h1b, NN, 768, K1P);
    compute_e<3><<<(NN + 3) / 4, 256, 0, stream>>>(h1b, a_src1, a_dst1, es1, ed1, NN);
    gat_aggregate<3, true, __hip_bfloat16><<<NN, 256, 0, stream>>>(h1b, es1, ed1, offs, csr, b1, hob);

    mfma_gemm<__hip_bfloat16><<<dim3(2, 157), 256, 0, stream>>>(hob, w2t, h2b, NN, 256, 768);
    compute_e<1><<<(NN + 3) / 4, 256, 0, stream>>>(h2b, a_src2, a_dst2, es2, ed2, NN);
    gat_aggregate<1, false, float><<<NN, 256, 0, stream>>>(h2b, es2, ed2, offs, csr, b2, out2);

    pool_partial<<<dim3(NG, PCH), 256, 0, stream>>>(out2, batch, part, cnts);
    head_kernel<<<NG, 256, 0, stream>>>(phy, part, cnts,
                                        fc1_w1, fc1_b1, fc1_w2, fc1_b2,
                                        fc2_w1, fc2_b1, fc2_w2, fc2_b2, out);
}

// Round 4
// 313.933 us; speedup vs baseline: 3.9883x; 1.1166x over previous
//
#include <hip/hip_runtime.h>
#include <hip/hip_bf16.h>
#include <math.h>

#define NN    20000
#define NP    20096          // 157*128 padded rows
#define E0    160000
#define EL    180000
#define NG    64
#define INDIM 1304
#define K1P   1312           // K padded to multiple of 32
#define NEG_SLOPE 0.2f
#define PCH   8              // pool chunks per graph

typedef __bf16 bf16x8 __attribute__((ext_vector_type(8)));
typedef __bf16 bf16x4 __attribute__((ext_vector_type(4)));
typedef float  f32x4  __attribute__((ext_vector_type(4)));

__device__ __forceinline__ void gload16(const void* g, void* l) {
    __builtin_amdgcn_global_load_lds(
        (const __attribute__((address_space(1))) void*)g,
        (__attribute__((address_space(3))) void*)l, 16, 0, 0);
}

// ---------------- bf16 MFMA GEMM: C[M,N] = A[Mp,K] @ Bt[N,K]^T ----------------
// m97 structure + XCD-aware bijective swizzle (m204): same-A-panel blocks land
// on the same XCD's L2 -> A fetched once per XCD chunk instead of per block.
template<typename CT>
__global__ __launch_bounds__(256)
void mfma_gemm(const __hip_bfloat16* __restrict__ A,   // [Mp][K] row-major (pad rows zeroed)
               const __hip_bfloat16* __restrict__ Bt,  // [N][K]  row-major (= B transposed)
               CT* __restrict__ C,                     // [M][N]  row-major
               int M, int N, int K, int NX) {          // K%32==0; N%128==0; NX=N/128
    __shared__ __hip_bfloat16 As[128 * 32];
    __shared__ __hip_bfloat16 Bs[128 * 32];
    const int t = threadIdx.x;
    const int w = t >> 6;
    const int l = t & 63;

    // bijective XCD swizzle: xcd = bid%8 gets a contiguous chunk of m-major logical ids
    const int nwg = gridDim.x;
    const int q = nwg >> 3, r = nwg & 7;
    const int xcd = blockIdx.x & 7, idx = blockIdx.x >> 3;
    const int logical = (xcd < r ? xcd * (q + 1) : r * (q + 1) + (xcd - r) * q) + idx;
    const int bm = (logical / NX) * 128;
    const int bn = (logical % NX) * 128;

    const int wm = (w >> 1) * 64;
    const int wn = (w & 1) * 64;

    f32x4 acc[4][4];
#pragma unroll
    for (int i = 0; i < 4; i++)
#pragma unroll
        for (int j = 0; j < 4; j++) acc[i][j] = (f32x4){0.f, 0.f, 0.f, 0.f};

    const int sr = t >> 2;
    const int sc = (t & 3) * 8;
    const __hip_bfloat16* a0 = A  + (size_t)(bm + sr)      * K + sc;
    const __hip_bfloat16* a1 = A  + (size_t)(bm + 64 + sr) * K + sc;
    const __hip_bfloat16* b0 = Bt + (size_t)(bn + sr)      * K + sc;
    const __hip_bfloat16* b1 = Bt + (size_t)(bn + 64 + sr) * K + sc;
    char* asw0 = (char*)As + w * 1024;
    char* asw1 = (char*)As + 4096 + w * 1024;
    char* bsw0 = (char*)Bs + w * 1024;
    char* bsw1 = (char*)Bs + 4096 + w * 1024;

    const int fr = l & 15;
    const int fq = l >> 4;

    for (int k0 = 0; k0 < K; k0 += 32) {
        gload16(a0 + k0, asw0);
        gload16(a1 + k0, asw1);
        gload16(b0 + k0, bsw0);
        gload16(b1 + k0, bsw1);
        __syncthreads();
        bf16x8 av[4], bv[4];
#pragma unroll
        for (int i = 0; i < 4; i++)
            av[i] = *(const bf16x8*)&As[(wm + i * 16 + fr) * 32 + fq * 8];
#pragma unroll
        for (int j = 0; j < 4; j++)
            bv[j] = *(const bf16x8*)&Bs[(wn + j * 16 + fr) * 32 + fq * 8];
#pragma unroll
        for (int i = 0; i < 4; i++)
#pragma unroll
            for (int j = 0; j < 4; j++)
                acc[i][j] = __builtin_amdgcn_mfma_f32_16x16x32_bf16(av[i], bv[j], acc[i][j], 0, 0, 0);
        __syncthreads();
    }

#pragma unroll
    for (int i = 0; i < 4; i++) {
#pragma unroll
        for (int j = 0; j < 4; j++) {
#pragma unroll
            for (int r2 = 0; r2 < 4; r2++) {
                int row = bm + wm + i * 16 + fq * 4 + r2;
                int col = bn + wn + j * 16 + fr;
                if (row < M) {
                    if constexpr (sizeof(CT) == 2)
                        C[(size_t)row * N + col] = __float2bfloat16(acc[i][j][r2]);
                    else
                        C[(size_t)row * N + col] = acc[i][j][r2];
                }
            }
        }
    }
}

// ---------------- fp32 -> bf16 conversions ----------------
__global__ __launch_bounds__(256)
void convert_x(const float* __restrict__ X, __hip_bfloat16* __restrict__ Xb) {
    int idx = blockIdx.x * 256 + threadIdx.x;
    const int nb = K1P / 8;
    if (idx >= NP * nb) return;
    int row = idx / nb;
    int cb = (idx - row * nb) * 8;
    union { __hip_bfloat16 h[8]; float4 f4; } u;
    if (row < NN && cb + 8 <= INDIM) {
        const float4* p = (const float4*)(X + (size_t)row * INDIM + cb);
        float4 u0 = p[0], u1 = p[1];
        u.h[0] = __float2bfloat16(u0.x); u.h[1] = __float2bfloat16(u0.y);
        u.h[2] = __float2bfloat16(u0.z); u.h[3] = __float2bfloat16(u0.w);
        u.h[4] = __float2bfloat16(u1.x); u.h[5] = __float2bfloat16(u1.y);
        u.h[6] = __float2bfloat16(u1.z); u.h[7] = __float2bfloat16(u1.w);
    } else {
#pragma unroll
        for (int e = 0; e < 8; e++) {
            float f = (row < NN && cb + e < INDIM) ? X[(size_t)row * INDIM + cb + e] : 0.f;
            u.h[e] = __float2bfloat16(f);
        }
    }
    *(float4*)(Xb + (size_t)row * K1P + cb) = u.f4;
}

__global__ __launch_bounds__(256)
void convert_wT(const float* __restrict__ W, __hip_bfloat16* __restrict__ Wt,
                int K, int N, int Kp) {
    int idx = blockIdx.x * 256 + threadIdx.x;
    if (idx >= N * Kp) return;
    int n = idx / Kp, k = idx - n * Kp;
    float f = (k < K) ? W[(size_t)k * N + n] : 0.f;
    Wt[idx] = __float2bfloat16(f);
}

// ---------------- attention logits: one wave per node ----------------
template<int H>
__global__ __launch_bounds__(256)
void compute_e(const __hip_bfloat16* __restrict__ hfeat, const float* __restrict__ a_src,
               const float* __restrict__ a_dst, float* __restrict__ esrc,
               float* __restrict__ edst, int N) {
    const int wv = threadIdx.x >> 6, lane = threadIdx.x & 63;
    const int n = blockIdx.x * 4 + wv;
    if (n >= N) return;
#pragma unroll
    for (int hd = 0; hd < H; hd++) {
        bf16x4 hv = *(const bf16x4*)(hfeat + (size_t)n * (H * 256) + hd * 256 + lane * 4);
        float ps = 0.f, pd = 0.f;
#pragma unroll
        for (int e = 0; e < 4; e++) {
            float f = (float)hv[e];
            ps += f * a_src[hd * 256 + lane * 4 + e];
            pd += f * a_dst[hd * 256 + lane * 4 + e];
        }
#pragma unroll
        for (int o = 32; o > 0; o >>= 1) {
            ps += __shfl_down(ps, o, 64);
            pd += __shfl_down(pd, o, 64);
        }
        if (lane == 0) {
            esrc[n * H + hd] = ps;
            edst[n * H + hd] = pd;
        }
    }
}

// ---------------- CSR build ----------------
__global__ void hist_kernel(const int* __restrict__ ei, int* __restrict__ deg) {
    int e = blockIdx.x * 256 + threadIdx.x;
    if (e >= EL) return;
    int d = (e < E0) ? ei[E0 + e] : (e - E0);
    atomicAdd(&deg[d], 1);
}

__global__ __launch_bounds__(1024)
void scan_kernel(const int* __restrict__ deg, int* __restrict__ off) {
    __shared__ int wsum[16];
    __shared__ int carry_s;
    int t = threadIdx.x, lane = t & 63, wv = t >> 6;
    if (t == 0) { carry_s = 0; off[0] = 0; }
    __syncthreads();
    for (int base = 0; base < NN; base += 1024) {
        int i = base + t;
        int v = (i < NN) ? deg[i] : 0;
        int x = v;
#pragma unroll
        for (int o = 1; o < 64; o <<= 1) {
            int y = __shfl_up(x, o, 64);
            if (lane >= o) x += y;
        }
        if (lane == 63) wsum[wv] = x;
        __syncthreads();
        if (wv == 0 && lane < 16) {
            int s = wsum[lane];
#pragma unroll
            for (int o = 1; o < 16; o <<= 1) {
                int y = __shfl_up(s, o, 64);
                if (lane >= o) s += y;
            }
            wsum[lane] = s;
        }
        __syncthreads();
        int woff = (wv == 0) ? 0 : wsum[wv - 1];
        int total = wsum[15];
        if (i < NN) off[i + 1] = carry_s + woff + x;
        __syncthreads();
        if (t == 0) carry_s += total;
        __syncthreads();
    }
}

__global__ void fill_kernel(const int* __restrict__ ei, const int* __restrict__ off,
                            int* __restrict__ cur, int* __restrict__ csr) {
    int e = blockIdx.x * 256 + threadIdx.x;
    if (e >= EL) return;
    int d = (e < E0) ? ei[E0 + e] : (e - E0);
    int s = (e < E0) ? ei[e] : (e - E0);
    int pos = off[d] + atomicAdd(&cur[d], 1);
    csr[pos] = s;
}

// ---------------- GAT aggregation: one WAVE per node, no LDS, no barriers ----------------
// Lane owns 4 channels per head; edge logits/weights broadcast via shuffles.
template<int H, bool RELU, typename OutT>
__global__ __launch_bounds__(256)
void gat_aggregate(const __hip_bfloat16* __restrict__ hfeat,  // [N][H*256] bf16
                   const float* __restrict__ esrc,
                   const float* __restrict__ edst,
                   const int* __restrict__ off, const int* __restrict__ csr,
                   const float* __restrict__ bias,
                   OutT* __restrict__ out, int N) {
    const int wv = threadIdx.x >> 6, lane = threadIdx.x & 63;
    const int n = blockIdx.x * 4 + wv;
    if (n >= N) return;
    const int beg = off[n];
    const int deg = off[n + 1] - beg;

    float ed[H], m[H], den[H];
    f32x4 acc[H];
#pragma unroll
    for (int h = 0; h < H; h++) {
        ed[h] = edst[n * H + h];
        m[h] = -INFINITY;
        den[h] = 0.f;
        acc[h] = (f32x4){0.f, 0.f, 0.f, 0.f};
    }

    for (int base = 0; base < deg; base += 64) {
        const int i = base + lane;
        int s = 0;
        float lg[H];
        if (i < deg) {
            s = csr[beg + i];
#pragma unroll
            for (int h = 0; h < H; h++) {
                float v = esrc[s * H + h] + ed[h];
                lg[h] = (v >= 0.f) ? v : NEG_SLOPE * v;
            }
        } else {
#pragma unroll
            for (int h = 0; h < H; h++) lg[h] = -INFINITY;
        }
        // wave max per head
        float cm[H];
#pragma unroll
        for (int h = 0; h < H; h++) {
            cm[h] = lg[h];
#pragma unroll
            for (int o = 1; o < 64; o <<= 1)
                cm[h] = fmaxf(cm[h], __shfl_xor(cm[h], o, 64));
        }
        // online rescale
#pragma unroll
        for (int h = 0; h < H; h++) {
            float nm = fmaxf(m[h], cm[h]);
            float sc = expf(m[h] - nm);   // m=-inf first chunk -> 0
            den[h] *= sc;
#pragma unroll
            for (int e = 0; e < 4; e++) acc[h][e] *= sc;
            m[h] = nm;
        }
        float wgt[H];
#pragma unroll
        for (int h = 0; h < H; h++) {
            wgt[h] = (i < deg) ? expf(lg[h] - m[h]) : 0.f;
            den[h] += wgt[h];   // lane-partial denominator
        }
        const int cnt = min(64, deg - base);
        for (int j = 0; j < cnt; j++) {
            int sj = __shfl(s, j, 64);
#pragma unroll
            for (int h = 0; h < H; h++) {
                float wj = __shfl(wgt[h], j, 64);
                bf16x4 hv = *(const bf16x4*)(hfeat + (size_t)sj * (H * 256) + h * 256 + 4 * lane);
#pragma unroll
                for (int e = 0; e < 4; e++) acc[h][e] += wj * (float)hv[e];
            }
        }
    }
    // reduce lane-partial denominators
#pragma unroll
    for (int h = 0; h < H; h++) {
#pragma unroll
        for (int o = 1; o < 64; o <<= 1) den[h] += __shfl_xor(den[h], o, 64);
    }
#pragma unroll
    for (int h = 0; h < H; h++) {
        float inv = 1.f / (den[h] + 1e-16f);
        if constexpr (sizeof(OutT) == 2) {
            bf16x4 r;
#pragma unroll
            for (int e = 0; e < 4; e++) {
                float f = acc[h][e] * inv + bias[h * 256 + 4 * lane + e];
                if (RELU) f = fmaxf(f, 0.f);
                r[e] = (__bf16)f;
            }
            *(bf16x4*)((__hip_bfloat16*)out + (size_t)n * (H * 256) + h * 256 + 4 * lane) = r;
        } else {
            float4 r;
            float* rp = &r.x;
#pragma unroll
            for (int e = 0; e < 4; e++) {
                float f = acc[h][e] * inv + bias[h * 256 + 4 * lane + e];
                if (RELU) f = fmaxf(f, 0.f);
                rp[e] = f;
            }
            *(float4*)((float*)out + (size_t)n * (H * 256) + h * 256 + 4 * lane) = r;
        }
    }
}

// ---------------- pooling: deterministic segmented reduction ----------------
__device__ __forceinline__ int lower_bound_batch(const int* __restrict__ batch, int key) {
    int lo = 0, hi = NN;
    while (lo < hi) {
        int mid = (lo + hi) >> 1;
        if (batch[mid] < key) lo = mid + 1; else hi = mid;
    }
    return lo;
}

__global__ __launch_bounds__(256)
void pool_partial(const float* __restrict__ out2, const int* __restrict__ batch,
                  float* __restrict__ partial, float* __restrict__ cnts) {
    const int g = blockIdx.x, c = blockIdx.y, t = threadIdx.x;
    const int s = lower_bound_batch(batch, g);
    const int e = lower_bound_batch(batch, g + 1);
    float acc = 0.f;
    for (int n = s + c; n < e; n += PCH) acc += out2[(size_t)n * 256 + t];
    partial[((size_t)g * PCH + c) * 256 + t] = acc;
    if (t == 0 && c == 0) cnts[g] = (float)(e - s);
}

// ---------------- MLP head + softmax (folds 8-way pool reduction) ----------------
__global__ __launch_bounds__(256)
void head_kernel(const float* __restrict__ phy, const float* __restrict__ partial,
                 const float* __restrict__ cnts,
                 const float* __restrict__ w11, const float* __restrict__ b11,
                 const float* __restrict__ w12, const float* __restrict__ b12,
                 const float* __restrict__ w21, const float* __restrict__ b21,
                 const float* __restrict__ w22, const float* __restrict__ b22,
                 float* __restrict__ out) {
    int g = blockIdx.x, t = threadIdx.x;
    __shared__ float ph[188];
    __shared__ float z[384];
    __shared__ float mid[128];
    __shared__ float t1[192];
    __shared__ float lg[2];
    if (t < 188) ph[t] = phy[g * 188 + t];
    {
        float s = 0.f;
#pragma unroll
        for (int c = 0; c < PCH; c++) s += partial[((size_t)g * PCH + c) * 256 + t];
        z[t] = s / fmaxf(cnts[g], 1.0f);
    }
    __syncthreads();
    if (t < 128) {
        float s = b11[t];
        for (int k = 0; k < 188; k++) s += ph[k] * w11[k * 128 + t];
        mid[t] = fmaxf(s, 0.f);
    }
    __syncthreads();
    if (t < 128) {
        float s = b12[t];
        for (int k = 0; k < 128; k++) s += mid[k] * w12[k * 128 + t];
        z[256 + t] = fmaxf(s, 0.f);
    }
    __syncthreads();
    if (t < 192) {
        float s = b21[t];
        for (int k = 0; k < 384; k++) s += z[k] * w21[k * 192 + t];
        t1[t] = fmaxf(s, 0.f);
    }
    __syncthreads();
    if (t < 2) {
        float s = b22[t];
        for (int k = 0; k < 192; k++) s += t1[k] * w22[k * 2 + t];
        lg[t] = s;
    }
    __syncthreads();
    if (t == 0) {
        float mx = fmaxf(lg[0], lg[1]);
        float e0 = expf(lg[0] - mx), e1 = expf(lg[1] - mx);
        float d = e0 + e1;
        out[g * 2 + 0] = e0 / d;
        out[g * 2 + 1] = e1 / d;
    }
}

extern "C" void kernel_launch(void* const* d_in, const int* in_sizes, int n_in,
                              void* d_out, int out_size, void* d_ws, size_t ws_size,
                              hipStream_t stream) {
    const float* x       = (const float*)d_in[0];
    const int*   ei      = (const int*)  d_in[1];
    const float* phy     = (const float*)d_in[2];
    const int*   batch   = (const int*)  d_in[3];
    const float* W1      = (const float*)d_in[4];
    const float* a_src1  = (const float*)d_in[5];
    const float* a_dst1  = (const float*)d_in[6];
    const float* b1      = (const float*)d_in[7];
    const float* W2      = (const float*)d_in[8];
    const float* a_src2  = (const float*)d_in[9];
    const float* a_dst2  = (const float*)d_in[10];
    const float* b2      = (const float*)d_in[11];
    const float* fc1_w1  = (const float*)d_in[12];
    const float* fc1_b1  = (const float*)d_in[13];
    const float* fc1_w2  = (const float*)d_in[14];
    const float* fc1_b2  = (const float*)d_in[15];
    const float* fc2_w1  = (const float*)d_in[16];
    const float* fc2_b1  = (const float*)d_in[17];
    const float* fc2_w2  = (const float*)d_in[18];
    const float* fc2_b2  = (const float*)d_in[19];
    float* out = (float*)d_out;

    char* base = (char*)d_ws;
    size_t o = 0;
    auto alloc = [&](size_t bytes) { size_t r = o; o += (bytes + 255) & ~255ULL; return r; };

    size_t o_xb   = alloc((size_t)NP * K1P * 2);     // reused for h2b/out2 after GEMM1
    size_t o_w1t  = alloc((size_t)768 * K1P * 2);
    size_t o_w2t  = alloc((size_t)256 * 768 * 2);
    size_t o_h1b  = alloc((size_t)NP * 768 * 2);
    size_t o_hob  = alloc((size_t)NP * 768 * 2);
    size_t o_es1  = alloc((size_t)NN * 3 * 4);
    size_t o_ed1  = alloc((size_t)NN * 3 * 4);
    size_t o_es2  = alloc((size_t)NN * 4);
    size_t o_ed2  = alloc((size_t)NN * 4);
    size_t o_deg  = alloc((size_t)(NN + 1) * 4);
    size_t o_off  = alloc((size_t)(NN + 1) * 4);
    size_t o_cur  = alloc((size_t)NN * 4);
    size_t o_csr  = alloc((size_t)EL * 4);
    size_t o_part = alloc((size_t)NG * PCH * 256 * 4);
    size_t o_cnts = alloc((size_t)NG * 4);

    __hip_bfloat16* xb   = (__hip_bfloat16*)(base + o_xb);
    __hip_bfloat16* w1t  = (__hip_bfloat16*)(base + o_w1t);
    __hip_bfloat16* w2t  = (__hip_bfloat16*)(base + o_w2t);
    __hip_bfloat16* h1b  = (__hip_bfloat16*)(base + o_h1b);
    __hip_bfloat16* hob  = (__hip_bfloat16*)(base + o_hob);
    __hip_bfloat16* h2b  = (__hip_bfloat16*)(base + o_xb);
    float*          out2 = (float*)(base + o_xb + (size_t)24 * 1024 * 1024);
    float* es1   = (float*)(base + o_es1);
    float* ed1   = (float*)(base + o_ed1);
    float* es2   = (float*)(base + o_es2);
    float* ed2   = (float*)(base + o_ed2);
    int*   deg   = (int*)(base + o_deg);
    int*   offs  = (int*)(base + o_off);
    int*   cur   = (int*)(base + o_cur);
    int*   csr   = (int*)(base + o_csr);
    float* part  = (float*)(base + o_part);
    float* cnts  = (float*)(base + o_cnts);

    hipMemsetAsync(deg, 0, (size_t)(NN + 1) * 4, stream);
    hipMemsetAsync(cur, 0, (size_t)NN * 4, stream);
    hipMemsetAsync(hob + (size_t)NN * 768, 0, (size_t)(NP - NN) * 768 * 2, stream);

    convert_x<<<(NP * (K1P / 8) + 255) / 256, 256, 0, stream>>>(x, xb);
    convert_wT<<<(768 * K1P + 255) / 256, 256, 0, stream>>>(W1, w1t, INDIM, 768, K1P);
    convert_wT<<<(256 * 768 + 255) / 256, 256, 0, stream>>>(W2, w2t, 768, 256, 768);

    hist_kernel<<<(EL + 255) / 256, 256, 0, stream>>>(ei, deg);
    scan_kernel<<<1, 1024, 0, stream>>>(deg, offs);
    fill_kernel<<<(EL + 255) / 256, 256, 0, stream>>>(ei, offs, cur, csr);

    mfma_gemm<__hip_bfloat16><<<6 * 157, 256, 0, stream>>>(xb, w1t, h1b, NN, 768, K1P, 6);
    compute_e<3><<<(NN + 3) / 4, 256, 0, stream>>>(h1b, a_src1, a_dst1, es1, ed1, NN);
    gat_aggregate<3, true, __hip_bfloat16><<<(NN + 3) / 4, 256, 0, stream>>>(h1b, es1, ed1, offs, csr, b1, hob, NN);

    mfma_gemm<__hip_bfloat16><<<2 * 157, 256, 0, stream>>>(hob, w2t, h2b, NN, 256, 768, 2);
    compute_e<1><<<(NN + 3) / 4, 256, 0, stream>>>(h2b, a_src2, a_dst2, es2, ed2, NN);
    gat_aggregate<1, false, float><<<(NN + 3) / 4, 256, 0, stream>>>(h2b, es2, ed2, offs, csr, b2, out2, NN);

    pool_partial<<<dim3(NG, PCH), 256, 0, stream>>>(out2, batch, part, cnts);
    head_kernel<<<NG, 256, 0, stream>>>(phy, part, cnts,
                                        fc1_w1, fc1_b1, fc1_w2, fc1_b2,
                                        fc2_w1, fc2_b1, fc2_w2, fc2_b2, out);
}

// Round 5
// 280.443 us; speedup vs baseline: 4.4646x; 1.1194x over previous
//
#include <hip/hip_runtime.h>
#include <hip/hip_bf16.h>
#include <math.h>

#define NN    20000
#define MP1   20224          // 79*256 padded rows for gemm1
#define NP    20096          // 157*128 padded rows for gemm2 A
#define E0    160000
#define EL    180000
#define NG    64
#define INDIM 1304
#define K1P   1344           // K padded to multiple of 64 (21 K-tiles)
#define GNT   21             // K1P/64
#define GNX   3              // 768/256
#define GMB   79             // M blocks
#define NEG_SLOPE 0.2f
#define PCH   8

typedef __bf16 bf16x8 __attribute__((ext_vector_type(8)));
typedef __bf16 bf16x4 __attribute__((ext_vector_type(4)));
typedef float  f32x4  __attribute__((ext_vector_type(4)));

__device__ __forceinline__ void gload16(const void* g, void* l) {
    __builtin_amdgcn_global_load_lds(
        (const __attribute__((address_space(1))) void*)g,
        (__attribute__((address_space(3))) void*)l, 16, 0, 0);
}

#define BAR()  { __builtin_amdgcn_s_barrier(); asm volatile("" ::: "memory"); }
#define VMW(n) { asm volatile("s_waitcnt vmcnt(" #n ")" ::: "memory"); __builtin_amdgcn_sched_barrier(0); }

// stage one 16-KB A half (mh) of K-tile kt: linear LDS dest, inverse-swizzled global src
__device__ __forceinline__ void stA(const __hip_bfloat16* __restrict__ A, int bm, int kt, int mh,
                                    char* abuf, int w, int l) {
#pragma unroll
    for (int u = 0; u < 2; u++) {
        int rl = (w << 3) + (l >> 3);            // row_local 0..63
        int lrow = u * 128 + mh * 64 + rl;       // row in 256-row tile
        int skb = ((l & 7) << 4) ^ ((rl & 7) << 4);
        const char* g = (const char*)(A + (size_t)(bm + lrow) * K1P + kt * 64) + skb;
        gload16(g, abuf + (u * 128 + mh * 64) * 128 + (w << 10));
    }
}

// stage one 16-KB B region (nh: rows with (r&63)>>5 == nh), 4 chunks of 32 rows
__device__ __forceinline__ void stB(const __hip_bfloat16* __restrict__ Bt, int bn, int kt, int nh,
                                    char* bbuf, int w, int l) {
#pragma unroll
    for (int u = 0; u < 2; u++) {
        int c = u * 2 + (w >> 2);
        int row0 = c * 64 + nh * 32;
        int rl = ((w & 3) << 3) + (l >> 3);      // 0..31
        int skb = ((l & 7) << 4) ^ ((rl & 7) << 4);
        const char* g = (const char*)(Bt + (size_t)(bn + row0 + rl) * K1P + kt * 64) + skb;
        gload16(g, bbuf + row0 * 128 + ((w & 3) << 10));
    }
}

// ---------------- 256x256 8-phase bf16 MFMA GEMM (GEMM1 only) ----------------
// C[M,768] = A[MP1,K1P] @ Bt[768,K1P]^T
__global__ __launch_bounds__(512)
void gemm256(const __hip_bfloat16* __restrict__ A,
             const __hip_bfloat16* __restrict__ Bt,
             __hip_bfloat16* __restrict__ C, int M) {
    __shared__ char lds[131072];   // buf b: A @ b*65536, B @ b*65536+32768
    const int t = threadIdx.x;
    const int w = t >> 6, l = t & 63;
    const int wm = w >> 2, wn = w & 3;           // 2 x 4 waves, each 128x64 output
    const int fr = l & 15, fq = l >> 4;
    const int amask = (fr & 7) << 4;             // read-side swizzle mask

    // bijective XCD swizzle (m204), m-major logical order
    const int nwg = GMB * GNX;
    const int q8 = nwg >> 3, r8 = nwg & 7;
    const int xcd = blockIdx.x & 7, sub = blockIdx.x >> 3;
    const int logical = (xcd < r8 ? xcd * (q8 + 1) : r8 * (q8 + 1) + (xcd - r8) * q8) + sub;
    const int bm = (logical / GNX) * 256;
    const int bn = (logical % GNX) * 256;

    f32x4 acc[8][4];
#pragma unroll
    for (int i = 0; i < 8; i++)
#pragma unroll
        for (int j = 0; j < 4; j++) acc[i][j] = (f32x4){0.f, 0.f, 0.f, 0.f};

    char* A0 = lds;            char* B0 = lds + 32768;
    char* A1 = lds + 65536;    char* B1 = lds + 98304;

    // prologue: 6 pieces in steady-state issue order
    stA(A, bm, 0, 0, A0, w, l);
    stB(Bt, bn, 0, 0, B0, w, l);
    stA(A, bm, 0, 1, A0, w, l);
    stB(Bt, bn, 0, 1, B0, w, l);
    stA(A, bm, 1, 0, A1, w, l);
    stB(Bt, bn, 1, 0, B1, w, l);
    VMW(8);
    BAR();

    for (int kt = 0; kt < GNT; kt++) {
        char* Ab = lds + (kt & 1) * 65536;
        char* Bb = Ab + 32768;
        char* An = lds + ((kt + 1) & 1) * 65536;
        char* Bn = An + 32768;
        bf16x8 a_c[4][2], b_c0[2][2], b_c1[2][2];

        // ---- q0: read A(mh0)+B(nh0), stage A(mh1,kt+1), MFMA quad(0,0) ----
#pragma unroll
        for (int im = 0; im < 4; im++)
#pragma unroll
            for (int kk = 0; kk < 2; kk++)
                a_c[im][kk] = *(const bf16x8*)(Ab + (wm * 128 + im * 16 + fr) * 128 + ((kk * 64 + fq * 16) ^ amask));
#pragma unroll
        for (int jn = 0; jn < 2; jn++)
#pragma unroll
            for (int kk = 0; kk < 2; kk++)
                b_c0[jn][kk] = *(const bf16x8*)(Bb + (wn * 64 + jn * 16 + fr) * 128 + ((kk * 64 + fq * 16) ^ amask));
        if (kt + 1 < GNT) stA(A, bm, kt + 1, 1, An, w, l);
        BAR();
        __builtin_amdgcn_s_setprio(1);
#pragma unroll
        for (int im = 0; im < 4; im++)
#pragma unroll
            for (int jn = 0; jn < 2; jn++)
#pragma unroll
                for (int kk = 0; kk < 2; kk++)
                    acc[im][jn] = __builtin_amdgcn_mfma_f32_16x16x32_bf16(a_c[im][kk], b_c0[jn][kk], acc[im][jn], 0, 0, 0);
        __builtin_amdgcn_s_setprio(0);
        if (kt == GNT - 1) { VMW(0); } else { VMW(6); }
        BAR();

        // ---- q1: read B(nh1), stage B(nh1,kt+1), MFMA quad(0,1) ----
#pragma unroll
        for (int jn = 0; jn < 2; jn++)
#pragma unroll
            for (int kk = 0; kk < 2; kk++)
                b_c1[jn][kk] = *(const bf16x8*)(Bb + (wn * 64 + 32 + jn * 16 + fr) * 128 + ((kk * 64 + fq * 16) ^ amask));
        if (kt + 1 < GNT) stB(Bt, bn, kt + 1, 1, Bn, w, l);
        BAR();
        __builtin_amdgcn_s_setprio(1);
#pragma unroll
        for (int im = 0; im < 4; im++)
#pragma unroll
            for (int jn = 0; jn < 2; jn++)
#pragma unroll
                for (int kk = 0; kk < 2; kk++)
                    acc[im][2 + jn] = __builtin_amdgcn_mfma_f32_16x16x32_bf16(a_c[im][kk], b_c1[jn][kk], acc[im][2 + jn], 0, 0, 0);
        __builtin_amdgcn_s_setprio(0);
        if (kt == GNT - 1) { VMW(2); } else { VMW(10); }
        BAR();

        // ---- q2: read A(mh1) (overwrite cache), stage A(mh0,kt+2), MFMA quad(1,0) ----
#pragma unroll
        for (int im = 0; im < 4; im++)
#pragma unroll
            for (int kk = 0; kk < 2; kk++)
                a_c[im][kk] = *(const bf16x8*)(Ab + (wm * 128 + 64 + im * 16 + fr) * 128 + ((kk * 64 + fq * 16) ^ amask));
        if (kt + 2 < GNT) stA(A, bm, kt + 2, 0, Ab, w, l);
        BAR();
        __builtin_amdgcn_s_setprio(1);
#pragma unroll
        for (int im = 0; im < 4; im++)
#pragma unroll
            for (int jn = 0; jn < 2; jn++)
#pragma unroll
                for (int kk = 0; kk < 2; kk++)
                    acc[4 + im][jn] = __builtin_amdgcn_mfma_f32_16x16x32_bf16(a_c[im][kk], b_c0[jn][kk], acc[4 + im][jn], 0, 0, 0);
        __builtin_amdgcn_s_setprio(0);
        BAR();

        // ---- q3: stage B(nh0,kt+2), MFMA quad(1,1) ----
        if (kt + 2 < GNT) stB(Bt, bn, kt + 2, 0, Bb, w, l);
        BAR();
        __builtin_amdgcn_s_setprio(1);
#pragma unroll
        for (int im = 0; im < 4; im++)
#pragma unroll
            for (int jn = 0; jn < 2; jn++)
#pragma unroll
                for (int kk = 0; kk < 2; kk++)
                    acc[4 + im][2 + jn] = __builtin_amdgcn_mfma_f32_16x16x32_bf16(a_c[im][kk], b_c1[jn][kk], acc[4 + im][2 + jn], 0, 0, 0);
        __builtin_amdgcn_s_setprio(0);
        if (kt + 2 < GNT) { VMW(8); }
        else if (kt + 2 == GNT) { VMW(4); }
        BAR();
    }

    // epilogue: C/D layout col=lane&15, row=(lane>>4)*4+reg
#pragma unroll
    for (int i = 0; i < 8; i++)
#pragma unroll
        for (int j = 0; j < 4; j++)
#pragma unroll
            for (int r = 0; r < 4; r++) {
                int row = bm + wm * 128 + i * 16 + fq * 4 + r;
                int col = bn + wn * 64 + j * 16 + fr;
                if (row < M) C[(size_t)row * 768 + col] = __float2bfloat16(acc[i][j][r]);
            }
}

// ---------------- m97-style 128x128 GEMM (GEMM2) ----------------
template<typename CT>
__global__ __launch_bounds__(256)
void mfma_gemm(const __hip_bfloat16* __restrict__ A,
               const __hip_bfloat16* __restrict__ Bt,
               CT* __restrict__ C,
               int M, int N, int K, int NX) {
    __shared__ __hip_bfloat16 As[128 * 32];
    __shared__ __hip_bfloat16 Bs[128 * 32];
    const int t = threadIdx.x;
    const int w = t >> 6;
    const int l = t & 63;

    const int nwg = gridDim.x;
    const int q = nwg >> 3, r = nwg & 7;
    const int xcd = blockIdx.x & 7, idx = blockIdx.x >> 3;
    const int logical = (xcd < r ? xcd * (q + 1) : r * (q + 1) + (xcd - r) * q) + idx;
    const int bm = (logical / NX) * 128;
    const int bn = (logical % NX) * 128;

    const int wm = (w >> 1) * 64;
    const int wn = (w & 1) * 64;

    f32x4 acc[4][4];
#pragma unroll
    for (int i = 0; i < 4; i++)
#pragma unroll
        for (int j = 0; j < 4; j++) acc[i][j] = (f32x4){0.f, 0.f, 0.f, 0.f};

    const int sr = t >> 2;
    const int sc = (t & 3) * 8;
    const __hip_bfloat16* a0 = A  + (size_t)(bm + sr)      * K + sc;
    const __hip_bfloat16* a1 = A  + (size_t)(bm + 64 + sr) * K + sc;
    const __hip_bfloat16* b0 = Bt + (size_t)(bn + sr)      * K + sc;
    const __hip_bfloat16* b1 = Bt + (size_t)(bn + 64 + sr) * K + sc;
    char* asw0 = (char*)As + w * 1024;
    char* asw1 = (char*)As + 4096 + w * 1024;
    char* bsw0 = (char*)Bs + w * 1024;
    char* bsw1 = (char*)Bs + 4096 + w * 1024;

    const int fr = l & 15;
    const int fq = l >> 4;

    for (int k0 = 0; k0 < K; k0 += 32) {
        gload16(a0 + k0, asw0);
        gload16(a1 + k0, asw1);
        gload16(b0 + k0, bsw0);
        gload16(b1 + k0, bsw1);
        __syncthreads();
        bf16x8 av[4], bv[4];
#pragma unroll
        for (int i = 0; i < 4; i++)
            av[i] = *(const bf16x8*)&As[(wm + i * 16 + fr) * 32 + fq * 8];
#pragma unroll
        for (int j = 0; j < 4; j++)
            bv[j] = *(const bf16x8*)&Bs[(wn + j * 16 + fr) * 32 + fq * 8];
#pragma unroll
        for (int i = 0; i < 4; i++)
#pragma unroll
            for (int j = 0; j < 4; j++)
                acc[i][j] = __builtin_amdgcn_mfma_f32_16x16x32_bf16(av[i], bv[j], acc[i][j], 0, 0, 0);
        __syncthreads();
    }

#pragma unroll
    for (int i = 0; i < 4; i++) {
#pragma unroll
        for (int j = 0; j < 4; j++) {
#pragma unroll
            for (int r2 = 0; r2 < 4; r2++) {
                int row = bm + wm + i * 16 + fq * 4 + r2;
                int col = bn + wn + j * 16 + fr;
                if (row < M) {
                    if constexpr (sizeof(CT) == 2)
                        C[(size_t)row * N + col] = __float2bfloat16(acc[i][j][r2]);
                    else
                        C[(size_t)row * N + col] = acc[i][j][r2];
                }
            }
        }
    }
}

// ---------------- fp32 -> bf16 conversions ----------------
__global__ __launch_bounds__(256)
void convert_x(const float* __restrict__ X, __hip_bfloat16* __restrict__ Xb) {
    int idx = blockIdx.x * 256 + threadIdx.x;
    const int nb = K1P / 8;   // 168
    if (idx >= MP1 * nb) return;
    int row = idx / nb;
    int cb = (idx - row * nb) * 8;
    union { __hip_bfloat16 h[8]; float4 f4; } u;
    if (row < NN && cb + 8 <= INDIM) {
        const float4* p = (const float4*)(X + (size_t)row * INDIM + cb);
        float4 u0 = p[0], u1 = p[1];
        u.h[0] = __float2bfloat16(u0.x); u.h[1] = __float2bfloat16(u0.y);
        u.h[2] = __float2bfloat16(u0.z); u.h[3] = __float2bfloat16(u0.w);
        u.h[4] = __float2bfloat16(u1.x); u.h[5] = __float2bfloat16(u1.y);
        u.h[6] = __float2bfloat16(u1.z); u.h[7] = __float2bfloat16(u1.w);
    } else {
#pragma unroll
        for (int e = 0; e < 8; e++) {
            float f = (row < NN && cb + e < INDIM) ? X[(size_t)row * INDIM + cb + e] : 0.f;
            u.h[e] = __float2bfloat16(f);
        }
    }
    *(float4*)(Xb + (size_t)row * K1P + cb) = u.f4;
}

__global__ __launch_bounds__(256)
void convert_wT(const float* __restrict__ W, __hip_bfloat16* __restrict__ Wt,
                int K, int N, int Kp) {
    int idx = blockIdx.x * 256 + threadIdx.x;
    if (idx >= N * Kp) return;
    int n = idx / Kp, k = idx - n * Kp;
    float f = (k < K) ? W[(size_t)k * N + n] : 0.f;
    Wt[idx] = __float2bfloat16(f);
}

// ---------------- attention logits: one wave per node ----------------
template<int H>
__global__ __launch_bounds__(256)
void compute_e(const __hip_bfloat16* __restrict__ hfeat, const float* __restrict__ a_src,
               const float* __restrict__ a_dst, float* __restrict__ esrc,
               float* __restrict__ edst, int N) {
    const int wv = threadIdx.x >> 6, lane = threadIdx.x & 63;
    const int n = blockIdx.x * 4 + wv;
    if (n >= N) return;
#pragma unroll
    for (int hd = 0; hd < H; hd++) {
        bf16x4 hv = *(const bf16x4*)(hfeat + (size_t)n * (H * 256) + hd * 256 + lane * 4);
        float ps = 0.f, pd = 0.f;
#pragma unroll
        for (int e = 0; e < 4; e++) {
            float f = (float)hv[e];
            ps += f * a_src[hd * 256 + lane * 4 + e];
            pd += f * a_dst[hd * 256 + lane * 4 + e];
        }
#pragma unroll
        for (int o = 32; o > 0; o >>= 1) {
            ps += __shfl_down(ps, o, 64);
            pd += __shfl_down(pd, o, 64);
        }
        if (lane == 0) {
            esrc[n * H + hd] = ps;
            edst[n * H + hd] = pd;
        }
    }
}

// ---------------- CSR build ----------------
__global__ void hist_kernel(const int* __restrict__ ei, int* __restrict__ deg) {
    int e = blockIdx.x * 256 + threadIdx.x;
    if (e >= EL) return;
    int d = (e < E0) ? ei[E0 + e] : (e - E0);
    atomicAdd(&deg[d], 1);
}

__global__ __launch_bounds__(1024)
void scan_kernel(const int* __restrict__ deg, int* __restrict__ off) {
    __shared__ int wsum[16];
    __shared__ int carry_s;
    int t = threadIdx.x, lane = t & 63, wv = t >> 6;
    if (t == 0) { carry_s = 0; off[0] = 0; }
    __syncthreads();
    for (int base = 0; base < NN; base += 1024) {
        int i = base + t;
        int v = (i < NN) ? deg[i] : 0;
        int x = v;
#pragma unroll
        for (int o = 1; o < 64; o <<= 1) {
            int y = __shfl_up(x, o, 64);
            if (lane >= o) x += y;
        }
        if (lane == 63) wsum[wv] = x;
        __syncthreads();
        if (wv == 0 && lane < 16) {
            int s = wsum[lane];
#pragma unroll
            for (int o = 1; o < 16; o <<= 1) {
                int y = __shfl_up(s, o, 64);
                if (lane >= o) s += y;
            }
            wsum[lane] = s;
        }
        __syncthreads();
        int woff = (wv == 0) ? 0 : wsum[wv - 1];
        int total = wsum[15];
        if (i < NN) off[i + 1] = carry_s + woff + x;
        __syncthreads();
        if (t == 0) carry_s += total;
        __syncthreads();
    }
}

__global__ void fill_kernel(const int* __restrict__ ei, const int* __restrict__ off,
                            int* __restrict__ cur, int* __restrict__ csr) {
    int e = blockIdx.x * 256 + threadIdx.x;
    if (e >= EL) return;
    int d = (e < E0) ? ei[E0 + e] : (e - E0);
    int s = (e < E0) ? ei[e] : (e - E0);
    int pos = off[d] + atomicAdd(&cur[d], 1);
    csr[pos] = s;
}

// ---------------- GAT aggregation: one WAVE per node ----------------
template<int H, bool RELU, typename OutT>
__global__ __launch_bounds__(256)
void gat_aggregate(const __hip_bfloat16* __restrict__ hfeat,
                   const float* __restrict__ esrc,
                   const float* __restrict__ edst,
                   const int* __restrict__ off, const int* __restrict__ csr,
                   const float* __restrict__ bias,
                   OutT* __restrict__ out, int N) {
    const int wv = threadIdx.x >> 6, lane = threadIdx.x & 63;
    const int n = blockIdx.x * 4 + wv;
    if (n >= N) return;
    const int beg = off[n];
    const int deg = off[n + 1] - beg;

    float ed[H], m[H], den[H];
    f32x4 acc[H];
#pragma unroll
    for (int h = 0; h < H; h++) {
        ed[h] = edst[n * H + h];
        m[h] = -INFINITY;
        den[h] = 0.f;
        acc[h] = (f32x4){0.f, 0.f, 0.f, 0.f};
    }

    for (int base = 0; base < deg; base += 64) {
        const int i = base + lane;
        int s = 0;
        float lg[H];
        if (i < deg) {
            s = csr[beg + i];
#pragma unroll
            for (int h = 0; h < H; h++) {
                float v = esrc[s * H + h] + ed[h];
                lg[h] = (v >= 0.f) ? v : NEG_SLOPE * v;
            }
        } else {
#pragma unroll
            for (int h = 0; h < H; h++) lg[h] = -INFINITY;
        }
        float cm[H];
#pragma unroll
        for (int h = 0; h < H; h++) {
            cm[h] = lg[h];
#pragma unroll
            for (int o = 1; o < 64; o <<= 1)
                cm[h] = fmaxf(cm[h], __shfl_xor(cm[h], o, 64));
        }
#pragma unroll
        for (int h = 0; h < H; h++) {
            float nm = fmaxf(m[h], cm[h]);
            float sc = expf(m[h] - nm);
            den[h] *= sc;
#pragma unroll
            for (int e = 0; e < 4; e++) acc[h][e] *= sc;
            m[h] = nm;
        }
        float wgt[H];
#pragma unroll
        for (int h = 0; h < H; h++) {
            wgt[h] = (i < deg) ? expf(lg[h] - m[h]) : 0.f;
            den[h] += wgt[h];
        }
        const int cnt = min(64, deg - base);
        for (int j = 0; j < cnt; j++) {
            int sj = __shfl(s, j, 64);
#pragma unroll
            for (int h = 0; h < H; h++) {
                float wj = __shfl(wgt[h], j, 64);
                bf16x4 hv = *(const bf16x4*)(hfeat + (size_t)sj * (H * 256) + h * 256 + 4 * lane);
#pragma unroll
                for (int e = 0; e < 4; e++) acc[h][e] += wj * (float)hv[e];
            }
        }
    }
#pragma unroll
    for (int h = 0; h < H; h++) {
#pragma unroll
        for (int o = 1; o < 64; o <<= 1) den[h] += __shfl_xor(den[h], o, 64);
    }
#pragma unroll
    for (int h = 0; h < H; h++) {
        float inv = 1.f / (den[h] + 1e-16f);
        if constexpr (sizeof(OutT) == 2) {
            bf16x4 r;
#pragma unroll
            for (int e = 0; e < 4; e++) {
                float f = acc[h][e] * inv + bias[h * 256 + 4 * lane + e];
                if (RELU) f = fmaxf(f, 0.f);
                r[e] = (__bf16)f;
            }
            *(bf16x4*)((__hip_bfloat16*)out + (size_t)n * (H * 256) + h * 256 + 4 * lane) = r;
        } else {
            float4 r;
            float* rp = &r.x;
#pragma unroll
            for (int e = 0; e < 4; e++) {
                float f = acc[h][e] * inv + bias[h * 256 + 4 * lane + e];
                if (RELU) f = fmaxf(f, 0.f);
                rp[e] = f;
            }
            *(float4*)((float*)out + (size_t)n * (H * 256) + h * 256 + 4 * lane) = r;
        }
    }
}

// ---------------- pooling ----------------
__device__ __forceinline__ int lower_bound_batch(const int* __restrict__ batch, int key) {
    int lo = 0, hi = NN;
    while (lo < hi) {
        int mid = (lo + hi) >> 1;
        if (batch[mid] < key) lo = mid + 1; else hi = mid;
    }
    return lo;
}

__global__ __launch_bounds__(256)
void pool_partial(const float* __restrict__ out2, const int* __restrict__ batch,
                  float* __restrict__ partial, float* __restrict__ cnts) {
    const int g = blockIdx.x, c = blockIdx.y, t = threadIdx.x;
    const int s = lower_bound_batch(batch, g);
    const int e = lower_bound_batch(batch, g + 1);
    float acc = 0.f;
    for (int n = s + c; n < e; n += PCH) acc += out2[(size_t)n * 256 + t];
    partial[((size_t)g * PCH + c) * 256 + t] = acc;
    if (t == 0 && c == 0) cnts[g] = (float)(e - s);
}

// ---------------- MLP head + softmax ----------------
__global__ __launch_bounds__(256)
void head_kernel(const float* __restrict__ phy, const float* __restrict__ partial,
                 const float* __restrict__ cnts,
                 const float* __restrict__ w11, const float* __restrict__ b11,
                 const float* __restrict__ w12, const float* __restrict__ b12,
                 const float* __restrict__ w21, const float* __restrict__ b21,
                 const float* __restrict__ w22, const float* __restrict__ b22,
                 float* __restrict__ out) {
    int g = blockIdx.x, t = threadIdx.x;
    __shared__ float ph[188];
    __shared__ float z[384];
    __shared__ float mid[128];
    __shared__ float t1[192];
    __shared__ float lg[2];
    if (t < 188) ph[t] = phy[g * 188 + t];
    {
        float s = 0.f;
#pragma unroll
        for (int c = 0; c < PCH; c++) s += partial[((size_t)g * PCH + c) * 256 + t];
        z[t] = s / fmaxf(cnts[g], 1.0f);
    }
    __syncthreads();
    if (t < 128) {
        float s = b11[t];
        for (int k = 0; k < 188; k++) s += ph[k] * w11[k * 128 + t];
        mid[t] = fmaxf(s, 0.f);
    }
    __syncthreads();
    if (t < 128) {
        float s = b12[t];
        for (int k = 0; k < 128; k++) s += mid[k] * w12[k * 128 + t];
        z[256 + t] = fmaxf(s, 0.f);
    }
    __syncthreads();
    if (t < 192) {
        float s = b21[t];
        for (int k = 0; k < 384; k++) s += z[k] * w21[k * 192 + t];
        t1[t] = fmaxf(s, 0.f);
    }
    __syncthreads();
    if (t < 2) {
        float s = b22[t];
        for (int k = 0; k < 192; k++) s += t1[k] * w22[k * 2 + t];
        lg[t] = s;
    }
    __syncthreads();
    if (t == 0) {
        float mx = fmaxf(lg[0], lg[1]);
        float e0 = expf(lg[0] - mx), e1 = expf(lg[1] - mx);
        float d = e0 + e1;
        out[g * 2 + 0] = e0 / d;
        out[g * 2 + 1] = e1 / d;
    }
}

extern "C" void kernel_launch(void* const* d_in, const int* in_sizes, int n_in,
                              void* d_out, int out_size, void* d_ws, size_t ws_size,
                              hipStream_t stream) {
    const float* x       = (const float*)d_in[0];
    const int*   ei      = (const int*)  d_in[1];
    const float* phy     = (const float*)d_in[2];
    const int*   batch   = (const int*)  d_in[3];
    const float* W1      = (const float*)d_in[4];
    const float* a_src1  = (const float*)d_in[5];
    const float* a_dst1  = (const float*)d_in[6];
    const float* b1      = (const float*)d_in[7];
    const float* W2      = (const float*)d_in[8];
    const float* a_src2  = (const float*)d_in[9];
    const float* a_dst2  = (const float*)d_in[10];
    const float* b2      = (const float*)d_in[11];
    const float* fc1_w1  = (const float*)d_in[12];
    const float* fc1_b1  = (const float*)d_in[13];
    const float* fc1_w2  = (const float*)d_in[14];
    const float* fc1_b2  = (const float*)d_in[15];
    const float* fc2_w1  = (const float*)d_in[16];
    const float* fc2_b1  = (const float*)d_in[17];
    const float* fc2_w2  = (const float*)d_in[18];
    const float* fc2_b2  = (const float*)d_in[19];
    float* out = (float*)d_out;

    char* base = (char*)d_ws;
    size_t o = 0;
    auto alloc = [&](size_t bytes) { size_t r = o; o += (bytes + 255) & ~255ULL; return r; };

    size_t o_xb   = alloc((size_t)MP1 * K1P * 2);    // reused for h2b/out2 after GEMM1
    size_t o_w1t  = alloc((size_t)768 * K1P * 2);
    size_t o_w2t  = alloc((size_t)256 * 768 * 2);
    size_t o_h1b  = alloc((size_t)NP * 768 * 2);
    size_t o_hob  = alloc((size_t)NP * 768 * 2);
    size_t o_es1  = alloc((size_t)NN * 3 * 4);
    size_t o_ed1  = alloc((size_t)NN * 3 * 4);
    size_t o_es2  = alloc((size_t)NN * 4);
    size_t o_ed2  = alloc((size_t)NN * 4);
    size_t o_deg  = alloc((size_t)(NN + 1) * 4);
    size_t o_off  = alloc((size_t)(NN + 1) * 4);
    size_t o_cur  = alloc((size_t)NN * 4);
    size_t o_csr  = alloc((size_t)EL * 4);
    size_t o_part = alloc((size_t)NG * PCH * 256 * 4);
    size_t o_cnts = alloc((size_t)NG * 4);

    __hip_bfloat16* xb   = (__hip_bfloat16*)(base + o_xb);
    __hip_bfloat16* w1t  = (__hip_bfloat16*)(base + o_w1t);
    __hip_bfloat16* w2t  = (__hip_bfloat16*)(base + o_w2t);
    __hip_bfloat16* h1b  = (__hip_bfloat16*)(base + o_h1b);
    __hip_bfloat16* hob  = (__hip_bfloat16*)(base + o_hob);
    __hip_bfloat16* h2b  = (__hip_bfloat16*)(base + o_xb);
    float*          out2 = (float*)(base + o_xb + (size_t)24 * 1024 * 1024);
    float* es1   = (float*)(base + o_es1);
    float* ed1   = (float*)(base + o_ed1);
    float* es2   = (float*)(base + o_es2);
    float* ed2   = (float*)(base + o_ed2);
    int*   deg   = (int*)(base + o_deg);
    int*   offs  = (int*)(base + o_off);
    int*   cur   = (int*)(base + o_cur);
    int*   csr   = (int*)(base + o_csr);
    float* part  = (float*)(base + o_part);
    float* cnts  = (float*)(base + o_cnts);

    hipMemsetAsync(deg, 0, (size_t)(NN + 1) * 4, stream);
    hipMemsetAsync(cur, 0, (size_t)NN * 4, stream);
    hipMemsetAsync(hob + (size_t)NN * 768, 0, (size_t)(NP - NN) * 768 * 2, stream);

    convert_x<<<(MP1 * (K1P / 8) + 255) / 256, 256, 0, stream>>>(x, xb);
    convert_wT<<<(768 * K1P + 255) / 256, 256, 0, stream>>>(W1, w1t, INDIM, 768, K1P);
    convert_wT<<<(256 * 768 + 255) / 256, 256, 0, stream>>>(W2, w2t, 768, 256, 768);

    hist_kernel<<<(EL + 255) / 256, 256, 0, stream>>>(ei, deg);
    scan_kernel<<<1, 1024, 0, stream>>>(deg, offs);
    fill_kernel<<<(EL + 255) / 256, 256, 0, stream>>>(ei, offs, cur, csr);

    gemm256<<<GMB * GNX, 512, 0, stream>>>(xb, w1t, h1b, NN);
    compute_e<3><<<(NN + 3) / 4, 256, 0, stream>>>(h1b, a_src1, a_dst1, es1, ed1, NN);
    gat_aggregate<3, true, __hip_bfloat16><<<(NN + 3) / 4, 256, 0, stream>>>(h1b, es1, ed1, offs, csr, b1, hob, NN);

    mfma_gemm<__hip_bfloat16><<<2 * 157, 256, 0, stream>>>(hob, w2t, h2b, NN, 256, 768, 2);
    compute_e<1><<<(NN + 3) / 4, 256, 0, stream>>>(h2b, a_src2, a_dst2, es2, ed2, NN);
    gat_aggregate<1, false, float><<<(NN + 3) / 4, 256, 0, stream>>>(h2b, es2, ed2, offs, csr, b2, out2, NN);

    pool_partial<<<dim3(NG, PCH), 256, 0, stream>>>(out2, batch, part, cnts);
    head_kernel<<<NG, 256, 0, stream>>>(phy, part, cnts,
                                        fc1_w1, fc1_b1, fc1_w2, fc1_b2,
                                        fc2_w1, fc2_b1, fc2_w2, fc2_b2, out);
}

// Round 6
// 255.037 us; speedup vs baseline: 4.9093x; 1.0996x over previous
//
#include <hip/hip_runtime.h>
#include <hip/hip_bf16.h>
#include <math.h>

#define NN    20000
#define MP1   20224          // 79*256 padded rows for gemm1
#define NP    20096          // 157*128 padded rows for gemm2 A
#define E0    160000
#define EL    180000
#define NG    64
#define INDIM 1304
#define K1P   1344           // K padded to multiple of 64 (21 K-tiles)
#define GNT   21             // K1P/64
#define GNX   3              // 768/256
#define GMB   79             // M blocks
#define NEG_SLOPE 0.2f
#define PCH   8
#define NSB   20             // scan blocks = ceil(NN/1024)

typedef __bf16 bf16x8 __attribute__((ext_vector_type(8)));
typedef __bf16 bf16x4 __attribute__((ext_vector_type(4)));
typedef float  f32x4  __attribute__((ext_vector_type(4)));

__device__ __forceinline__ void gload16(const void* g, void* l) {
    __builtin_amdgcn_global_load_lds(
        (const __attribute__((address_space(1))) void*)g,
        (__attribute__((address_space(3))) void*)l, 16, 0, 0);
}

#define BAR()  { __builtin_amdgcn_s_barrier(); asm volatile("" ::: "memory"); }
#define VMW(n) { asm volatile("s_waitcnt vmcnt(" #n ")" ::: "memory"); __builtin_amdgcn_sched_barrier(0); }

// stage one 16-KB A half (mh) of K-tile kt: linear LDS dest, inverse-swizzled global src
__device__ __forceinline__ void stA(const __hip_bfloat16* __restrict__ A, int bm, int kt, int mh,
                                    char* abuf, int w, int l) {
#pragma unroll
    for (int u = 0; u < 2; u++) {
        int rl = (w << 3) + (l >> 3);            // row_local 0..63
        int lrow = u * 128 + mh * 64 + rl;       // row in 256-row tile
        int skb = ((l & 7) << 4) ^ ((rl & 7) << 4);
        const char* g = (const char*)(A + (size_t)(bm + lrow) * K1P + kt * 64) + skb;
        gload16(g, abuf + (u * 128 + mh * 64) * 128 + (w << 10));
    }
}

// stage one 16-KB B region (nh), 4 chunks of 32 rows
__device__ __forceinline__ void stB(const __hip_bfloat16* __restrict__ Bt, int bn, int kt, int nh,
                                    char* bbuf, int w, int l) {
#pragma unroll
    for (int u = 0; u < 2; u++) {
        int c = u * 2 + (w >> 2);
        int row0 = c * 64 + nh * 32;
        int rl = ((w & 3) << 3) + (l >> 3);      // 0..31
        int skb = ((l & 7) << 4) ^ ((rl & 7) << 4);
        const char* g = (const char*)(Bt + (size_t)(bn + row0 + rl) * K1P + kt * 64) + skb;
        gload16(g, bbuf + row0 * 128 + ((w & 3) << 10));
    }
}

// ---------------- 256x256 8-phase bf16 MFMA GEMM + fused layer-1 e_src/e_dst ----------------
// C[M,768] = A[MP1,K1P] @ Bt[768,K1P]^T ; head = bn/256 aligns with BN
__global__ __launch_bounds__(512)
void gemm256(const __hip_bfloat16* __restrict__ A,
             const __hip_bfloat16* __restrict__ Bt,
             __hip_bfloat16* __restrict__ C,
             const float* __restrict__ a_src, const float* __restrict__ a_dst,
             float* __restrict__ esrc, float* __restrict__ edst, int M) {
    __shared__ char lds[131072];
    const int t = threadIdx.x;
    const int w = t >> 6, l = t & 63;
    const int wm = w >> 2, wn = w & 3;           // 2 x 4 waves, each 128x64 output
    const int fr = l & 15, fq = l >> 4;
    const int amask = (fr & 7) << 4;

    const int nwg = GMB * GNX;
    const int q8 = nwg >> 3, r8 = nwg & 7;
    const int xcd = blockIdx.x & 7, sub = blockIdx.x >> 3;
    const int logical = (xcd < r8 ? xcd * (q8 + 1) : r8 * (q8 + 1) + (xcd - r8) * q8) + sub;
    const int bm = (logical / GNX) * 256;
    const int bn = (logical % GNX) * 256;

    f32x4 acc[8][4];
#pragma unroll
    for (int i = 0; i < 8; i++)
#pragma unroll
        for (int j = 0; j < 4; j++) acc[i][j] = (f32x4){0.f, 0.f, 0.f, 0.f};

    char* A0 = lds;            char* B0 = lds + 32768;
    char* A1 = lds + 65536;    char* B1 = lds + 98304;

    stA(A, bm, 0, 0, A0, w, l);
    stB(Bt, bn, 0, 0, B0, w, l);
    stA(A, bm, 0, 1, A0, w, l);
    stB(Bt, bn, 0, 1, B0, w, l);
    stA(A, bm, 1, 0, A1, w, l);
    stB(Bt, bn, 1, 0, B1, w, l);
    VMW(8);
    BAR();

    for (int kt = 0; kt < GNT; kt++) {
        char* Ab = lds + (kt & 1) * 65536;
        char* Bb = Ab + 32768;
        char* An = lds + ((kt + 1) & 1) * 65536;
        char* Bn = An + 32768;
        bf16x8 a_c[4][2], b_c0[2][2], b_c1[2][2];

        // ---- q0 ----
#pragma unroll
        for (int im = 0; im < 4; im++)
#pragma unroll
            for (int kk = 0; kk < 2; kk++)
                a_c[im][kk] = *(const bf16x8*)(Ab + (wm * 128 + im * 16 + fr) * 128 + ((kk * 64 + fq * 16) ^ amask));
#pragma unroll
        for (int jn = 0; jn < 2; jn++)
#pragma unroll
            for (int kk = 0; kk < 2; kk++)
                b_c0[jn][kk] = *(const bf16x8*)(Bb + (wn * 64 + jn * 16 + fr) * 128 + ((kk * 64 + fq * 16) ^ amask));
        if (kt + 1 < GNT) stA(A, bm, kt + 1, 1, An, w, l);
        BAR();
        __builtin_amdgcn_s_setprio(1);
#pragma unroll
        for (int im = 0; im < 4; im++)
#pragma unroll
            for (int jn = 0; jn < 2; jn++)
#pragma unroll
                for (int kk = 0; kk < 2; kk++)
                    acc[im][jn] = __builtin_amdgcn_mfma_f32_16x16x32_bf16(a_c[im][kk], b_c0[jn][kk], acc[im][jn], 0, 0, 0);
        __builtin_amdgcn_s_setprio(0);
        if (kt == GNT - 1) { VMW(0); } else { VMW(6); }
        BAR();

        // ---- q1 ----
#pragma unroll
        for (int jn = 0; jn < 2; jn++)
#pragma unroll
            for (int kk = 0; kk < 2; kk++)
                b_c1[jn][kk] = *(const bf16x8*)(Bb + (wn * 64 + 32 + jn * 16 + fr) * 128 + ((kk * 64 + fq * 16) ^ amask));
        if (kt + 1 < GNT) stB(Bt, bn, kt + 1, 1, Bn, w, l);
        BAR();
        __builtin_amdgcn_s_setprio(1);
#pragma unroll
        for (int im = 0; im < 4; im++)
#pragma unroll
            for (int jn = 0; jn < 2; jn++)
#pragma unroll
                for (int kk = 0; kk < 2; kk++)
                    acc[im][2 + jn] = __builtin_amdgcn_mfma_f32_16x16x32_bf16(a_c[im][kk], b_c1[jn][kk], acc[im][2 + jn], 0, 0, 0);
        __builtin_amdgcn_s_setprio(0);
        if (kt == GNT - 1) { VMW(2); } else { VMW(10); }
        BAR();

        // ---- q2 ----
#pragma unroll
        for (int im = 0; im < 4; im++)
#pragma unroll
            for (int kk = 0; kk < 2; kk++)
                a_c[im][kk] = *(const bf16x8*)(Ab + (wm * 128 + 64 + im * 16 + fr) * 128 + ((kk * 64 + fq * 16) ^ amask));
        if (kt + 2 < GNT) stA(A, bm, kt + 2, 0, Ab, w, l);
        BAR();
        __builtin_amdgcn_s_setprio(1);
#pragma unroll
        for (int im = 0; im < 4; im++)
#pragma unroll
            for (int jn = 0; jn < 2; jn++)
#pragma unroll
                for (int kk = 0; kk < 2; kk++)
                    acc[4 + im][jn] = __builtin_amdgcn_mfma_f32_16x16x32_bf16(a_c[im][kk], b_c0[jn][kk], acc[4 + im][jn], 0, 0, 0);
        __builtin_amdgcn_s_setprio(0);
        BAR();

        // ---- q3 ----
        if (kt + 2 < GNT) stB(Bt, bn, kt + 2, 0, Bb, w, l);
        BAR();
        __builtin_amdgcn_s_setprio(1);
#pragma unroll
        for (int im = 0; im < 4; im++)
#pragma unroll
            for (int jn = 0; jn < 2; jn++)
#pragma unroll
                for (int kk = 0; kk < 2; kk++)
                    acc[4 + im][2 + jn] = __builtin_amdgcn_mfma_f32_16x16x32_bf16(a_c[im][kk], b_c1[jn][kk], acc[4 + im][2 + jn], 0, 0, 0);
        __builtin_amdgcn_s_setprio(0);
        if (kt + 2 < GNT) { VMW(8); }
        else if (kt + 2 == GNT) { VMW(4); }
        BAR();
    }

    // C-write: col=lane&15, row=(lane>>4)*4+reg
#pragma unroll
    for (int i = 0; i < 8; i++)
#pragma unroll
        for (int j = 0; j < 4; j++)
#pragma unroll
            for (int r = 0; r < 4; r++) {
                int row = bm + wm * 128 + i * 16 + fq * 4 + r;
                int col = bn + wn * 64 + j * 16 + fr;
                if (row < M) C[(size_t)row * 768 + col] = __float2bfloat16(acc[i][j][r]);
            }

    // ---- fused e_src/e_dst (this block owns ALL channels of head bn/256) ----
    const int head = bn >> 8;
    float asv[4], adv[4];
#pragma unroll
    for (int j = 0; j < 4; j++) {
        asv[j] = a_src[head * 256 + wn * 64 + j * 16 + fr];
        adv[j] = a_dst[head * 256 + wn * 64 + j * 16 + fr];
    }
    __syncthreads();                     // done with MFMA lds; reuse as [256][4][2] f32
    float* eb = (float*)lds;
#pragma unroll
    for (int i = 0; i < 8; i++) {
#pragma unroll
        for (int r = 0; r < 4; r++) {
            float ps = 0.f, pd = 0.f;
#pragma unroll
            for (int j = 0; j < 4; j++) { ps += acc[i][j][r] * asv[j]; pd += acc[i][j][r] * adv[j]; }
#pragma unroll
            for (int o = 8; o >= 1; o >>= 1) { ps += __shfl_xor(ps, o, 64); pd += __shfl_xor(pd, o, 64); }
            if (fr == 0) {
                int rowl = wm * 128 + i * 16 + fq * 4 + r;
                eb[(rowl * 4 + wn) * 2 + 0] = ps;
                eb[(rowl * 4 + wn) * 2 + 1] = pd;
            }
        }
    }
    __syncthreads();
    if (t < 256) {
        int row = bm + t;
        if (row < M) {
            float s = eb[t * 8 + 0] + eb[t * 8 + 2] + eb[t * 8 + 4] + eb[t * 8 + 6];
            float d = eb[t * 8 + 1] + eb[t * 8 + 3] + eb[t * 8 + 5] + eb[t * 8 + 7];
            esrc[row * 3 + head] = s;
            edst[row * 3 + head] = d;
        }
    }
}

// ---------------- 2-phase double-buffered 128x128 GEMM (GEMM2) ----------------
template<typename CT>
__global__ __launch_bounds__(256)
void mfma_gemm(const __hip_bfloat16* __restrict__ A,
               const __hip_bfloat16* __restrict__ Bt,
               CT* __restrict__ C,
               int M, int N, int K, int NX) {
    __shared__ __hip_bfloat16 As[2][128 * 32];
    __shared__ __hip_bfloat16 Bs[2][128 * 32];
    const int t = threadIdx.x;
    const int w = t >> 6;
    const int l = t & 63;

    const int nwg = gridDim.x;
    const int q = nwg >> 3, r = nwg & 7;
    const int xcd = blockIdx.x & 7, idx = blockIdx.x >> 3;
    const int logical = (xcd < r ? xcd * (q + 1) : r * (q + 1) + (xcd - r) * q) + idx;
    const int bm = (logical / NX) * 128;
    const int bn = (logical % NX) * 128;

    const int wm = (w >> 1) * 64;
    const int wn = (w & 1) * 64;

    f32x4 acc[4][4];
#pragma unroll
    for (int i = 0; i < 4; i++)
#pragma unroll
        for (int j = 0; j < 4; j++) acc[i][j] = (f32x4){0.f, 0.f, 0.f, 0.f};

    const int sr = t >> 2;
    const int sc = (t & 3) * 8;
    const __hip_bfloat16* a0 = A  + (size_t)(bm + sr)      * K + sc;
    const __hip_bfloat16* a1 = A  + (size_t)(bm + 64 + sr) * K + sc;
    const __hip_bfloat16* b0 = Bt + (size_t)(bn + sr)      * K + sc;
    const __hip_bfloat16* b1 = Bt + (size_t)(bn + 64 + sr) * K + sc;

    const int fr = l & 15;
    const int fq = l >> 4;
    const int NT = K / 32;

    auto stage = [&](int k0, int b) {
        char* asb = (char*)&As[b][0];
        char* bsb = (char*)&Bs[b][0];
        gload16(a0 + k0, asb + w * 1024);
        gload16(a1 + k0, asb + 4096 + w * 1024);
        gload16(b0 + k0, bsb + w * 1024);
        gload16(b1 + k0, bsb + 4096 + w * 1024);
    };

    stage(0, 0);
    __syncthreads();

    for (int kt = 0; kt < NT; kt++) {
        const int cb = kt & 1;
        if (kt + 1 < NT) stage((kt + 1) * 32, cb ^ 1);   // prefetch next tile
        bf16x8 av[4], bv[4];
#pragma unroll
        for (int i = 0; i < 4; i++)
            av[i] = *(const bf16x8*)&As[cb][(wm + i * 16 + fr) * 32 + fq * 8];
#pragma unroll
        for (int j = 0; j < 4; j++)
            bv[j] = *(const bf16x8*)&Bs[cb][(wn + j * 16 + fr) * 32 + fq * 8];
#pragma unroll
        for (int i = 0; i < 4; i++)
#pragma unroll
            for (int j = 0; j < 4; j++)
                acc[i][j] = __builtin_amdgcn_mfma_f32_16x16x32_bf16(av[i], bv[j], acc[i][j], 0, 0, 0);
        __syncthreads();   // drains vmcnt (next tile staged) + lgkm; 1 barrier/iter
    }

#pragma unroll
    for (int i = 0; i < 4; i++) {
#pragma unroll
        for (int j = 0; j < 4; j++) {
#pragma unroll
            for (int r2 = 0; r2 < 4; r2++) {
                int row = bm + wm + i * 16 + fq * 4 + r2;
                int col = bn + wn + j * 16 + fr;
                if (row < M) {
                    if constexpr (sizeof(CT) == 2)
                        C[(size_t)row * N + col] = __float2bfloat16(acc[i][j][r2]);
                    else
                        C[(size_t)row * N + col] = acc[i][j][r2];
                }
            }
        }
    }
}

// ---------------- fp32 -> bf16 conversions ----------------
__global__ __launch_bounds__(256)
void convert_x(const float* __restrict__ X, __hip_bfloat16* __restrict__ Xb) {
    int idx = blockIdx.x * 256 + threadIdx.x;
    const int nb = K1P / 8;   // 168
    if (idx >= MP1 * nb) return;
    int row = idx / nb;
    int cb = (idx - row * nb) * 8;
    union { __hip_bfloat16 h[8]; float4 f4; } u;
    if (row < NN && cb + 8 <= INDIM) {
        const float4* p = (const float4*)(X + (size_t)row * INDIM + cb);
        float4 u0 = p[0], u1 = p[1];
        u.h[0] = __float2bfloat16(u0.x); u.h[1] = __float2bfloat16(u0.y);
        u.h[2] = __float2bfloat16(u0.z); u.h[3] = __float2bfloat16(u0.w);
        u.h[4] = __float2bfloat16(u1.x); u.h[5] = __float2bfloat16(u1.y);
        u.h[6] = __float2bfloat16(u1.z); u.h[7] = __float2bfloat16(u1.w);
    } else {
#pragma unroll
        for (int e = 0; e < 8; e++) {
            float f = (row < NN && cb + e < INDIM) ? X[(size_t)row * INDIM + cb + e] : 0.f;
            u.h[e] = __float2bfloat16(f);
        }
    }
    *(float4*)(Xb + (size_t)row * K1P + cb) = u.f4;
}

// both weight transposes in one launch
__global__ __launch_bounds__(256)
void convert_w_all(const float* __restrict__ W1, const float* __restrict__ W2,
                   __hip_bfloat16* __restrict__ w1t, __hip_bfloat16* __restrict__ w2t) {
    int idx = blockIdx.x * 256 + threadIdx.x;
    const int n1 = 768 * K1P;
    if (idx < n1) {
        int n = idx / K1P, k = idx - n * K1P;
        float f = (k < INDIM) ? W1[(size_t)k * 768 + n] : 0.f;
        w1t[idx] = __float2bfloat16(f);
    } else {
        int i2 = idx - n1;
        if (i2 < 256 * 768) {
            int n = i2 / 768, k = i2 - n * 768;
            w2t[i2] = __float2bfloat16(W2[(size_t)k * 256 + n]);
        }
    }
}

// ---------------- attention logits (layer 2 only) ----------------
template<int H>
__global__ __launch_bounds__(256)
void compute_e(const __hip_bfloat16* __restrict__ hfeat, const float* __restrict__ a_src,
               const float* __restrict__ a_dst, float* __restrict__ esrc,
               float* __restrict__ edst, int N) {
    const int wv = threadIdx.x >> 6, lane = threadIdx.x & 63;
    const int n = blockIdx.x * 4 + wv;
    if (n >= N) return;
#pragma unroll
    for (int hd = 0; hd < H; hd++) {
        bf16x4 hv = *(const bf16x4*)(hfeat + (size_t)n * (H * 256) + hd * 256 + lane * 4);
        float ps = 0.f, pd = 0.f;
#pragma unroll
        for (int e = 0; e < 4; e++) {
            float f = (float)hv[e];
            ps += f * a_src[hd * 256 + lane * 4 + e];
            pd += f * a_dst[hd * 256 + lane * 4 + e];
        }
#pragma unroll
        for (int o = 32; o > 0; o >>= 1) {
            ps += __shfl_down(ps, o, 64);
            pd += __shfl_down(pd, o, 64);
        }
        if (lane == 0) {
            esrc[n * H + hd] = ps;
            edst[n * H + hd] = pd;
        }
    }
}

// ---------------- CSR build ----------------
__global__ void hist_kernel(const int* __restrict__ ei, int* __restrict__ deg) {
    int e = blockIdx.x * 256 + threadIdx.x;
    if (e >= EL) return;
    int d = (e < E0) ? ei[E0 + e] : (e - E0);
    atomicAdd(&deg[d], 1);
}

// hierarchical scan: per-block local inclusive scan + block totals
__global__ __launch_bounds__(1024)
void scan_blk(const int* __restrict__ deg, int* __restrict__ off, int* __restrict__ bsum) {
    __shared__ int wsum[16];
    const int b = blockIdx.x, t = threadIdx.x, lane = t & 63, wv = t >> 6;
    const int i = b * 1024 + t;
    int v = (i < NN) ? deg[i] : 0;
    int x = v;
#pragma unroll
    for (int o = 1; o < 64; o <<= 1) {
        int y = __shfl_up(x, o, 64);
        if (lane >= o) x += y;
    }
    if (lane == 63) wsum[wv] = x;
    __syncthreads();
    if (wv == 0 && lane < 16) {
        int s = wsum[lane];
#pragma unroll
        for (int o = 1; o < 16; o <<= 1) {
            int y = __shfl_up(s, o, 64);
            if (lane >= o) s += y;
        }
        wsum[lane] = s;
    }
    __syncthreads();
    int woff = (wv == 0) ? 0 : wsum[wv - 1];
    if (i < NN) off[i + 1] = woff + x;
    if (t == 1023) bsum[b] = wsum[15];
}

__global__ void scan_top(const int* __restrict__ bsum, int* __restrict__ boff) {
    int lane = threadIdx.x;   // 64 threads
    int v = (lane < NSB) ? bsum[lane] : 0;
    int x = v;
#pragma unroll
    for (int o = 1; o < 64; o <<= 1) {
        int y = __shfl_up(x, o, 64);
        if (lane >= o) x += y;
    }
    if (lane < NSB) boff[lane] = x - v;   // exclusive
}

__global__ __launch_bounds__(1024)
void scan_add(int* __restrict__ off, const int* __restrict__ boff) {
    const int b = blockIdx.x, t = threadIdx.x;
    const int i = b * 1024 + t;
    if (i < NN) off[i + 1] += boff[b];
    if (b == 0 && t == 0) off[0] = 0;
}

__global__ void fill_kernel(const int* __restrict__ ei, const int* __restrict__ off,
                            int* __restrict__ cur, int* __restrict__ csr) {
    int e = blockIdx.x * 256 + threadIdx.x;
    if (e >= EL) return;
    int d = (e < E0) ? ei[E0 + e] : (e - E0);
    int s = (e < E0) ? ei[e] : (e - E0);
    int pos = off[d] + atomicAdd(&cur[d], 1);
    csr[pos] = s;
}

// ---------------- GAT aggregation: one WAVE per node ----------------
template<int H, bool RELU, typename OutT>
__global__ __launch_bounds__(256)
void gat_aggregate(const __hip_bfloat16* __restrict__ hfeat,
                   const float* __restrict__ esrc,
                   const float* __restrict__ edst,
                   const int* __restrict__ off, const int* __restrict__ csr,
                   const float* __restrict__ bias,
                   OutT* __restrict__ out, int N) {
    const int wv = threadIdx.x >> 6, lane = threadIdx.x & 63;
    const int n = blockIdx.x * 4 + wv;
    if (n >= N) return;
    const int beg = off[n];
    const int deg = off[n + 1] - beg;

    float ed[H], m[H], den[H];
    f32x4 acc[H];
#pragma unroll
    for (int h = 0; h < H; h++) {
        ed[h] = edst[n * H + h];
        m[h] = -INFINITY;
        den[h] = 0.f;
        acc[h] = (f32x4){0.f, 0.f, 0.f, 0.f};
    }

    for (int base = 0; base < deg; base += 64) {
        const int i = base + lane;
        int s = 0;
        float lg[H];
        if (i < deg) {
            s = csr[beg + i];
#pragma unroll
            for (int h = 0; h < H; h++) {
                float v = esrc[s * H + h] + ed[h];
                lg[h] = (v >= 0.f) ? v : NEG_SLOPE * v;
            }
        } else {
#pragma unroll
            for (int h = 0; h < H; h++) lg[h] = -INFINITY;
        }
        float cm[H];
#pragma unroll
        for (int h = 0; h < H; h++) {
            cm[h] = lg[h];
#pragma unroll
            for (int o = 1; o < 64; o <<= 1)
                cm[h] = fmaxf(cm[h], __shfl_xor(cm[h], o, 64));
        }
#pragma unroll
        for (int h = 0; h < H; h++) {
            float nm = fmaxf(m[h], cm[h]);
            float sc = expf(m[h] - nm);
            den[h] *= sc;
#pragma unroll
            for (int e = 0; e < 4; e++) acc[h][e] *= sc;
            m[h] = nm;
        }
        float wgt[H];
#pragma unroll
        for (int h = 0; h < H; h++) {
            wgt[h] = (i < deg) ? expf(lg[h] - m[h]) : 0.f;
            den[h] += wgt[h];
        }
        const int cnt = min(64, deg - base);
        for (int j = 0; j < cnt; j++) {
            int sj = __shfl(s, j, 64);
#pragma unroll
            for (int h = 0; h < H; h++) {
                float wj = __shfl(wgt[h], j, 64);
                bf16x4 hv = *(const bf16x4*)(hfeat + (size_t)sj * (H * 256) + h * 256 + 4 * lane);
#pragma unroll
                for (int e = 0; e < 4; e++) acc[h][e] += wj * (float)hv[e];
            }
        }
    }
#pragma unroll
    for (int h = 0; h < H; h++) {
#pragma unroll
        for (int o = 1; o < 64; o <<= 1) den[h] += __shfl_xor(den[h], o, 64);
    }
#pragma unroll
    for (int h = 0; h < H; h++) {
        float inv = 1.f / (den[h] + 1e-16f);
        if constexpr (sizeof(OutT) == 2) {
            bf16x4 r;
#pragma unroll
            for (int e = 0; e < 4; e++) {
                float f = acc[h][e] * inv + bias[h * 256 + 4 * lane + e];
                if (RELU) f = fmaxf(f, 0.f);
                r[e] = (__bf16)f;
            }
            *(bf16x4*)((__hip_bfloat16*)out + (size_t)n * (H * 256) + h * 256 + 4 * lane) = r;
        } else {
            float4 r;
            float* rp = &r.x;
#pragma unroll
            for (int e = 0; e < 4; e++) {
                float f = acc[h][e] * inv + bias[h * 256 + 4 * lane + e];
                if (RELU) f = fmaxf(f, 0.f);
                rp[e] = f;
            }
            *(float4*)((float*)out + (size_t)n * (H * 256) + h * 256 + 4 * lane) = r;
        }
    }
}

// ---------------- pooling ----------------
__device__ __forceinline__ int lower_bound_batch(const int* __restrict__ batch, int key) {
    int lo = 0, hi = NN;
    while (lo < hi) {
        int mid = (lo + hi) >> 1;
        if (batch[mid] < key) lo = mid + 1; else hi = mid;
    }
    return lo;
}

__global__ __launch_bounds__(256)
void pool_partial(const float* __restrict__ out2, const int* __restrict__ batch,
                  float* __restrict__ partial, float* __restrict__ cnts) {
    const int g = blockIdx.x, c = blockIdx.y, t = threadIdx.x;
    const int s = lower_bound_batch(batch, g);
    const int e = lower_bound_batch(batch, g + 1);
    float acc = 0.f;
    for (int n = s + c; n < e; n += PCH) acc += out2[(size_t)n * 256 + t];
    partial[((size_t)g * PCH + c) * 256 + t] = acc;
    if (t == 0 && c == 0) cnts[g] = (float)(e - s);
}

// ---------------- MLP head + softmax ----------------
__global__ __launch_bounds__(256)
void head_kernel(const float* __restrict__ phy, const float* __restrict__ partial,
                 const float* __restrict__ cnts,
                 const float* __restrict__ w11, const float* __restrict__ b11,
                 const float* __restrict__ w12, const float* __restrict__ b12,
                 const float* __restrict__ w21, const float* __restrict__ b21,
                 const float* __restrict__ w22, const float* __restrict__ b22,
                 float* __restrict__ out) {
    int g = blockIdx.x, t = threadIdx.x;
    __shared__ float ph[188];
    __shared__ float z[384];
    __shared__ float mid[128];
    __shared__ float t1[192];
    __shared__ float lg[2];
    if (t < 188) ph[t] = phy[g * 188 + t];
    {
        float s = 0.f;
#pragma unroll
        for (int c = 0; c < PCH; c++) s += partial[((size_t)g * PCH + c) * 256 + t];
        z[t] = s / fmaxf(cnts[g], 1.0f);
    }
    __syncthreads();
    if (t < 128) {
        float s = b11[t];
        for (int k = 0; k < 188; k++) s += ph[k] * w11[k * 128 + t];
        mid[t] = fmaxf(s, 0.f);
    }
    __syncthreads();
    if (t < 128) {
        float s = b12[t];
        for (int k = 0; k < 128; k++) s += mid[k] * w12[k * 128 + t];
        z[256 + t] = fmaxf(s, 0.f);
    }
    __syncthreads();
    if (t < 192) {
        float s = b21[t];
        for (int k = 0; k < 384; k++) s += z[k] * w21[k * 192 + t];
        t1[t] = fmaxf(s, 0.f);
    }
    __syncthreads();
    if (t < 2) {
        float s = b22[t];
        for (int k = 0; k < 192; k++) s += t1[k] * w22[k * 2 + t];
        lg[t] = s;
    }
    __syncthreads();
    if (t == 0) {
        float mx = fmaxf(lg[0], lg[1]);
        float e0 = expf(lg[0] - mx), e1 = expf(lg[1] - mx);
        float d = e0 + e1;
        out[g * 2 + 0] = e0 / d;
        out[g * 2 + 1] = e1 / d;
    }
}

extern "C" void kernel_launch(void* const* d_in, const int* in_sizes, int n_in,
                              void* d_out, int out_size, void* d_ws, size_t ws_size,
                              hipStream_t stream) {
    const float* x       = (const float*)d_in[0];
    const int*   ei      = (const int*)  d_in[1];
    const float* phy     = (const float*)d_in[2];
    const int*   batch   = (const int*)  d_in[3];
    const float* W1      = (const float*)d_in[4];
    const float* a_src1  = (const float*)d_in[5];
    const float* a_dst1  = (const float*)d_in[6];
    const float* b1      = (const float*)d_in[7];
    const float* W2      = (const float*)d_in[8];
    const float* a_src2  = (const float*)d_in[9];
    const float* a_dst2  = (const float*)d_in[10];
    const float* b2      = (const float*)d_in[11];
    const float* fc1_w1  = (const float*)d_in[12];
    const float* fc1_b1  = (const float*)d_in[13];
    const float* fc1_w2  = (const float*)d_in[14];
    const float* fc1_b2  = (const float*)d_in[15];
    const float* fc2_w1  = (const float*)d_in[16];
    const float* fc2_b1  = (const float*)d_in[17];
    const float* fc2_w2  = (const float*)d_in[18];
    const float* fc2_b2  = (const float*)d_in[19];
    float* out = (float*)d_out;

    char* base = (char*)d_ws;
    size_t o = 0;
    auto alloc = [&](size_t bytes) { size_t r = o; o += (bytes + 255) & ~255ULL; return r; };

    size_t o_xb   = alloc((size_t)MP1 * K1P * 2);    // reused for h2b/out2 after GEMM1
    size_t o_w1t  = alloc((size_t)768 * K1P * 2);
    size_t o_w2t  = alloc((size_t)256 * 768 * 2);
    size_t o_h1b  = alloc((size_t)NP * 768 * 2);
    size_t o_hob  = alloc((size_t)NP * 768 * 2);
    size_t o_es1  = alloc((size_t)NN * 3 * 4);
    size_t o_ed1  = alloc((size_t)NN * 3 * 4);
    size_t o_es2  = alloc((size_t)NN * 4);
    size_t o_ed2  = alloc((size_t)NN * 4);
    size_t o_deg  = alloc((size_t)(NN + 1) * 4);
    size_t o_cur  = alloc((size_t)NN * 4);           // adjacent to deg: one memset
    size_t o_off  = alloc((size_t)(NN + 1) * 4);
    size_t o_csr  = alloc((size_t)EL * 4);
    size_t o_bsum = alloc((size_t)NSB * 4);
    size_t o_boff = alloc((size_t)NSB * 4);
    size_t o_part = alloc((size_t)NG * PCH * 256 * 4);
    size_t o_cnts = alloc((size_t)NG * 4);

    __hip_bfloat16* xb   = (__hip_bfloat16*)(base + o_xb);
    __hip_bfloat16* w1t  = (__hip_bfloat16*)(base + o_w1t);
    __hip_bfloat16* w2t  = (__hip_bfloat16*)(base + o_w2t);
    __hip_bfloat16* h1b  = (__hip_bfloat16*)(base + o_h1b);
    __hip_bfloat16* hob  = (__hip_bfloat16*)(base + o_hob);
    __hip_bfloat16* h2b  = (__hip_bfloat16*)(base + o_xb);
    float*          out2 = (float*)(base + o_xb + (size_t)24 * 1024 * 1024);
    float* es1   = (float*)(base + o_es1);
    float* ed1   = (float*)(base + o_ed1);
    float* es2   = (float*)(base + o_es2);
    float* ed2   = (float*)(base + o_ed2);
    int*   deg   = (int*)(base + o_deg);
    int*   cur   = (int*)(base + o_cur);
    int*   offs  = (int*)(base + o_off);
    int*   csr   = (int*)(base + o_csr);
    int*   bsum  = (int*)(base + o_bsum);
    int*   boff  = (int*)(base + o_boff);
    float* part  = (float*)(base + o_part);
    float* cnts  = (float*)(base + o_cnts);

    // one memset covers deg + cur (adjacent)
    hipMemsetAsync(deg, 0, (o_cur - o_deg) + (size_t)NN * 4, stream);
    hipMemsetAsync(hob + (size_t)NN * 768, 0, (size_t)(NP - NN) * 768 * 2, stream);

    convert_x<<<(MP1 * (K1P / 8) + 255) / 256, 256, 0, stream>>>(x, xb);
    convert_w_all<<<(768 * K1P + 256 * 768 + 255) / 256, 256, 0, stream>>>(W1, W2, w1t, w2t);

    hist_kernel<<<(EL + 255) / 256, 256, 0, stream>>>(ei, deg);
    scan_blk<<<NSB, 1024, 0, stream>>>(deg, offs, bsum);
    scan_top<<<1, 64, 0, stream>>>(bsum, boff);
    scan_add<<<NSB, 1024, 0, stream>>>(offs, boff);
    fill_kernel<<<(EL + 255) / 256, 256, 0, stream>>>(ei, offs, cur, csr);

    gemm256<<<GMB * GNX, 512, 0, stream>>>(xb, w1t, h1b, a_src1, a_dst1, es1, ed1, NN);
    gat_aggregate<3, true, __hip_bfloat16><<<(NN + 3) / 4, 256, 0, stream>>>(h1b, es1, ed1, offs, csr, b1, hob, NN);

    mfma_gemm<__hip_bfloat16><<<2 * 157, 256, 0, stream>>>(hob, w2t, h2b, NN, 256, 768, 2);
    compute_e<1><<<(NN + 3) / 4, 256, 0, stream>>>(h2b, a_src2, a_dst2, es2, ed2, NN);
    gat_aggregate<1, false, float><<<(NN + 3) / 4, 256, 0, stream>>>(h2b, es2, ed2, offs, csr, b2, out2, NN);

    pool_partial<<<dim3(NG, PCH), 256, 0, stream>>>(out2, batch, part, cnts);
    head_kernel<<<NG, 256, 0, stream>>>(phy, part, cnts,
                                        fc1_w1, fc1_b1, fc1_w2, fc1_b2,
                                        fc2_w1, fc2_b1, fc2_w2, fc2_b2, out);
}

// Round 7
// 252.811 us; speedup vs baseline: 4.9525x; 1.0088x over previous
//
#include <hip/hip_runtime.h>
#include <hip/hip_bf16.h>
#include <math.h>

#define NN    20000
#define MP1   20224          // 79*256 padded rows for gemm1
#define NP    20096          // 157*128 padded rows for gemm2 A
#define E0    160000
#define EL    180000
#define NG    64
#define INDIM 1304
#define K1P   1344           // K padded to multiple of 64 (21 K-tiles)
#define GNT   21             // K1P/64
#define GNX   3              // 768/256
#define GMB   79             // M blocks
#define NEG_SLOPE 0.2f
#define PCH   8
#define NSB   20             // scan blocks = ceil(NN/1024)

typedef __bf16 bf16x8 __attribute__((ext_vector_type(8)));
typedef __bf16 bf16x4 __attribute__((ext_vector_type(4)));
typedef float  f32x4  __attribute__((ext_vector_type(4)));

__device__ __forceinline__ void gload16(const void* g, void* l) {
    __builtin_amdgcn_global_load_lds(
        (const __attribute__((address_space(1))) void*)g,
        (__attribute__((address_space(3))) void*)l, 16, 0, 0);
}

#define BAR()  { __builtin_amdgcn_s_barrier(); asm volatile("" ::: "memory"); }
#define VMW(n) { asm volatile("s_waitcnt vmcnt(" #n ")" ::: "memory"); __builtin_amdgcn_sched_barrier(0); }

// fast zero: grid-stride uint4
__global__ __launch_bounds__(256)
void zero_kernel(uint4* __restrict__ p, int n16) {
    uint4 z = {0u, 0u, 0u, 0u};
    for (int i = blockIdx.x * 256 + threadIdx.x; i < n16; i += gridDim.x * 256)
        p[i] = z;
}

// stage one 16-KB A half (mh) of K-tile kt: linear LDS dest, inverse-swizzled global src
__device__ __forceinline__ void stA(const __hip_bfloat16* __restrict__ A, int bm, int kt, int mh,
                                    char* abuf, int w, int l) {
#pragma unroll
    for (int u = 0; u < 2; u++) {
        int rl = (w << 3) + (l >> 3);            // row_local 0..63
        int lrow = u * 128 + mh * 64 + rl;       // row in 256-row tile
        int skb = ((l & 7) << 4) ^ ((rl & 7) << 4);
        const char* g = (const char*)(A + (size_t)(bm + lrow) * K1P + kt * 64) + skb;
        gload16(g, abuf + (u * 128 + mh * 64) * 128 + (w << 10));
    }
}

// stage one 16-KB B region (nh), 4 chunks of 32 rows
__device__ __forceinline__ void stB(const __hip_bfloat16* __restrict__ Bt, int bn, int kt, int nh,
                                    char* bbuf, int w, int l) {
#pragma unroll
    for (int u = 0; u < 2; u++) {
        int c = u * 2 + (w >> 2);
        int row0 = c * 64 + nh * 32;
        int rl = ((w & 3) << 3) + (l >> 3);      // 0..31
        int skb = ((l & 7) << 4) ^ ((rl & 7) << 4);
        const char* g = (const char*)(Bt + (size_t)(bn + row0 + rl) * K1P + kt * 64) + skb;
        gload16(g, bbuf + row0 * 128 + ((w & 3) << 10));
    }
}

// ---------------- 256x256 8-phase bf16 MFMA GEMM + fused layer-1 e_src/e_dst ----------------
__global__ __launch_bounds__(512)
void gemm256(const __hip_bfloat16* __restrict__ A,
             const __hip_bfloat16* __restrict__ Bt,
             __hip_bfloat16* __restrict__ C,
             const float* __restrict__ a_src, const float* __restrict__ a_dst,
             float* __restrict__ esrc, float* __restrict__ edst, int M) {
    __shared__ char lds[131072];
    const int t = threadIdx.x;
    const int w = t >> 6, l = t & 63;
    const int wm = w >> 2, wn = w & 3;           // 2 x 4 waves, each 128x64 output
    const int fr = l & 15, fq = l >> 4;
    const int amask = (fr & 7) << 4;

    const int nwg = GMB * GNX;
    const int q8 = nwg >> 3, r8 = nwg & 7;
    const int xcd = blockIdx.x & 7, sub = blockIdx.x >> 3;
    const int logical = (xcd < r8 ? xcd * (q8 + 1) : r8 * (q8 + 1) + (xcd - r8) * q8) + sub;
    const int bm = (logical / GNX) * 256;
    const int bn = (logical % GNX) * 256;

    f32x4 acc[8][4];
#pragma unroll
    for (int i = 0; i < 8; i++)
#pragma unroll
        for (int j = 0; j < 4; j++) acc[i][j] = (f32x4){0.f, 0.f, 0.f, 0.f};

    char* A0 = lds;            char* B0 = lds + 32768;
    char* A1 = lds + 65536;    char* B1 = lds + 98304;

    stA(A, bm, 0, 0, A0, w, l);
    stB(Bt, bn, 0, 0, B0, w, l);
    stA(A, bm, 0, 1, A0, w, l);
    stB(Bt, bn, 0, 1, B0, w, l);
    stA(A, bm, 1, 0, A1, w, l);
    stB(Bt, bn, 1, 0, B1, w, l);
    VMW(8);
    BAR();

    for (int kt = 0; kt < GNT; kt++) {
        char* Ab = lds + (kt & 1) * 65536;
        char* Bb = Ab + 32768;
        char* An = lds + ((kt + 1) & 1) * 65536;
        char* Bn = An + 32768;
        bf16x8 a_c[4][2], b_c0[2][2], b_c1[2][2];

        // ---- q0 ----
#pragma unroll
        for (int im = 0; im < 4; im++)
#pragma unroll
            for (int kk = 0; kk < 2; kk++)
                a_c[im][kk] = *(const bf16x8*)(Ab + (wm * 128 + im * 16 + fr) * 128 + ((kk * 64 + fq * 16) ^ amask));
#pragma unroll
        for (int jn = 0; jn < 2; jn++)
#pragma unroll
            for (int kk = 0; kk < 2; kk++)
                b_c0[jn][kk] = *(const bf16x8*)(Bb + (wn * 64 + jn * 16 + fr) * 128 + ((kk * 64 + fq * 16) ^ amask));
        if (kt + 1 < GNT) stA(A, bm, kt + 1, 1, An, w, l);
        BAR();
        __builtin_amdgcn_s_setprio(1);
#pragma unroll
        for (int im = 0; im < 4; im++)
#pragma unroll
            for (int jn = 0; jn < 2; jn++)
#pragma unroll
                for (int kk = 0; kk < 2; kk++)
                    acc[im][jn] = __builtin_amdgcn_mfma_f32_16x16x32_bf16(a_c[im][kk], b_c0[jn][kk], acc[im][jn], 0, 0, 0);
        __builtin_amdgcn_s_setprio(0);
        if (kt == GNT - 1) { VMW(0); } else { VMW(6); }
        BAR();

        // ---- q1 ----
#pragma unroll
        for (int jn = 0; jn < 2; jn++)
#pragma unroll
            for (int kk = 0; kk < 2; kk++)
                b_c1[jn][kk] = *(const bf16x8*)(Bb + (wn * 64 + 32 + jn * 16 + fr) * 128 + ((kk * 64 + fq * 16) ^ amask));
        if (kt + 1 < GNT) stB(Bt, bn, kt + 1, 1, Bn, w, l);
        BAR();
        __builtin_amdgcn_s_setprio(1);
#pragma unroll
        for (int im = 0; im < 4; im++)
#pragma unroll
            for (int jn = 0; jn < 2; jn++)
#pragma unroll
                for (int kk = 0; kk < 2; kk++)
                    acc[im][2 + jn] = __builtin_amdgcn_mfma_f32_16x16x32_bf16(a_c[im][kk], b_c1[jn][kk], acc[im][2 + jn], 0, 0, 0);
        __builtin_amdgcn_s_setprio(0);
        if (kt == GNT - 1) { VMW(2); } else { VMW(10); }
        BAR();

        // ---- q2 ----
#pragma unroll
        for (int im = 0; im < 4; im++)
#pragma unroll
            for (int kk = 0; kk < 2; kk++)
                a_c[im][kk] = *(const bf16x8*)(Ab + (wm * 128 + 64 + im * 16 + fr) * 128 + ((kk * 64 + fq * 16) ^ amask));
        if (kt + 2 < GNT) stA(A, bm, kt + 2, 0, Ab, w, l);
        BAR();
        __builtin_amdgcn_s_setprio(1);
#pragma unroll
        for (int im = 0; im < 4; im++)
#pragma unroll
            for (int jn = 0; jn < 2; jn++)
#pragma unroll
                for (int kk = 0; kk < 2; kk++)
                    acc[4 + im][jn] = __builtin_amdgcn_mfma_f32_16x16x32_bf16(a_c[im][kk], b_c0[jn][kk], acc[4 + im][jn], 0, 0, 0);
        __builtin_amdgcn_s_setprio(0);
        BAR();

        // ---- q3 ----
        if (kt + 2 < GNT) stB(Bt, bn, kt + 2, 0, Bb, w, l);
        BAR();
        __builtin_amdgcn_s_setprio(1);
#pragma unroll
        for (int im = 0; im < 4; im++)
#pragma unroll
            for (int jn = 0; jn < 2; jn++)
#pragma unroll
                for (int kk = 0; kk < 2; kk++)
                    acc[4 + im][2 + jn] = __builtin_amdgcn_mfma_f32_16x16x32_bf16(a_c[im][kk], b_c1[jn][kk], acc[4 + im][2 + jn], 0, 0, 0);
        __builtin_amdgcn_s_setprio(0);
        if (kt + 2 < GNT) { VMW(8); }
        else if (kt + 2 == GNT) { VMW(4); }
        BAR();
    }

    // C-write: col=lane&15, row=(lane>>4)*4+reg
#pragma unroll
    for (int i = 0; i < 8; i++)
#pragma unroll
        for (int j = 0; j < 4; j++)
#pragma unroll
            for (int r = 0; r < 4; r++) {
                int row = bm + wm * 128 + i * 16 + fq * 4 + r;
                int col = bn + wn * 64 + j * 16 + fr;
                if (row < M) C[(size_t)row * 768 + col] = __float2bfloat16(acc[i][j][r]);
            }

    // ---- fused e_src/e_dst (this block owns ALL channels of head bn/256) ----
    const int head = bn >> 8;
    float asv[4], adv[4];
#pragma unroll
    for (int j = 0; j < 4; j++) {
        asv[j] = a_src[head * 256 + wn * 64 + j * 16 + fr];
        adv[j] = a_dst[head * 256 + wn * 64 + j * 16 + fr];
    }
    __syncthreads();                     // done with MFMA lds; reuse as [256][4][2] f32
    float* eb = (float*)lds;
#pragma unroll
    for (int i = 0; i < 8; i++) {
#pragma unroll
        for (int r = 0; r < 4; r++) {
            float ps = 0.f, pd = 0.f;
#pragma unroll
            for (int j = 0; j < 4; j++) { ps += acc[i][j][r] * asv[j]; pd += acc[i][j][r] * adv[j]; }
#pragma unroll
            for (int o = 8; o >= 1; o >>= 1) { ps += __shfl_xor(ps, o, 64); pd += __shfl_xor(pd, o, 64); }
            if (fr == 0) {
                int rowl = wm * 128 + i * 16 + fq * 4 + r;
                eb[(rowl * 4 + wn) * 2 + 0] = ps;
                eb[(rowl * 4 + wn) * 2 + 1] = pd;
            }
        }
    }
    __syncthreads();
    if (t < 256) {
        int row = bm + t;
        if (row < M) {
            float s = eb[t * 8 + 0] + eb[t * 8 + 2] + eb[t * 8 + 4] + eb[t * 8 + 6];
            float d = eb[t * 8 + 1] + eb[t * 8 + 3] + eb[t * 8 + 5] + eb[t * 8 + 7];
            esrc[row * 3 + head] = s;
            edst[row * 3 + head] = d;
        }
    }
}

// ---------------- 2-phase double-buffered 128x128 GEMM (GEMM2) ----------------
template<typename CT>
__global__ __launch_bounds__(256)
void mfma_gemm(const __hip_bfloat16* __restrict__ A,
               const __hip_bfloat16* __restrict__ Bt,
               CT* __restrict__ C,
               int M, int N, int K, int NX) {
    __shared__ __hip_bfloat16 As[2][128 * 32];
    __shared__ __hip_bfloat16 Bs[2][128 * 32];
    const int t = threadIdx.x;
    const int w = t >> 6;
    const int l = t & 63;

    const int nwg = gridDim.x;
    const int q = nwg >> 3, r = nwg & 7;
    const int xcd = blockIdx.x & 7, idx = blockIdx.x >> 3;
    const int logical = (xcd < r ? xcd * (q + 1) : r * (q + 1) + (xcd - r) * q) + idx;
    const int bm = (logical / NX) * 128;
    const int bn = (logical % NX) * 128;

    const int wm = (w >> 1) * 64;
    const int wn = (w & 1) * 64;

    f32x4 acc[4][4];
#pragma unroll
    for (int i = 0; i < 4; i++)
#pragma unroll
        for (int j = 0; j < 4; j++) acc[i][j] = (f32x4){0.f, 0.f, 0.f, 0.f};

    const int sr = t >> 2;
    const int sc = (t & 3) * 8;
    const __hip_bfloat16* a0 = A  + (size_t)(bm + sr)      * K + sc;
    const __hip_bfloat16* a1 = A  + (size_t)(bm + 64 + sr) * K + sc;
    const __hip_bfloat16* b0 = Bt + (size_t)(bn + sr)      * K + sc;
    const __hip_bfloat16* b1 = Bt + (size_t)(bn + 64 + sr) * K + sc;

    const int fr = l & 15;
    const int fq = l >> 4;
    const int NT = K / 32;

    auto stage = [&](int k0, int b) {
        char* asb = (char*)&As[b][0];
        char* bsb = (char*)&Bs[b][0];
        gload16(a0 + k0, asb + w * 1024);
        gload16(a1 + k0, asb + 4096 + w * 1024);
        gload16(b0 + k0, bsb + w * 1024);
        gload16(b1 + k0, bsb + 4096 + w * 1024);
    };

    stage(0, 0);
    __syncthreads();

    for (int kt = 0; kt < NT; kt++) {
        const int cb = kt & 1;
        if (kt + 1 < NT) stage((kt + 1) * 32, cb ^ 1);   // prefetch next tile
        bf16x8 av[4], bv[4];
#pragma unroll
        for (int i = 0; i < 4; i++)
            av[i] = *(const bf16x8*)&As[cb][(wm + i * 16 + fr) * 32 + fq * 8];
#pragma unroll
        for (int j = 0; j < 4; j++)
            bv[j] = *(const bf16x8*)&Bs[cb][(wn + j * 16 + fr) * 32 + fq * 8];
#pragma unroll
        for (int i = 0; i < 4; i++)
#pragma unroll
            for (int j = 0; j < 4; j++)
                acc[i][j] = __builtin_amdgcn_mfma_f32_16x16x32_bf16(av[i], bv[j], acc[i][j], 0, 0, 0);
        __syncthreads();   // drains vmcnt (next tile staged) + lgkm; 1 barrier/iter
    }

#pragma unroll
    for (int i = 0; i < 4; i++) {
#pragma unroll
        for (int j = 0; j < 4; j++) {
#pragma unroll
            for (int r2 = 0; r2 < 4; r2++) {
                int row = bm + wm + i * 16 + fq * 4 + r2;
                int col = bn + wn + j * 16 + fr;
                if (row < M) {
                    if constexpr (sizeof(CT) == 2)
                        C[(size_t)row * N + col] = __float2bfloat16(acc[i][j][r2]);
                    else
                        C[(size_t)row * N + col] = acc[i][j][r2];
                }
            }
        }
    }
}

// ---------------- fp32 -> bf16 conversions ----------------
__global__ __launch_bounds__(256)
void convert_x(const float* __restrict__ X, __hip_bfloat16* __restrict__ Xb) {
    int idx = blockIdx.x * 256 + threadIdx.x;
    const int nb = K1P / 8;   // 168
    if (idx >= MP1 * nb) return;
    int row = idx / nb;
    int cb = (idx - row * nb) * 8;
    union { __hip_bfloat16 h[8]; float4 f4; } u;
    if (row < NN && cb + 8 <= INDIM) {
        const float4* p = (const float4*)(X + (size_t)row * INDIM + cb);
        float4 u0 = p[0], u1 = p[1];
        u.h[0] = __float2bfloat16(u0.x); u.h[1] = __float2bfloat16(u0.y);
        u.h[2] = __float2bfloat16(u0.z); u.h[3] = __float2bfloat16(u0.w);
        u.h[4] = __float2bfloat16(u1.x); u.h[5] = __float2bfloat16(u1.y);
        u.h[6] = __float2bfloat16(u1.z); u.h[7] = __float2bfloat16(u1.w);
    } else {
#pragma unroll
        for (int e = 0; e < 8; e++) {
            float f = (row < NN && cb + e < INDIM) ? X[(size_t)row * INDIM + cb + e] : 0.f;
            u.h[e] = __float2bfloat16(f);
        }
    }
    *(float4*)(Xb + (size_t)row * K1P + cb) = u.f4;
}

// both weight transposes in one launch
__global__ __launch_bounds__(256)
void convert_w_all(const float* __restrict__ W1, const float* __restrict__ W2,
                   __hip_bfloat16* __restrict__ w1t, __hip_bfloat16* __restrict__ w2t) {
    int idx = blockIdx.x * 256 + threadIdx.x;
    const int n1 = 768 * K1P;
    if (idx < n1) {
        int n = idx / K1P, k = idx - n * K1P;
        float f = (k < INDIM) ? W1[(size_t)k * 768 + n] : 0.f;
        w1t[idx] = __float2bfloat16(f);
    } else {
        int i2 = idx - n1;
        if (i2 < 256 * 768) {
            int n = i2 / 768, k = i2 - n * 768;
            w2t[i2] = __float2bfloat16(W2[(size_t)k * 256 + n]);
        }
    }
}

// ---------------- attention logits (layer 2 only) ----------------
template<int H>
__global__ __launch_bounds__(256)
void compute_e(const __hip_bfloat16* __restrict__ hfeat, const float* __restrict__ a_src,
               const float* __restrict__ a_dst, float* __restrict__ esrc,
               float* __restrict__ edst, int N) {
    const int wv = threadIdx.x >> 6, lane = threadIdx.x & 63;
    const int n = blockIdx.x * 4 + wv;
    if (n >= N) return;
#pragma unroll
    for (int hd = 0; hd < H; hd++) {
        bf16x4 hv = *(const bf16x4*)(hfeat + (size_t)n * (H * 256) + hd * 256 + lane * 4);
        float ps = 0.f, pd = 0.f;
#pragma unroll
        for (int e = 0; e < 4; e++) {
            float f = (float)hv[e];
            ps += f * a_src[hd * 256 + lane * 4 + e];
            pd += f * a_dst[hd * 256 + lane * 4 + e];
        }
#pragma unroll
        for (int o = 32; o > 0; o >>= 1) {
            ps += __shfl_down(ps, o, 64);
            pd += __shfl_down(pd, o, 64);
        }
        if (lane == 0) {
            esrc[n * H + hd] = ps;
            edst[n * H + hd] = pd;
        }
    }
}

// ---------------- CSR build ----------------
__global__ void hist_kernel(const int* __restrict__ ei, int* __restrict__ deg) {
    int e = blockIdx.x * 256 + threadIdx.x;
    if (e >= EL) return;
    int d = (e < E0) ? ei[E0 + e] : (e - E0);
    atomicAdd(&deg[d], 1);
}

// hierarchical scan
__global__ __launch_bounds__(1024)
void scan_blk(const int* __restrict__ deg, int* __restrict__ off, int* __restrict__ bsum) {
    __shared__ int wsum[16];
    const int b = blockIdx.x, t = threadIdx.x, lane = t & 63, wv = t >> 6;
    const int i = b * 1024 + t;
    int v = (i < NN) ? deg[i] : 0;
    int x = v;
#pragma unroll
    for (int o = 1; o < 64; o <<= 1) {
        int y = __shfl_up(x, o, 64);
        if (lane >= o) x += y;
    }
    if (lane == 63) wsum[wv] = x;
    __syncthreads();
    if (wv == 0 && lane < 16) {
        int s = wsum[lane];
#pragma unroll
        for (int o = 1; o < 16; o <<= 1) {
            int y = __shfl_up(s, o, 64);
            if (lane >= o) s += y;
        }
        wsum[lane] = s;
    }
    __syncthreads();
    int woff = (wv == 0) ? 0 : wsum[wv - 1];
    if (i < NN) off[i + 1] = woff + x;
    if (t == 1023) bsum[b] = wsum[15];
}

__global__ void scan_top(const int* __restrict__ bsum, int* __restrict__ boff) {
    int lane = threadIdx.x;   // 64 threads
    int v = (lane < NSB) ? bsum[lane] : 0;
    int x = v;
#pragma unroll
    for (int o = 1; o < 64; o <<= 1) {
        int y = __shfl_up(x, o, 64);
        if (lane >= o) x += y;
    }
    if (lane < NSB) boff[lane] = x - v;   // exclusive
}

__global__ __launch_bounds__(1024)
void scan_add(int* __restrict__ off, const int* __restrict__ boff) {
    const int b = blockIdx.x, t = threadIdx.x;
    const int i = b * 1024 + t;
    if (i < NN) off[i + 1] += boff[b];
    if (b == 0 && t == 0) off[0] = 0;
}

__global__ void fill_kernel(const int* __restrict__ ei, const int* __restrict__ off,
                            int* __restrict__ cur, int* __restrict__ csr) {
    int e = blockIdx.x * 256 + threadIdx.x;
    if (e >= EL) return;
    int d = (e < E0) ? ei[E0 + e] : (e - E0);
    int s = (e < E0) ? ei[e] : (e - E0);
    int pos = off[d] + atomicAdd(&cur[d], 1);
    csr[pos] = s;
}

// ---------------- GAT aggregation: one WAVE per node ----------------
template<int H, bool RELU, typename OutT>
__global__ __launch_bounds__(256)
void gat_aggregate(const __hip_bfloat16* __restrict__ hfeat,
                   const float* __restrict__ esrc,
                   const float* __restrict__ edst,
                   const int* __restrict__ off, const int* __restrict__ csr,
                   const float* __restrict__ bias,
                   OutT* __restrict__ out, int N) {
    const int wv = threadIdx.x >> 6, lane = threadIdx.x & 63;
    const int n = blockIdx.x * 4 + wv;
    if (n >= N) return;
    const int beg = off[n];
    const int deg = off[n + 1] - beg;

    float ed[H], m[H], den[H];
    f32x4 acc[H];
#pragma unroll
    for (int h = 0; h < H; h++) {
        ed[h] = edst[n * H + h];
        m[h] = -INFINITY;
        den[h] = 0.f;
        acc[h] = (f32x4){0.f, 0.f, 0.f, 0.f};
    }

    for (int base = 0; base < deg; base += 64) {
        const int i = base + lane;
        int s = 0;
        float lg[H];
        if (i < deg) {
            s = csr[beg + i];
#pragma unroll
            for (int h = 0; h < H; h++) {
                float v = esrc[s * H + h] + ed[h];
                lg[h] = (v >= 0.f) ? v : NEG_SLOPE * v;
            }
        } else {
#pragma unroll
            for (int h = 0; h < H; h++) lg[h] = -INFINITY;
        }
        float cm[H];
#pragma unroll
        for (int h = 0; h < H; h++) {
            cm[h] = lg[h];
#pragma unroll
            for (int o = 1; o < 64; o <<= 1)
                cm[h] = fmaxf(cm[h], __shfl_xor(cm[h], o, 64));
        }
#pragma unroll
        for (int h = 0; h < H; h++) {
            float nm = fmaxf(m[h], cm[h]);
            float sc = expf(m[h] - nm);
            den[h] *= sc;
#pragma unroll
            for (int e = 0; e < 4; e++) acc[h][e] *= sc;
            m[h] = nm;
        }
        float wgt[H];
#pragma unroll
        for (int h = 0; h < H; h++) {
            wgt[h] = (i < deg) ? expf(lg[h] - m[h]) : 0.f;
            den[h] += wgt[h];
        }
        const int cnt = min(64, deg - base);
        for (int j = 0; j < cnt; j++) {
            int sj = __shfl(s, j, 64);
#pragma unroll
            for (int h = 0; h < H; h++) {
                float wj = __shfl(wgt[h], j, 64);
                bf16x4 hv = *(const bf16x4*)(hfeat + (size_t)sj * (H * 256) + h * 256 + 4 * lane);
#pragma unroll
                for (int e = 0; e < 4; e++) acc[h][e] += wj * (float)hv[e];
            }
        }
    }
#pragma unroll
    for (int h = 0; h < H; h++) {
#pragma unroll
        for (int o = 1; o < 64; o <<= 1) den[h] += __shfl_xor(den[h], o, 64);
    }
#pragma unroll
    for (int h = 0; h < H; h++) {
        float inv = 1.f / (den[h] + 1e-16f);
        if constexpr (sizeof(OutT) == 2) {
            bf16x4 r;
#pragma unroll
            for (int e = 0; e < 4; e++) {
                float f = acc[h][e] * inv + bias[h * 256 + 4 * lane + e];
                if (RELU) f = fmaxf(f, 0.f);
                r[e] = (__bf16)f;
            }
            *(bf16x4*)((__hip_bfloat16*)out + (size_t)n * (H * 256) + h * 256 + 4 * lane) = r;
        } else {
            float4 r;
            float* rp = &r.x;
#pragma unroll
            for (int e = 0; e < 4; e++) {
                float f = acc[h][e] * inv + bias[h * 256 + 4 * lane + e];
                if (RELU) f = fmaxf(f, 0.f);
                rp[e] = f;
            }
            *(float4*)((float*)out + (size_t)n * (H * 256) + h * 256 + 4 * lane) = r;
        }
    }
}

// ---------------- pooling ----------------
__device__ __forceinline__ int lower_bound_batch(const int* __restrict__ batch, int key) {
    int lo = 0, hi = NN;
    while (lo < hi) {
        int mid = (lo + hi) >> 1;
        if (batch[mid] < key) lo = mid + 1; else hi = mid;
    }
    return lo;
}

__global__ __launch_bounds__(256)
void pool_partial(const float* __restrict__ out2, const int* __restrict__ batch,
                  float* __restrict__ partial, float* __restrict__ cnts) {
    const int g = blockIdx.x, c = blockIdx.y, t = threadIdx.x;
    const int s = lower_bound_batch(batch, g);
    const int e = lower_bound_batch(batch, g + 1);
    float acc = 0.f;
    for (int n = s + c; n < e; n += PCH) acc += out2[(size_t)n * 256 + t];
    partial[((size_t)g * PCH + c) * 256 + t] = acc;
    if (t == 0 && c == 0) cnts[g] = (float)(e - s);
}

// ---------------- MLP head + softmax ----------------
__global__ __launch_bounds__(256)
void head_kernel(const float* __restrict__ phy, const float* __restrict__ partial,
                 const float* __restrict__ cnts,
                 const float* __restrict__ w11, const float* __restrict__ b11,
                 const float* __restrict__ w12, const float* __restrict__ b12,
                 const float* __restrict__ w21, const float* __restrict__ b21,
                 const float* __restrict__ w22, const float* __restrict__ b22,
                 float* __restrict__ out) {
    int g = blockIdx.x, t = threadIdx.x;
    __shared__ float ph[188];
    __shared__ float z[384];
    __shared__ float mid[128];
    __shared__ float t1[192];
    __shared__ float lg[2];
    if (t < 188) ph[t] = phy[g * 188 + t];
    {
        float s = 0.f;
#pragma unroll
        for (int c = 0; c < PCH; c++) s += partial[((size_t)g * PCH + c) * 256 + t];
        z[t] = s / fmaxf(cnts[g], 1.0f);
    }
    __syncthreads();
    if (t < 128) {
        float s = b11[t];
        for (int k = 0; k < 188; k++) s += ph[k] * w11[k * 128 + t];
        mid[t] = fmaxf(s, 0.f);
    }
    __syncthreads();
    if (t < 128) {
        float s = b12[t];
        for (int k = 0; k < 128; k++) s += mid[k] * w12[k * 128 + t];
        z[256 + t] = fmaxf(s, 0.f);
    }
    __syncthreads();
    if (t < 192) {
        float s = b21[t];
        for (int k = 0; k < 384; k++) s += z[k] * w21[k * 192 + t];
        t1[t] = fmaxf(s, 0.f);
    }
    __syncthreads();
    if (t < 2) {
        float s = b22[t];
        for (int k = 0; k < 192; k++) s += t1[k] * w22[k * 2 + t];
        lg[t] = s;
    }
    __syncthreads();
    if (t == 0) {
        float mx = fmaxf(lg[0], lg[1]);
        float e0 = expf(lg[0] - mx), e1 = expf(lg[1] - mx);
        float d = e0 + e1;
        out[g * 2 + 0] = e0 / d;
        out[g * 2 + 1] = e1 / d;
    }
}

extern "C" void kernel_launch(void* const* d_in, const int* in_sizes, int n_in,
                              void* d_out, int out_size, void* d_ws, size_t ws_size,
                              hipStream_t stream) {
    const float* x       = (const float*)d_in[0];
    const int*   ei      = (const int*)  d_in[1];
    const float* phy     = (const float*)d_in[2];
    const int*   batch   = (const int*)  d_in[3];
    const float* W1      = (const float*)d_in[4];
    const float* a_src1  = (const float*)d_in[5];
    const float* a_dst1  = (const float*)d_in[6];
    const float* b1      = (const float*)d_in[7];
    const float* W2      = (const float*)d_in[8];
    const float* a_src2  = (const float*)d_in[9];
    const float* a_dst2  = (const float*)d_in[10];
    const float* b2      = (const float*)d_in[11];
    const float* fc1_w1  = (const float*)d_in[12];
    const float* fc1_b1  = (const float*)d_in[13];
    const float* fc1_w2  = (const float*)d_in[14];
    const float* fc1_b2  = (const float*)d_in[15];
    const float* fc2_w1  = (const float*)d_in[16];
    const float* fc2_b1  = (const float*)d_in[17];
    const float* fc2_w2  = (const float*)d_in[18];
    const float* fc2_b2  = (const float*)d_in[19];
    float* out = (float*)d_out;

    char* base = (char*)d_ws;
    size_t o = 0;
    auto alloc = [&](size_t bytes) { size_t r = o; o += (bytes + 255) & ~255ULL; return r; };

    size_t o_xb   = alloc((size_t)MP1 * K1P * 2);    // reused for h2b/out2 after GEMM1
    size_t o_w1t  = alloc((size_t)768 * K1P * 2);
    size_t o_w2t  = alloc((size_t)256 * 768 * 2);
    size_t o_h1b  = alloc((size_t)NP * 768 * 2);
    size_t o_hob  = alloc((size_t)NP * 768 * 2);
    size_t o_es1  = alloc((size_t)NN * 3 * 4);
    size_t o_ed1  = alloc((size_t)NN * 3 * 4);
    size_t o_es2  = alloc((size_t)NN * 4);
    size_t o_ed2  = alloc((size_t)NN * 4);
    size_t o_deg  = alloc((size_t)(NN + 1) * 4);
    size_t o_cur  = alloc((size_t)NN * 4);           // adjacent to deg: one zero pass
    size_t o_off  = alloc((size_t)(NN + 1) * 4);
    size_t o_csr  = alloc((size_t)EL * 4);
    size_t o_bsum = alloc((size_t)NSB * 4);
    size_t o_boff = alloc((size_t)NSB * 4);
    size_t o_part = alloc((size_t)NG * PCH * 256 * 4);
    size_t o_cnts = alloc((size_t)NG * 4);

    __hip_bfloat16* xb   = (__hip_bfloat16*)(base + o_xb);
    __hip_bfloat16* w1t  = (__hip_bfloat16*)(base + o_w1t);
    __hip_bfloat16* w2t  = (__hip_bfloat16*)(base + o_w2t);
    __hip_bfloat16* h1b  = (__hip_bfloat16*)(base + o_h1b);
    __hip_bfloat16* hob  = (__hip_bfloat16*)(base + o_hob);
    __hip_bfloat16* h2b  = (__hip_bfloat16*)(base + o_xb);
    float*          out2 = (float*)(base + o_xb + (size_t)24 * 1024 * 1024);
    float* es1   = (float*)(base + o_es1);
    float* ed1   = (float*)(base + o_ed1);
    float* es2   = (float*)(base + o_es2);
    float* ed2   = (float*)(base + o_ed2);
    int*   deg   = (int*)(base + o_deg);
    int*   cur   = (int*)(base + o_cur);
    int*   offs  = (int*)(base + o_off);
    int*   csr   = (int*)(base + o_csr);
    int*   bsum  = (int*)(base + o_bsum);
    int*   boff  = (int*)(base + o_boff);
    float* part  = (float*)(base + o_part);
    float* cnts  = (float*)(base + o_cnts);

    // zero deg+cur with our own kernel (rocclr fillBuffer was ~59us for this!)
    // region [o_deg, o_cur + NN*4) is 256-aligned and a multiple of 16 bytes.
    {
        size_t zbytes = (o_cur - o_deg) + (size_t)NN * 4;
        zero_kernel<<<64, 256, 0, stream>>>((uint4*)(base + o_deg), (int)(zbytes / 16));
    }
    // NOTE: hob pad rows (NN..NP) intentionally NOT zeroed — their products only
    // reach discarded (row >= M) accumulators in GEMM2.

    convert_x<<<(MP1 * (K1P / 8) + 255) / 256, 256, 0, stream>>>(x, xb);
    convert_w_all<<<(768 * K1P + 256 * 768 + 255) / 256, 256, 0, stream>>>(W1, W2, w1t, w2t);

    hist_kernel<<<(EL + 255) / 256, 256, 0, stream>>>(ei, deg);
    scan_blk<<<NSB, 1024, 0, stream>>>(deg, offs, bsum);
    scan_top<<<1, 64, 0, stream>>>(bsum, boff);
    scan_add<<<NSB, 1024, 0, stream>>>(offs, boff);
    fill_kernel<<<(EL + 255) / 256, 256, 0, stream>>>(ei, offs, cur, csr);

    gemm256<<<GMB * GNX, 512, 0, stream>>>(xb, w1t, h1b, a_src1, a_dst1, es1, ed1, NN);
    gat_aggregate<3, true, __hip_bfloat16><<<(NN + 3) / 4, 256, 0, stream>>>(h1b, es1, ed1, offs, csr, b1, hob, NN);

    mfma_gemm<__hip_bfloat16><<<2 * 157, 256, 0, stream>>>(hob, w2t, h2b, NN, 256, 768, 2);
    compute_e<1><<<(NN + 3) / 4, 256, 0, stream>>>(h2b, a_src2, a_dst2, es2, ed2, NN);
    gat_aggregate<1, false, float><<<(NN + 3) / 4, 256, 0, stream>>>(h2b, es2, ed2, offs, csr, b2, out2, NN);

    pool_partial<<<dim3(NG, PCH), 256, 0, stream>>>(out2, batch, part, cnts);
    head_kernel<<<NG, 256, 0, stream>>>(phy, part, cnts,
                                        fc1_w1, fc1_b1, fc1_w2, fc1_b2,
                                        fc2_w1, fc2_b1, fc2_w2, fc2_b2, out);
}

// Round 8
// 243.471 us; speedup vs baseline: 5.1425x; 1.0384x over previous
//
#include <hip/hip_runtime.h>
#include <hip/hip_bf16.h>
#include <math.h>

#define NN    20000
#define MP1   20224          // 79*256 padded rows for gemm1
#define NP    20096          // 157*128 padded rows for gemm2 A
#define E0    160000
#define EL    180000
#define NG    64
#define INDIM 1304
#define K1P   1344           // K padded to multiple of 64 (21 K-tiles)
#define GNT   21             // K1P/64
#define GNX   3              // 768/256
#define GMB   79             // M blocks
#define NEG_SLOPE 0.2f
#define PCH   8
#define NSB   20             // scan blocks = ceil(NN/1024)

// init_kernel block ranges
#define ZB    80             // zero blocks (es2+ed2+deg+cur ~320KB)
#define XB    13272          // convert_x blocks = MP1*168/256
#define WB    4800           // convert_w blocks

typedef __bf16 bf16x8 __attribute__((ext_vector_type(8)));
typedef __bf16 bf16x4 __attribute__((ext_vector_type(4)));
typedef float  f32x4  __attribute__((ext_vector_type(4)));

__device__ __forceinline__ void gload16(const void* g, void* l) {
    __builtin_amdgcn_global_load_lds(
        (const __attribute__((address_space(1))) void*)g,
        (__attribute__((address_space(3))) void*)l, 16, 0, 0);
}

#define BAR()  { __builtin_amdgcn_s_barrier(); asm volatile("" ::: "memory"); }
#define VMW(n) { asm volatile("s_waitcnt vmcnt(" #n ")" ::: "memory"); __builtin_amdgcn_sched_barrier(0); }

// ---------------- merged init: zero small buffers + convert x + convert weights ----------------
__global__ __launch_bounds__(256)
void init_kernel(uint4* __restrict__ zreg, int n16,
                 const float* __restrict__ X, __hip_bfloat16* __restrict__ Xb,
                 const float* __restrict__ W1, const float* __restrict__ W2,
                 __hip_bfloat16* __restrict__ w1t, __hip_bfloat16* __restrict__ w2t) {
    const int b = blockIdx.x, t = threadIdx.x;
    if (b < ZB) {
        int i = b * 256 + t;
        if (i < n16) zreg[i] = (uint4){0u, 0u, 0u, 0u};
        return;
    }
    if (b < ZB + XB) {
        int idx = (b - ZB) * 256 + t;
        const int nb = K1P / 8;   // 168
        int row = idx / nb;
        int cb = (idx - row * nb) * 8;
        union { __hip_bfloat16 h[8]; float4 f4; } u;
        if (row < NN && cb + 8 <= INDIM) {
            const float4* p = (const float4*)(X + (size_t)row * INDIM + cb);
            float4 u0 = p[0], u1 = p[1];
            u.h[0] = __float2bfloat16(u0.x); u.h[1] = __float2bfloat16(u0.y);
            u.h[2] = __float2bfloat16(u0.z); u.h[3] = __float2bfloat16(u0.w);
            u.h[4] = __float2bfloat16(u1.x); u.h[5] = __float2bfloat16(u1.y);
            u.h[6] = __float2bfloat16(u1.z); u.h[7] = __float2bfloat16(u1.w);
        } else {
#pragma unroll
            for (int e = 0; e < 8; e++) {
                float f = (row < NN && cb + e < INDIM) ? X[(size_t)row * INDIM + cb + e] : 0.f;
                u.h[e] = __float2bfloat16(f);
            }
        }
        *(float4*)(Xb + (size_t)row * K1P + cb) = u.f4;
        return;
    }
    {
        int idx = (b - ZB - XB) * 256 + t;
        const int n1 = 768 * K1P;
        if (idx < n1) {
            int n = idx / K1P, k = idx - n * K1P;
            float f = (k < INDIM) ? W1[(size_t)k * 768 + n] : 0.f;
            w1t[idx] = __float2bfloat16(f);
        } else {
            int i2 = idx - n1;
            if (i2 < 256 * 768) {
                int n = i2 / 768, k = i2 - n * 768;
                w2t[i2] = __float2bfloat16(W2[(size_t)k * 256 + n]);
            }
        }
    }
}

// stage one 16-KB A half (mh) of K-tile kt: linear LDS dest, inverse-swizzled global src
__device__ __forceinline__ void stA(const __hip_bfloat16* __restrict__ A, int bm, int kt, int mh,
                                    char* abuf, int w, int l) {
#pragma unroll
    for (int u = 0; u < 2; u++) {
        int rl = (w << 3) + (l >> 3);            // row_local 0..63
        int lrow = u * 128 + mh * 64 + rl;       // row in 256-row tile
        int skb = ((l & 7) << 4) ^ ((rl & 7) << 4);
        const char* g = (const char*)(A + (size_t)(bm + lrow) * K1P + kt * 64) + skb;
        gload16(g, abuf + (u * 128 + mh * 64) * 128 + (w << 10));
    }
}

// stage one 16-KB B region (nh), 4 chunks of 32 rows
__device__ __forceinline__ void stB(const __hip_bfloat16* __restrict__ Bt, int bn, int kt, int nh,
                                    char* bbuf, int w, int l) {
#pragma unroll
    for (int u = 0; u < 2; u++) {
        int c = u * 2 + (w >> 2);
        int row0 = c * 64 + nh * 32;
        int rl = ((w & 3) << 3) + (l >> 3);      // 0..31
        int skb = ((l & 7) << 4) ^ ((rl & 7) << 4);
        const char* g = (const char*)(Bt + (size_t)(bn + row0 + rl) * K1P + kt * 64) + skb;
        gload16(g, bbuf + row0 * 128 + ((w & 3) << 10));
    }
}

// ---------------- 256x256 8-phase bf16 MFMA GEMM + fused layer-1 e_src/e_dst ----------------
__global__ __launch_bounds__(512)
void gemm256(const __hip_bfloat16* __restrict__ A,
             const __hip_bfloat16* __restrict__ Bt,
             __hip_bfloat16* __restrict__ C,
             const float* __restrict__ a_src, const float* __restrict__ a_dst,
             float* __restrict__ esrc, float* __restrict__ edst, int M) {
    __shared__ char lds[131072];
    const int t = threadIdx.x;
    const int w = t >> 6, l = t & 63;
    const int wm = w >> 2, wn = w & 3;           // 2 x 4 waves, each 128x64 output
    const int fr = l & 15, fq = l >> 4;
    const int amask = (fr & 7) << 4;

    const int nwg = GMB * GNX;
    const int q8 = nwg >> 3, r8 = nwg & 7;
    const int xcd = blockIdx.x & 7, sub = blockIdx.x >> 3;
    const int logical = (xcd < r8 ? xcd * (q8 + 1) : r8 * (q8 + 1) + (xcd - r8) * q8) + sub;
    const int bm = (logical / GNX) * 256;
    const int bn = (logical % GNX) * 256;

    f32x4 acc[8][4];
#pragma unroll
    for (int i = 0; i < 8; i++)
#pragma unroll
        for (int j = 0; j < 4; j++) acc[i][j] = (f32x4){0.f, 0.f, 0.f, 0.f};

    char* A0 = lds;            char* B0 = lds + 32768;
    char* A1 = lds + 65536;    char* B1 = lds + 98304;

    stA(A, bm, 0, 0, A0, w, l);
    stB(Bt, bn, 0, 0, B0, w, l);
    stA(A, bm, 0, 1, A0, w, l);
    stB(Bt, bn, 0, 1, B0, w, l);
    stA(A, bm, 1, 0, A1, w, l);
    stB(Bt, bn, 1, 0, B1, w, l);
    VMW(8);
    BAR();

    for (int kt = 0; kt < GNT; kt++) {
        char* Ab = lds + (kt & 1) * 65536;
        char* Bb = Ab + 32768;
        char* An = lds + ((kt + 1) & 1) * 65536;
        char* Bn = An + 32768;
        bf16x8 a_c[4][2], b_c0[2][2], b_c1[2][2];

        // ---- q0 ----
#pragma unroll
        for (int im = 0; im < 4; im++)
#pragma unroll
            for (int kk = 0; kk < 2; kk++)
                a_c[im][kk] = *(const bf16x8*)(Ab + (wm * 128 + im * 16 + fr) * 128 + ((kk * 64 + fq * 16) ^ amask));
#pragma unroll
        for (int jn = 0; jn < 2; jn++)
#pragma unroll
            for (int kk = 0; kk < 2; kk++)
                b_c0[jn][kk] = *(const bf16x8*)(Bb + (wn * 64 + jn * 16 + fr) * 128 + ((kk * 64 + fq * 16) ^ amask));
        if (kt + 1 < GNT) stA(A, bm, kt + 1, 1, An, w, l);
        BAR();
        __builtin_amdgcn_s_setprio(1);
#pragma unroll
        for (int im = 0; im < 4; im++)
#pragma unroll
            for (int jn = 0; jn < 2; jn++)
#pragma unroll
                for (int kk = 0; kk < 2; kk++)
                    acc[im][jn] = __builtin_amdgcn_mfma_f32_16x16x32_bf16(a_c[im][kk], b_c0[jn][kk], acc[im][jn], 0, 0, 0);
        __builtin_amdgcn_s_setprio(0);
        if (kt == GNT - 1) { VMW(0); } else { VMW(6); }
        BAR();

        // ---- q1 ----
#pragma unroll
        for (int jn = 0; jn < 2; jn++)
#pragma unroll
            for (int kk = 0; kk < 2; kk++)
                b_c1[jn][kk] = *(const bf16x8*)(Bb + (wn * 64 + 32 + jn * 16 + fr) * 128 + ((kk * 64 + fq * 16) ^ amask));
        if (kt + 1 < GNT) stB(Bt, bn, kt + 1, 1, Bn, w, l);
        BAR();
        __builtin_amdgcn_s_setprio(1);
#pragma unroll
        for (int im = 0; im < 4; im++)
#pragma unroll
            for (int jn = 0; jn < 2; jn++)
#pragma unroll
                for (int kk = 0; kk < 2; kk++)
                    acc[im][2 + jn] = __builtin_amdgcn_mfma_f32_16x16x32_bf16(a_c[im][kk], b_c1[jn][kk], acc[im][2 + jn], 0, 0, 0);
        __builtin_amdgcn_s_setprio(0);
        if (kt == GNT - 1) { VMW(2); } else { VMW(10); }
        BAR();

        // ---- q2 ----
#pragma unroll
        for (int im = 0; im < 4; im++)
#pragma unroll
            for (int kk = 0; kk < 2; kk++)
                a_c[im][kk] = *(const bf16x8*)(Ab + (wm * 128 + 64 + im * 16 + fr) * 128 + ((kk * 64 + fq * 16) ^ amask));
        if (kt + 2 < GNT) stA(A, bm, kt + 2, 0, Ab, w, l);
        BAR();
        __builtin_amdgcn_s_setprio(1);
#pragma unroll
        for (int im = 0; im < 4; im++)
#pragma unroll
            for (int jn = 0; jn < 2; jn++)
#pragma unroll
                for (int kk = 0; kk < 2; kk++)
                    acc[4 + im][jn] = __builtin_amdgcn_mfma_f32_16x16x32_bf16(a_c[im][kk], b_c0[jn][kk], acc[4 + im][jn], 0, 0, 0);
        __builtin_amdgcn_s_setprio(0);
        BAR();

        // ---- q3 ----
        if (kt + 2 < GNT) stB(Bt, bn, kt + 2, 0, Bb, w, l);
        BAR();
        __builtin_amdgcn_s_setprio(1);
#pragma unroll
        for (int im = 0; im < 4; im++)
#pragma unroll
            for (int jn = 0; jn < 2; jn++)
#pragma unroll
                for (int kk = 0; kk < 2; kk++)
                    acc[4 + im][2 + jn] = __builtin_amdgcn_mfma_f32_16x16x32_bf16(a_c[im][kk], b_c1[jn][kk], acc[4 + im][2 + jn], 0, 0, 0);
        __builtin_amdgcn_s_setprio(0);
        if (kt + 2 < GNT) { VMW(8); }
        else if (kt + 2 == GNT) { VMW(4); }
        BAR();
    }

    // C-write: col=lane&15, row=(lane>>4)*4+reg
#pragma unroll
    for (int i = 0; i < 8; i++)
#pragma unroll
        for (int j = 0; j < 4; j++)
#pragma unroll
            for (int r = 0; r < 4; r++) {
                int row = bm + wm * 128 + i * 16 + fq * 4 + r;
                int col = bn + wn * 64 + j * 16 + fr;
                if (row < M) C[(size_t)row * 768 + col] = __float2bfloat16(acc[i][j][r]);
            }

    // ---- fused e_src/e_dst (this block owns ALL channels of head bn/256) ----
    const int head = bn >> 8;
    float asv[4], adv[4];
#pragma unroll
    for (int j = 0; j < 4; j++) {
        asv[j] = a_src[head * 256 + wn * 64 + j * 16 + fr];
        adv[j] = a_dst[head * 256 + wn * 64 + j * 16 + fr];
    }
    __syncthreads();                     // done with MFMA lds; reuse as [256][4][2] f32
    float* eb = (float*)lds;
#pragma unroll
    for (int i = 0; i < 8; i++) {
#pragma unroll
        for (int r = 0; r < 4; r++) {
            float ps = 0.f, pd = 0.f;
#pragma unroll
            for (int j = 0; j < 4; j++) { ps += acc[i][j][r] * asv[j]; pd += acc[i][j][r] * adv[j]; }
#pragma unroll
            for (int o = 8; o >= 1; o >>= 1) { ps += __shfl_xor(ps, o, 64); pd += __shfl_xor(pd, o, 64); }
            if (fr == 0) {
                int rowl = wm * 128 + i * 16 + fq * 4 + r;
                eb[(rowl * 4 + wn) * 2 + 0] = ps;
                eb[(rowl * 4 + wn) * 2 + 1] = pd;
            }
        }
    }
    __syncthreads();
    if (t < 256) {
        int row = bm + t;
        if (row < M) {
            float s = eb[t * 8 + 0] + eb[t * 8 + 2] + eb[t * 8 + 4] + eb[t * 8 + 6];
            float d = eb[t * 8 + 1] + eb[t * 8 + 3] + eb[t * 8 + 5] + eb[t * 8 + 7];
            esrc[row * 3 + head] = s;
            edst[row * 3 + head] = d;
        }
    }
}

// ---------------- 2-phase double-buffered 128x128 GEMM (GEMM2) + fused layer-2 e ----------------
__global__ __launch_bounds__(256)
void gemm2_fused(const __hip_bfloat16* __restrict__ A,
                 const __hip_bfloat16* __restrict__ Bt,
                 __hip_bfloat16* __restrict__ C,
                 const float* __restrict__ a_src2, const float* __restrict__ a_dst2,
                 float* __restrict__ esrc, float* __restrict__ edst,
                 int M, int N, int K, int NX) {
    __shared__ __hip_bfloat16 As[2][128 * 32];
    __shared__ __hip_bfloat16 Bs[2][128 * 32];
    const int t = threadIdx.x;
    const int w = t >> 6;
    const int l = t & 63;

    const int nwg = gridDim.x;
    const int q = nwg >> 3, r = nwg & 7;
    const int xcd = blockIdx.x & 7, idx = blockIdx.x >> 3;
    const int logical = (xcd < r ? xcd * (q + 1) : r * (q + 1) + (xcd - r) * q) + idx;
    const int bm = (logical / NX) * 128;
    const int bn = (logical % NX) * 128;

    const int wm = (w >> 1) * 64;
    const int wn = (w & 1) * 64;

    f32x4 acc[4][4];
#pragma unroll
    for (int i = 0; i < 4; i++)
#pragma unroll
        for (int j = 0; j < 4; j++) acc[i][j] = (f32x4){0.f, 0.f, 0.f, 0.f};

    const int sr = t >> 2;
    const int sc = (t & 3) * 8;
    const __hip_bfloat16* a0 = A  + (size_t)(bm + sr)      * K + sc;
    const __hip_bfloat16* a1 = A  + (size_t)(bm + 64 + sr) * K + sc;
    const __hip_bfloat16* b0 = Bt + (size_t)(bn + sr)      * K + sc;
    const __hip_bfloat16* b1 = Bt + (size_t)(bn + 64 + sr) * K + sc;

    const int fr = l & 15;
    const int fq = l >> 4;
    const int NT = K / 32;

    auto stage = [&](int k0, int b) {
        char* asb = (char*)&As[b][0];
        char* bsb = (char*)&Bs[b][0];
        gload16(a0 + k0, asb + w * 1024);
        gload16(a1 + k0, asb + 4096 + w * 1024);
        gload16(b0 + k0, bsb + w * 1024);
        gload16(b1 + k0, bsb + 4096 + w * 1024);
    };

    stage(0, 0);
    __syncthreads();

    for (int kt = 0; kt < NT; kt++) {
        const int cb = kt & 1;
        if (kt + 1 < NT) stage((kt + 1) * 32, cb ^ 1);
        bf16x8 av[4], bv[4];
#pragma unroll
        for (int i = 0; i < 4; i++)
            av[i] = *(const bf16x8*)&As[cb][(wm + i * 16 + fr) * 32 + fq * 8];
#pragma unroll
        for (int j = 0; j < 4; j++)
            bv[j] = *(const bf16x8*)&Bs[cb][(wn + j * 16 + fr) * 32 + fq * 8];
#pragma unroll
        for (int i = 0; i < 4; i++)
#pragma unroll
            for (int j = 0; j < 4; j++)
                acc[i][j] = __builtin_amdgcn_mfma_f32_16x16x32_bf16(av[i], bv[j], acc[i][j], 0, 0, 0);
        __syncthreads();
    }

#pragma unroll
    for (int i = 0; i < 4; i++) {
#pragma unroll
        for (int j = 0; j < 4; j++) {
#pragma unroll
            for (int r2 = 0; r2 < 4; r2++) {
                int row = bm + wm + i * 16 + fq * 4 + r2;
                int col = bn + wn + j * 16 + fr;
                if (row < M) C[(size_t)row * N + col] = __float2bfloat16(acc[i][j][r2]);
            }
        }
    }

    // ---- fused layer-2 e partials (this block covers cols bn+wn+{0..63}, H=1) ----
    float asv[4], adv[4];
#pragma unroll
    for (int j = 0; j < 4; j++) {
        asv[j] = a_src2[bn + wn + j * 16 + fr];
        adv[j] = a_dst2[bn + wn + j * 16 + fr];
    }
    __syncthreads();                      // done reading As/Bs; reuse As as eb[128][2][2]
    float* eb = (float*)&As[0][0];
#pragma unroll
    for (int i = 0; i < 4; i++) {
#pragma unroll
        for (int r2 = 0; r2 < 4; r2++) {
            float ps = 0.f, pd = 0.f;
#pragma unroll
            for (int j = 0; j < 4; j++) { ps += acc[i][j][r2] * asv[j]; pd += acc[i][j][r2] * adv[j]; }
#pragma unroll
            for (int o = 8; o >= 1; o >>= 1) { ps += __shfl_xor(ps, o, 64); pd += __shfl_xor(pd, o, 64); }
            if (fr == 0) {
                int rowl = wm + i * 16 + fq * 4 + r2;
                int wnIdx = wn >> 6;
                eb[(rowl * 2 + wnIdx) * 2 + 0] = ps;
                eb[(rowl * 2 + wnIdx) * 2 + 1] = pd;
            }
        }
    }
    __syncthreads();
    if (t < 128) {
        int row = bm + t;
        if (row < M) {
            atomicAdd(&esrc[row], eb[t * 4 + 0] + eb[t * 4 + 2]);
            atomicAdd(&edst[row], eb[t * 4 + 1] + eb[t * 4 + 3]);
        }
    }
}

// ---------------- CSR build ----------------
__global__ void hist_kernel(const int* __restrict__ ei, int* __restrict__ deg) {
    int e = blockIdx.x * 256 + threadIdx.x;
    if (e >= EL) return;
    int d = (e < E0) ? ei[E0 + e] : (e - E0);
    atomicAdd(&deg[d], 1);
}

__global__ __launch_bounds__(1024)
void scan_blk(const int* __restrict__ deg, int* __restrict__ off, int* __restrict__ bsum) {
    __shared__ int wsum[16];
    const int b = blockIdx.x, t = threadIdx.x, lane = t & 63, wv = t >> 6;
    const int i = b * 1024 + t;
    int v = (i < NN) ? deg[i] : 0;
    int x = v;
#pragma unroll
    for (int o = 1; o < 64; o <<= 1) {
        int y = __shfl_up(x, o, 64);
        if (lane >= o) x += y;
    }
    if (lane == 63) wsum[wv] = x;
    __syncthreads();
    if (wv == 0 && lane < 16) {
        int s = wsum[lane];
#pragma unroll
        for (int o = 1; o < 16; o <<= 1) {
            int y = __shfl_up(s, o, 64);
            if (lane >= o) s += y;
        }
        wsum[lane] = s;
    }
    __syncthreads();
    int woff = (wv == 0) ? 0 : wsum[wv - 1];
    if (i < NN) off[i + 1] = woff + x;
    if (t == 1023) bsum[b] = wsum[15];
}

// scan_add with inline top-level scan (each block redoes the tiny 20-elem scan)
__global__ __launch_bounds__(1024)
void scan_add(int* __restrict__ off, const int* __restrict__ bsum) {
    __shared__ int boffs[NSB];
    const int b = blockIdx.x, t = threadIdx.x;
    if (t < 64) {
        int lane = t;
        int v = (lane < NSB) ? bsum[lane] : 0;
        int x = v;
#pragma unroll
        for (int o = 1; o < 64; o <<= 1) {
            int y = __shfl_up(x, o, 64);
            if (lane >= o) x += y;
        }
        if (lane < NSB) boffs[lane] = x - v;   // exclusive
    }
    __syncthreads();
    const int i = b * 1024 + t;
    if (i < NN) off[i + 1] += boffs[b];
    if (b == 0 && t == 0) off[0] = 0;
}

__global__ void fill_kernel(const int* __restrict__ ei, const int* __restrict__ off,
                            int* __restrict__ cur, int* __restrict__ csr) {
    int e = blockIdx.x * 256 + threadIdx.x;
    if (e >= EL) return;
    int d = (e < E0) ? ei[E0 + e] : (e - E0);
    int s = (e < E0) ? ei[e] : (e - E0);
    int pos = off[d] + atomicAdd(&cur[d], 1);
    csr[pos] = s;
}

// ---------------- GAT aggregation: one WAVE per node ----------------
template<int H, bool RELU, typename OutT>
__global__ __launch_bounds__(256)
void gat_aggregate(const __hip_bfloat16* __restrict__ hfeat,
                   const float* __restrict__ esrc,
                   const float* __restrict__ edst,
                   const int* __restrict__ off, const int* __restrict__ csr,
                   const float* __restrict__ bias,
                   OutT* __restrict__ out, int N) {
    const int wv = threadIdx.x >> 6, lane = threadIdx.x & 63;
    const int n = blockIdx.x * 4 + wv;
    if (n >= N) return;
    const int beg = off[n];
    const int deg = off[n + 1] - beg;

    float ed[H], m[H], den[H];
    f32x4 acc[H];
#pragma unroll
    for (int h = 0; h < H; h++) {
        ed[h] = edst[n * H + h];
        m[h] = -INFINITY;
        den[h] = 0.f;
        acc[h] = (f32x4){0.f, 0.f, 0.f, 0.f};
    }

    for (int base = 0; base < deg; base += 64) {
        const int i = base + lane;
        int s = 0;
        float lg[H];
        if (i < deg) {
            s = csr[beg + i];
#pragma unroll
            for (int h = 0; h < H; h++) {
                float v = esrc[s * H + h] + ed[h];
                lg[h] = (v >= 0.f) ? v : NEG_SLOPE * v;
            }
        } else {
#pragma unroll
            for (int h = 0; h < H; h++) lg[h] = -INFINITY;
        }
        float cm[H];
#pragma unroll
        for (int h = 0; h < H; h++) {
            cm[h] = lg[h];
#pragma unroll
            for (int o = 1; o < 64; o <<= 1)
                cm[h] = fmaxf(cm[h], __shfl_xor(cm[h], o, 64));
        }
#pragma unroll
        for (int h = 0; h < H; h++) {
            float nm = fmaxf(m[h], cm[h]);
            float sc = expf(m[h] - nm);
            den[h] *= sc;
#pragma unroll
            for (int e = 0; e < 4; e++) acc[h][e] *= sc;
            m[h] = nm;
        }
        float wgt[H];
#pragma unroll
        for (int h = 0; h < H; h++) {
            wgt[h] = (i < deg) ? expf(lg[h] - m[h]) : 0.f;
            den[h] += wgt[h];
        }
        const int cnt = min(64, deg - base);
        for (int j = 0; j < cnt; j++) {
            int sj = __shfl(s, j, 64);
#pragma unroll
            for (int h = 0; h < H; h++) {
                float wj = __shfl(wgt[h], j, 64);
                bf16x4 hv = *(const bf16x4*)(hfeat + (size_t)sj * (H * 256) + h * 256 + 4 * lane);
#pragma unroll
                for (int e = 0; e < 4; e++) acc[h][e] += wj * (float)hv[e];
            }
        }
    }
#pragma unroll
    for (int h = 0; h < H; h++) {
#pragma unroll
        for (int o = 1; o < 64; o <<= 1) den[h] += __shfl_xor(den[h], o, 64);
    }
#pragma unroll
    for (int h = 0; h < H; h++) {
        float inv = 1.f / (den[h] + 1e-16f);
        if constexpr (sizeof(OutT) == 2) {
            bf16x4 r;
#pragma unroll
            for (int e = 0; e < 4; e++) {
                float f = acc[h][e] * inv + bias[h * 256 + 4 * lane + e];
                if (RELU) f = fmaxf(f, 0.f);
                r[e] = (__bf16)f;
            }
            *(bf16x4*)((__hip_bfloat16*)out + (size_t)n * (H * 256) + h * 256 + 4 * lane) = r;
        } else {
            float4 r;
            float* rp = &r.x;
#pragma unroll
            for (int e = 0; e < 4; e++) {
                float f = acc[h][e] * inv + bias[h * 256 + 4 * lane + e];
                if (RELU) f = fmaxf(f, 0.f);
                rp[e] = f;
            }
            *(float4*)((float*)out + (size_t)n * (H * 256) + h * 256 + 4 * lane) = r;
        }
    }
}

// ---------------- pooling (bf16 input) ----------------
__device__ __forceinline__ int lower_bound_batch(const int* __restrict__ batch, int key) {
    int lo = 0, hi = NN;
    while (lo < hi) {
        int mid = (lo + hi) >> 1;
        if (batch[mid] < key) lo = mid + 1; else hi = mid;
    }
    return lo;
}

__global__ __launch_bounds__(256)
void pool_partial(const __hip_bfloat16* __restrict__ out2, const int* __restrict__ batch,
                  float* __restrict__ partial, float* __restrict__ cnts) {
    const int g = blockIdx.x, c = blockIdx.y, t = threadIdx.x;
    const int s = lower_bound_batch(batch, g);
    const int e = lower_bound_batch(batch, g + 1);
    float acc = 0.f;
    for (int n = s + c; n < e; n += PCH) acc += __bfloat162float(out2[(size_t)n * 256 + t]);
    partial[((size_t)g * PCH + c) * 256 + t] = acc;
    if (t == 0 && c == 0) cnts[g] = (float)(e - s);
}

// ---------------- MLP head + softmax ----------------
__global__ __launch_bounds__(256)
void head_kernel(const float* __restrict__ phy, const float* __restrict__ partial,
                 const float* __restrict__ cnts,
                 const float* __restrict__ w11, const float* __restrict__ b11,
                 const float* __restrict__ w12, const float* __restrict__ b12,
                 const float* __restrict__ w21, const float* __restrict__ b21,
                 const float* __restrict__ w22, const float* __restrict__ b22,
                 float* __restrict__ out) {
    int g = blockIdx.x, t = threadIdx.x;
    __shared__ float ph[188];
    __shared__ float z[384];
    __shared__ float mid[128];
    __shared__ float t1[192];
    __shared__ float lg[2];
    if (t < 188) ph[t] = phy[g * 188 + t];
    {
        float s = 0.f;
#pragma unroll
        for (int c = 0; c < PCH; c++) s += partial[((size_t)g * PCH + c) * 256 + t];
        z[t] = s / fmaxf(cnts[g], 1.0f);
    }
    __syncthreads();
    if (t < 128) {
        float s = b11[t];
        for (int k = 0; k < 188; k++) s += ph[k] * w11[k * 128 + t];
        mid[t] = fmaxf(s, 0.f);
    }
    __syncthreads();
    if (t < 128) {
        float s = b12[t];
        for (int k = 0; k < 128; k++) s += mid[k] * w12[k * 128 + t];
        z[256 + t] = fmaxf(s, 0.f);
    }
    __syncthreads();
    if (t < 192) {
        float s = b21[t];
        for (int k = 0; k < 384; k++) s += z[k] * w21[k * 192 + t];
        t1[t] = fmaxf(s, 0.f);
    }
    __syncthreads();
    if (t < 2) {
        float s = b22[t];
        for (int k = 0; k < 192; k++) s += t1[k] * w22[k * 2 + t];
        lg[t] = s;
    }
    __syncthreads();
    if (t == 0) {
        float mx = fmaxf(lg[0], lg[1]);
        float e0 = expf(lg[0] - mx), e1 = expf(lg[1] - mx);
        float d = e0 + e1;
        out[g * 2 + 0] = e0 / d;
        out[g * 2 + 1] = e1 / d;
    }
}

extern "C" void kernel_launch(void* const* d_in, const int* in_sizes, int n_in,
                              void* d_out, int out_size, void* d_ws, size_t ws_size,
                              hipStream_t stream) {
    const float* x       = (const float*)d_in[0];
    const int*   ei      = (const int*)  d_in[1];
    const float* phy     = (const float*)d_in[2];
    const int*   batch   = (const int*)  d_in[3];
    const float* W1      = (const float*)d_in[4];
    const float* a_src1  = (const float*)d_in[5];
    const float* a_dst1  = (const float*)d_in[6];
    const float* b1      = (const float*)d_in[7];
    const float* W2      = (const float*)d_in[8];
    const float* a_src2  = (const float*)d_in[9];
    const float* a_dst2  = (const float*)d_in[10];
    const float* b2      = (const float*)d_in[11];
    const float* fc1_w1  = (const float*)d_in[12];
    const float* fc1_b1  = (const float*)d_in[13];
    const float* fc1_w2  = (const float*)d_in[14];
    const float* fc1_b2  = (const float*)d_in[15];
    const float* fc2_w1  = (const float*)d_in[16];
    const float* fc2_b1  = (const float*)d_in[17];
    const float* fc2_w2  = (const float*)d_in[18];
    const float* fc2_b2  = (const float*)d_in[19];
    float* out = (float*)d_out;

    char* base = (char*)d_ws;
    size_t o = 0;
    auto alloc = [&](size_t bytes) { size_t r = o; o += (bytes + 255) & ~255ULL; return r; };

    size_t o_xb   = alloc((size_t)MP1 * K1P * 2);    // reused for h2b/out2 after GEMM1
    size_t o_w1t  = alloc((size_t)768 * K1P * 2);
    size_t o_w2t  = alloc((size_t)256 * 768 * 2);
    size_t o_h1b  = alloc((size_t)NP * 768 * 2);
    size_t o_hob  = alloc((size_t)NP * 768 * 2);
    size_t o_es1  = alloc((size_t)NN * 3 * 4);
    size_t o_ed1  = alloc((size_t)NN * 3 * 4);
    // zero region: es2, ed2, deg, cur contiguous
    size_t o_es2  = alloc((size_t)NN * 4);
    size_t o_ed2  = alloc((size_t)NN * 4);
    size_t o_deg  = alloc((size_t)(NN + 1) * 4);
    size_t o_cur  = alloc((size_t)NN * 4);
    size_t o_zend = o;
    size_t o_off  = alloc((size_t)(NN + 1) * 4);
    size_t o_csr  = alloc((size_t)EL * 4);
    size_t o_bsum = alloc((size_t)NSB * 4);
    size_t o_part = alloc((size_t)NG * PCH * 256 * 4);
    size_t o_cnts = alloc((size_t)NG * 4);
    (void)o_cnts;

    __hip_bfloat16* xb   = (__hip_bfloat16*)(base + o_xb);
    __hip_bfloat16* w1t  = (__hip_bfloat16*)(base + o_w1t);
    __hip_bfloat16* w2t  = (__hip_bfloat16*)(base + o_w2t);
    __hip_bfloat16* h1b  = (__hip_bfloat16*)(base + o_h1b);
    __hip_bfloat16* hob  = (__hip_bfloat16*)(base + o_hob);
    __hip_bfloat16* h2b  = (__hip_bfloat16*)(base + o_xb);
    __hip_bfloat16* out2 = (__hip_bfloat16*)(base + o_xb + (size_t)24 * 1024 * 1024);
    float* es1   = (float*)(base + o_es1);
    float* ed1   = (float*)(base + o_ed1);
    float* es2   = (float*)(base + o_es2);
    float* ed2   = (float*)(base + o_ed2);
    int*   deg   = (int*)(base + o_deg);
    int*   cur   = (int*)(base + o_cur);
    int*   offs  = (int*)(base + o_off);
    int*   csr   = (int*)(base + o_csr);
    int*   bsum  = (int*)(base + o_bsum);
    float* part  = (float*)(base + o_part);
    float* cnts  = (float*)(base + o_cnts);

    // merged init: zero(es2,ed2,deg,cur) + convert_x + convert_w (one launch)
    {
        int n16 = (int)((o_zend - o_es2) / 16);
        init_kernel<<<ZB + XB + WB, 256, 0, stream>>>((uint4*)(base + o_es2), n16,
                                                      x, xb, W1, W2, w1t, w2t);
    }
    // NOTE: hob pad rows (NN..NP) not zeroed — products only reach discarded rows.

    hist_kernel<<<(EL + 255) / 256, 256, 0, stream>>>(ei, deg);
    scan_blk<<<NSB, 1024, 0, stream>>>(deg, offs, bsum);
    scan_add<<<NSB, 1024, 0, stream>>>(offs, bsum);
    fill_kernel<<<(EL + 255) / 256, 256, 0, stream>>>(ei, offs, cur, csr);

    gemm256<<<GMB * GNX, 512, 0, stream>>>(xb, w1t, h1b, a_src1, a_dst1, es1, ed1, NN);
    gat_aggregate<3, true, __hip_bfloat16><<<(NN + 3) / 4, 256, 0, stream>>>(h1b, es1, ed1, offs, csr, b1, hob, NN);

    gemm2_fused<<<2 * 157, 256, 0, stream>>>(hob, w2t, h2b, a_src2, a_dst2, es2, ed2, NN, 256, 768, 2);
    gat_aggregate<1, false, __hip_bfloat16><<<(NN + 3) / 4, 256, 0, stream>>>(h2b, es2, ed2, offs, csr, b2, out2, NN);

    pool_partial<<<dim3(NG, PCH), 256, 0, stream>>>(out2, batch, part, cnts);
    head_kernel<<<NG, 256, 0, stream>>>(phy, part, cnts,
                                        fc1_w1, fc1_b1, fc1_w2, fc1_b2,
                                        fc2_w1, fc2_b1, fc2_w2, fc2_b2, out);
}